// Round 2
// baseline (300.442 us; speedup 1.0000x reference)
//
#include <hip/hip_runtime.h>
#include <hip/hip_bf16.h>

// PointsToBEV round 17. R16 post-mortem: removing atomics moved FETCH only
// -4.8MB (== the removed 75k random cnt reads x 64B). The ~85MB/85MB
// unexplained symmetric traffic in k_mlp_mfma == ~820k 64B partial-row store
// segments x 128B RMW: the [row*80 + nt*16] layout splits each 320B row into
// five temporally-separated 64B stores. Fixes: (1) plane-major sums layout
// sums[nt*P + row*16 + ch16] -> chunk stores become contiguous full-line
// runs; (2) psorted packed to 8B fp16 cell-deltas + u16 cell (halves scatter
// lines + mlp reads); (3) k_fixup folded into k_head via offs/cnt math;
// (4) k_zero shrunk to cnt+diag window (sums rows fully owner-written,
// k_head gates on cnt>0); (5) k_mlp grid 1280 (5 blocks/CU) + next-chunk
// prefetch.

#define B_    4
#define NP_   200000
#define CH    80
#define COUT_ 128
#define BEVH  128
#define BEVW  128
#define HW_   (BEVH * BEVW)
#define NCHK  (NP_ / 64)        // 3125 chunks per batch (NP_ % 64 == 0)

// Per-batch bytes: cnt(HW u32) + sums+staging((HW+NCHK)*80 f32) +
// offs(HW u32 +pad) + cursor(HW u32) + psorted8(NP*8) + scell16(NP*2)
#define PER_BATCH ((size_t)HW_ * 332 + (size_t)NCHK * 320 + (size_t)NP_ * 10)
#define EXTRA_BYTES 512

#define MAGIC_OFF   128
#define SCRATCH_OFF 256

typedef _Float16 half4_t __attribute__((ext_vector_type(4)));
typedef _Float16 half8_t __attribute__((ext_vector_type(8)));
typedef float    f32x4_t __attribute__((ext_vector_type(4)));

#define HSTR 104   // W2T k-stride in f16 (52 dwords -> 2-way banks, free)
#define ESTR 72    // embT pt-stride in f16 (36 dwords -> 2-way banks, free)

__device__ __forceinline__ float bf2f(unsigned short u) {
    return __uint_as_float(((unsigned int)u) << 16);
}
__device__ __forceinline__ unsigned short f2h(float f) {
    return __builtin_bit_cast(unsigned short, (_Float16)f);
}
__device__ __forceinline__ float h2f(unsigned short u) {
    return (float)__builtin_bit_cast(_Float16, u);
}

// ---------------------------------------------------------------------------
// dtype probes: flags[0]=params fp32, flags[1]=points fp32.
// ---------------------------------------------------------------------------
__global__ void k_detect(const unsigned short* __restrict__ w1bits,
                         const unsigned short* __restrict__ ptsbits,
                         unsigned int* __restrict__ flags) {
    const int t = threadIdx.x;
    const int which = blockIdx.x;
    const unsigned short* src = which ? ptsbits : w1bits;
    const int n = which ? 512 : 320;
    float m = 0.0f;
    for (int i = t; i < n; i += 64) {
        const float a = fabsf(bf2f(src[i]));
        if (a == a) m = fmaxf(m, a);
    }
#pragma unroll
    for (int off = 32; off > 0; off >>= 1)
        m = fmaxf(m, __shfl_down(m, off));
    if (t == 0) flags[which] = (m > 1.0e6f) ? 1u : 0u;
}

__global__ __launch_bounds__(256) void k_zero(float4* __restrict__ p, int n4) {
    const float4 z = {0.0f, 0.0f, 0.0f, 0.0f};
    for (int i = blockIdx.x * 256 + threadIdx.x; i < n4; i += gridDim.x * 256)
        p[i] = z;
}

__device__ __forceinline__ int cell_of(float px, float py, int bloc) {
    const int ix = (int)floorf((px + 50.0f) / 0.78125f);
    const int iy = (int)floorf((py + 50.0f) / 0.78125f);
    if (ix < 0 || ix >= BEVW || iy < 0 || iy >= BEVH) return -1;
    return bloc * HW_ + iy * BEVW + ix;
}

__device__ __forceinline__ void load_pt(const void* pts_raw, size_t pidx, int pf32,
                                        float& px, float& py, float& pz, float& pw) {
    if (pf32) {
        const float4 p = ((const float4*)pts_raw)[pidx];
        px = p.x; py = p.y; pz = p.z; pw = p.w;
    } else {
        const ushort4 p = ((const ushort4*)pts_raw)[pidx];
        px = bf2f(p.x); py = bf2f(p.y); pz = bf2f(p.z); pw = bf2f(p.w);
    }
}

// ---------------------------------------------------------------------------
// Phase A: histogram.
// ---------------------------------------------------------------------------
__global__ __launch_bounds__(256) void k_bin(
    const void* __restrict__ pts_raw,
    const unsigned int* __restrict__ flags,
    unsigned int* __restrict__ cnt,
    int b0, int npts)
{
    const int gid = blockIdx.x * 256 + threadIdx.x;
    if (gid >= npts) return;
    float px, py, pz, pw;
    load_pt(pts_raw, (size_t)b0 * NP_ + gid, (int)flags[1], px, py, pz, pw);
    const int g = cell_of(px, py, gid / NP_);
    if (g >= 0) atomicAdd(&cnt[g], 1u);
}

// ---------------------------------------------------------------------------
// Phase B1: per-block (1024 cells) sums.
// ---------------------------------------------------------------------------
__global__ __launch_bounds__(256) void k_scan_part(
    const unsigned int* __restrict__ cnt,
    unsigned int* __restrict__ bsums)
{
    __shared__ unsigned int sd[256];
    const int t = threadIdx.x;
    const int i0 = blockIdx.x * 1024 + t * 4;
    unsigned int s = cnt[i0] + cnt[i0 + 1] + cnt[i0 + 2] + cnt[i0 + 3];
    sd[t] = s;
    __syncthreads();
    for (int d = 128; d > 0; d >>= 1) {
        if (t < d) sd[t] += sd[t + d];
        __syncthreads();
    }
    if (t == 0) bsums[blockIdx.x] = sd[0];
}

// ---------------------------------------------------------------------------
// Phase B2: apply prefix -> offs (+sentinel) and cursor.
// ---------------------------------------------------------------------------
__global__ __launch_bounds__(256) void k_scan_apply(
    const unsigned int* __restrict__ cnt,
    const unsigned int* __restrict__ bsums,
    unsigned int* __restrict__ offs,
    unsigned int* __restrict__ cursor,
    int nblocks, int n)
{
    __shared__ unsigned int sd[256];
    __shared__ unsigned int sBase;
    const int t = threadIdx.x;
    const int blk = blockIdx.x;
    const int i0 = blk * 1024 + t * 4;
    unsigned int c0 = cnt[i0], c1 = cnt[i0 + 1], c2 = cnt[i0 + 2], c3 = cnt[i0 + 3];
    const unsigned int s4 = c0 + c1 + c2 + c3;
    sd[t] = s4;
    if (t == 0) {
        unsigned int b = 0;
        for (int j = 0; j < blk; ++j) b += bsums[j];
        sBase = b;
    }
    __syncthreads();
    for (int d = 1; d < 256; d <<= 1) {
        const unsigned int add = (t >= d) ? sd[t - d] : 0u;
        __syncthreads();
        sd[t] += add;
        __syncthreads();
    }
    unsigned int run = sBase + sd[t] - s4;    // exclusive prefix
    offs[i0] = run;     cursor[i0] = run;     run += c0;
    offs[i0 + 1] = run; cursor[i0 + 1] = run; run += c1;
    offs[i0 + 2] = run; cursor[i0 + 2] = run; run += c2;
    offs[i0 + 3] = run; cursor[i0 + 3] = run; run += c3;
    if (blk == nblocks - 1 && t == 255) offs[n] = run;
}

// ---------------------------------------------------------------------------
// Phase C: materialize the sort — packed 8B fp16 cell-delta + u16 cell.
// ---------------------------------------------------------------------------
__global__ __launch_bounds__(256) void k_scatteridx(
    const void* __restrict__ pts_raw,
    const unsigned int* __restrict__ flags,
    unsigned int* __restrict__ cursor,
    ushort4* __restrict__ psorted8,
    unsigned short* __restrict__ scell16,
    int b0, int npts)
{
    const int gid = blockIdx.x * 256 + threadIdx.x;
    if (gid >= npts) return;
    float px, py, pz, pw;
    load_pt(pts_raw, (size_t)b0 * NP_ + gid, (int)flags[1], px, py, pz, pw);
    const int g = cell_of(px, py, gid / NP_);
    if (g < 0) return;
    const unsigned int pos = atomicAdd(&cursor[g], 1u);
    const int cellin = g & (HW_ - 1);
    const float cx = fmaf((float)(cellin & 127), 0.78125f, -49.609375f);
    const float cy = fmaf((float)(cellin >> 7), 0.78125f, -49.609375f);
    ushort4 r;
    r.x = f2h(px - cx);
    r.y = f2h(py - cy);
    r.z = f2h(pz);
    r.w = f2h(pw);
    psorted8[pos] = r;
    scell16[pos] = (unsigned short)g;
}

// ---------------------------------------------------------------------------
// Phase D (persistent MFMA): waves grid-stride over 64-point chunks.
// Plane-major sums: element (row, ch = nt*16+m15) at sums[nt*P + row*16+m15]
// -> each chunk's stores per plane are contiguous 64B blocks over its
// consecutive cell rows (full-line coverage, no partial-line RMW).
// Next-chunk psorted/scell prefetch hides HBM latency under the nt loop.
// ---------------------------------------------------------------------------
__global__ __launch_bounds__(256, 4) void k_mlp_mfma(
    const ushort4* __restrict__ psorted8,
    const unsigned short* __restrict__ scell16,
    const void* __restrict__ W1_raw,
    const void* __restrict__ b1_raw,
    const void* __restrict__ W2_raw,
    const void* __restrict__ b2_raw,
    const unsigned int* __restrict__ flags,
    unsigned int* __restrict__ magic,
    const unsigned int* __restrict__ offs,    // ncells+1 (sentinel = total)
    float* __restrict__ sums,                 // 5 planes of P floats
    int ncells, int P)
{
    __shared__ float sW1[4 * CH];             // [f][k]
    __shared__ float sb1[CH];
    __shared__ float sb2f[CH];
    __shared__ _Float16 sW2T[80 * HSTR];      // [ch_out][k], k 80..95 zero
    __shared__ _Float16 sEmb[4][16 * ESTR];   // per-wave embT slice [ch16][pt]
    __shared__ unsigned int sCellG[4][64];

    const int t = threadIdx.x;
    const int wf32 = (int)flags[0];

    if (wf32) {
        const float* W1 = (const float*)W1_raw;
        const float* b1 = (const float*)b1_raw;
        const float* b2 = (const float*)b2_raw;
        for (int i = t; i < 4 * CH; i += 256) sW1[i] = W1[i];
        if (t < CH) { sb1[t] = b1[t]; sb2f[t] = b2[t]; }
        const float* W2 = (const float*)W2_raw;
        for (int i = t; i < 80 * HSTR; i += 256) {
            const int row = i / HSTR, k = i % HSTR;
            sW2T[i] = (_Float16)((k < 80) ? W2[k * CH + row] : 0.0f);
        }
    } else {
        const unsigned short* W1 = (const unsigned short*)W1_raw;
        const unsigned short* b1 = (const unsigned short*)b1_raw;
        const unsigned short* b2 = (const unsigned short*)b2_raw;
        for (int i = t; i < 4 * CH; i += 256) sW1[i] = bf2f(W1[i]);
        if (t < CH) { sb1[t] = bf2f(b1[t]); sb2f[t] = bf2f(b2[t]); }
        const unsigned short* W2 = (const unsigned short*)W2_raw;
        for (int i = t; i < 80 * HSTR; i += 256) {
            const int row = i / HSTR, k = i % HSTR;
            sW2T[i] = (_Float16)((k < 80) ? bf2f(W2[k * CH + row]) : 0.0f);
        }
    }
    __syncthreads();

    if (blockIdx.x == 0 && t == 0) *magic = 0xCAFEBABEu;

    const int end = (int)offs[ncells];
    const int lane = t & 63;
    const int wid = t >> 6;
    const int m15 = lane & 15;
    const int quad = lane >> 4;
    const int totalWaves = gridDim.x * 4;
    const int nChunks = (end + 63) >> 6;

    int wv = blockIdx.x * 4 + wid;
    if (wv < nChunks) {
        // first-chunk loads (clamped so inactive lanes read a valid record)
        int pc = wv * 64 + lane; if (pc > end - 1) pc = end - 1;
        ushort4 pr = psorted8[pc];
        unsigned short c16 = scell16[pc];

        for (;;) {
            const int chunkStart = wv * 64;
            const int p = chunkStart + lane;
            const bool active = p < end;
            const int wvn = wv + totalWaves;
            const bool hasNext = wvn < nChunks;

            // ---- decode current record (always finite: clamped load).
            const int gi = (int)c16;
            const int cellin = gi & (HW_ - 1);
            const float cx = fmaf((float)(cellin & 127), 0.78125f, -49.609375f);
            const float cy = fmaf((float)(cellin >> 7), 0.78125f, -49.609375f);
            const float px = cx + h2f(pr.x);
            const float py = cy + h2f(pr.y);
            const float pz = h2f(pr.z);
            const float pw = h2f(pr.w);
            const int g = active ? gi : -1;

            // ---- segment bookkeeping (R13-verified).
            const int gprev = __shfl_up(g, 1);
            const bool isHead = active && (lane == 0 || gprev != g);
            const unsigned long long headmask = __ballot(isHead);
            const int cellLocal = active
                ? (__popcll(headmask << (63 - lane)) - 1) : 255;
            const int ncellsW = __popcll(headmask);
            if (isHead) {
                // Ownership: cell start within this chunk -> direct row g;
                // head cell that started earlier -> per-chunk staging row.
                unsigned int row = (unsigned int)g;
                if (cellLocal == 0) {
                    const unsigned int o = offs[g];
                    if (o < (unsigned int)chunkStart)
                        row = (unsigned int)(ncells + wv);
                }
                sCellG[wid][cellLocal] = row;
            }

            // ---- gather the 4 points this lane's A-fragments cover.
            float pmx[4], pmy[4], pmz[4], pmw[4];
#pragma unroll
            for (int mt = 0; mt < 4; ++mt) {
                const int src = mt * 16 + m15;
                pmx[mt] = __shfl(px, src);
                pmy[mt] = __shfl(py, src);
                pmz[mt] = __shfl(pz, src);
                pmw[mt] = __shfl(pw, src);
            }

            // ---- prefetch next chunk (latency hidden under nt loop).
            ushort4 prN = {0, 0, 0, 0};
            unsigned short c16N = 0;
            if (hasNext) {
                int pcn = wvn * 64 + lane; if (pcn > end - 1) pcn = end - 1;
                prN = psorted8[pcn];
                c16N = scell16[pcn];
            }

            // ---- layer 1 transposed: A-frag values born in registers.
            half8_t Af[3][4];
#pragma unroll
            for (int ks = 0; ks < 3; ++ks) {
                const int kb = ks * 32 + quad * 8;
                if (kb < 80) {
                    const float4 wa0 = *(const float4*)&sW1[0 * CH + kb];
                    const float4 wb0 = *(const float4*)&sW1[0 * CH + kb + 4];
                    const float4 wa1 = *(const float4*)&sW1[1 * CH + kb];
                    const float4 wb1 = *(const float4*)&sW1[1 * CH + kb + 4];
                    const float4 wa2 = *(const float4*)&sW1[2 * CH + kb];
                    const float4 wb2 = *(const float4*)&sW1[2 * CH + kb + 4];
                    const float4 wa3 = *(const float4*)&sW1[3 * CH + kb];
                    const float4 wb3 = *(const float4*)&sW1[3 * CH + kb + 4];
                    const float4 ba  = *(const float4*)&sb1[kb];
                    const float4 bb  = *(const float4*)&sb1[kb + 4];
                    float w0[8] = {wa0.x, wa0.y, wa0.z, wa0.w, wb0.x, wb0.y, wb0.z, wb0.w};
                    float w1[8] = {wa1.x, wa1.y, wa1.z, wa1.w, wb1.x, wb1.y, wb1.z, wb1.w};
                    float w2[8] = {wa2.x, wa2.y, wa2.z, wa2.w, wb2.x, wb2.y, wb2.z, wb2.w};
                    float w3[8] = {wa3.x, wa3.y, wa3.z, wa3.w, wb3.x, wb3.y, wb3.z, wb3.w};
                    float bv[8] = {ba.x, ba.y, ba.z, ba.w, bb.x, bb.y, bb.z, bb.w};
#pragma unroll
                    for (int mt = 0; mt < 4; ++mt) {
                        half8_t v;
#pragma unroll
                        for (int j = 0; j < 8; ++j) {
                            float hv = bv[j];
                            hv = fmaf(pmx[mt], w0[j], hv);
                            hv = fmaf(pmy[mt], w1[j], hv);
                            hv = fmaf(pmz[mt], w2[j], hv);
                            hv = fmaf(pmw[mt], w3[j], hv);
                            v[j] = (_Float16)fmaxf(hv, 0.0f);
                        }
                        Af[ks][mt] = v;
                    }
                } else {
                    const half8_t z8 = {0, 0, 0, 0, 0, 0, 0, 0};
#pragma unroll
                    for (int mt = 0; mt < 4; ++mt) Af[ks][mt] = z8;
                }
            }

            // ---- selector columns for MFMA2.
            int cl[2][8];
#pragma unroll
            for (int ks2 = 0; ks2 < 2; ++ks2)
#pragma unroll
                for (int j = 0; j < 8; ++j)
                    cl[ks2][j] = __shfl(cellLocal, ks2 * 32 + quad * 8 + j);

            const int nMt2 = (ncellsW + 15) >> 4;
            _Float16* embT = &sEmb[wid][0];

            // ---- per 16-channel tile: MFMA1 -> epilogue -> embT -> MFMA2 -> store.
#pragma unroll 1
            for (int nt = 0; nt < 5; ++nt) {
                f32x4_t acc[4];
#pragma unroll
                for (int mt = 0; mt < 4; ++mt) acc[mt] = (f32x4_t){0.0f, 0.0f, 0.0f, 0.0f};

#pragma unroll
                for (int ks = 0; ks < 3; ++ks) {
                    const half8_t Bf = *(const half8_t*)
                        &sW2T[(nt * 16 + m15) * HSTR + ks * 32 + quad * 8];
#pragma unroll
                    for (int mt = 0; mt < 4; ++mt)
                        acc[mt] = __builtin_amdgcn_mfma_f32_16x16x32_f16(
                            Af[ks][mt], Bf, acc[mt], 0, 0, 0);
                }

                // bias + relu -> embT slice [ch16=m15][pt].
                const float bb2 = sb2f[nt * 16 + m15];
#pragma unroll
                for (int mt = 0; mt < 4; ++mt) {
                    const f32x4_t a = acc[mt];
                    half4_t v;
                    v[0] = (_Float16)fmaxf(a[0] + bb2, 0.0f);
                    v[1] = (_Float16)fmaxf(a[1] + bb2, 0.0f);
                    v[2] = (_Float16)fmaxf(a[2] + bb2, 0.0f);
                    v[3] = (_Float16)fmaxf(a[3] + bb2, 0.0f);
                    *(half4_t*)&embT[m15 * ESTR + mt * 16 + quad * 4] = v;
                }

                half8_t B2[2];
#pragma unroll
                for (int ks2 = 0; ks2 < 2; ++ks2)
                    B2[ks2] = *(const half8_t*)&embT[m15 * ESTR + ks2 * 32 + quad * 8];

                float* const plane = sums + (size_t)nt * (size_t)P;
                for (int mt2 = 0; mt2 < nMt2; ++mt2) {
                    const int m2 = mt2 * 16 + m15;
                    f32x4_t acc2 = (f32x4_t){0.0f, 0.0f, 0.0f, 0.0f};
#pragma unroll
                    for (int ks2 = 0; ks2 < 2; ++ks2) {
                        half8_t A2;
#pragma unroll
                        for (int j = 0; j < 8; ++j)
                            A2[j] = (cl[ks2][j] == m2) ? (_Float16)1 : (_Float16)0;
                        acc2 = __builtin_amdgcn_mfma_f32_16x16x32_f16(
                            A2, B2[ks2], acc2, 0, 0, 0);
                    }
#pragma unroll
                    for (int r = 0; r < 4; ++r) {
                        const int cell = mt2 * 16 + quad * 4 + r;
                        if (cell < ncellsW) {
                            const unsigned int row = sCellG[wid][cell];
                            plane[((size_t)row << 4) + m15] = acc2[r];
                        }
                    }
                }
            }

            if (!hasNext) break;
            wv = wvn; pr = prN; c16 = c16N;
        }
    }
}

// ---------------------------------------------------------------------------
// Head: mean -> 1x1 conv -> BN -> relu -> out (fp32). Mean staged f16.
// Folds staged head-partials (plane rows ncells+b for b in the cell's chunk
// span) and gates on cnt>0 (sums is NOT pre-zeroed).
// ---------------------------------------------------------------------------
#define MPAD 84

__global__ __launch_bounds__(256) void k_head(
    const float* __restrict__ sums,
    const unsigned int* __restrict__ cnt,
    const unsigned int* __restrict__ offs,
    const void* __restrict__ Wp_raw,
    const void* __restrict__ bp_raw,
    const void* __restrict__ gamma_raw,
    const void* __restrict__ beta_raw,
    const void* __restrict__ rmean_raw,
    const void* __restrict__ rvar_raw,
    const unsigned int* __restrict__ flags,
    float* __restrict__ out,
    int b0, int ncells, int P)
{
    __shared__ float sWp[CH * COUT_];
    __shared__ _Float16 sMean[BEVW * MPAD];
    __shared__ float sAlpha[COUT_], sDelta[COUT_];

    const int t = threadIdx.x;
    const int blk = blockIdx.x;
    const int bl = blk >> 7, hrow = blk & 127;
    const int bg = b0 + bl;
    const int wf32 = (int)flags[0];

    if (wf32) {
        const float* Wp = (const float*)Wp_raw;
        for (int i = t; i < CH * COUT_; i += 256) sWp[i] = Wp[i];
        if (t < COUT_) {
            const float rs = rsqrtf(((const float*)rvar_raw)[t] + 1e-5f);
            const float al = ((const float*)gamma_raw)[t] * rs;
            sAlpha[t] = al;
            sDelta[t] = al * (((const float*)bp_raw)[t] - ((const float*)rmean_raw)[t])
                        + ((const float*)beta_raw)[t];
        }
    } else {
        const unsigned short* Wp = (const unsigned short*)Wp_raw;
        for (int i = t; i < CH * COUT_; i += 256) sWp[i] = bf2f(Wp[i]);
        if (t < COUT_) {
            const float rs = rsqrtf(bf2f(((const unsigned short*)rvar_raw)[t]) + 1e-5f);
            const float al = bf2f(((const unsigned short*)gamma_raw)[t]) * rs;
            sAlpha[t] = al;
            sDelta[t] = al * (bf2f(((const unsigned short*)bp_raw)[t])
                              - bf2f(((const unsigned short*)rmean_raw)[t]))
                        + bf2f(((const unsigned short*)beta_raw)[t]);
        }
    }

    const int cellbase = bl * HW_ + hrow * BEVW;
    for (int i = t; i < BEVW * 20; i += 256) {
        const int w = i / 20, c4 = i % 20;
        const int nt = c4 >> 2, q = c4 & 3;
        const int cell = cellbase + w;
        const unsigned int c = cnt[cell];
        float4 s = {0.0f, 0.0f, 0.0f, 0.0f};
        if (c > 0) {
            const float4* plane4 = (const float4*)(sums + (size_t)nt * (size_t)P);
            s = plane4[cell * 4 + q];
            const unsigned int o = offs[cell];
            const int bA = (int)(o >> 6) + 1;
            const int bB = (int)((o + c - 1) >> 6);
            for (int b = bA; b <= bB; ++b) {
                const float4 st = plane4[(ncells + b) * 4 + q];
                s.x += st.x; s.y += st.y; s.z += st.z; s.w += st.w;
            }
        }
        const float inv = 1.0f / fmaxf((float)c, 1.0f);
        _Float16* m = &sMean[w * MPAD + c4 * 4];
        m[0] = (_Float16)(s.x * inv);
        m[1] = (_Float16)(s.y * inv);
        m[2] = (_Float16)(s.z * inv);
        m[3] = (_Float16)(s.w * inv);
    }
    __syncthreads();

    const int v = t >> 6;
    const int w = (t & 63) + (v & 1) * 64;
    const int dbase = (v >> 1) * 64;

    float acc[64];
#pragma unroll
    for (int j = 0; j < 64; ++j) acc[j] = 0.0f;

    const _Float16* mrow = &sMean[w * MPAD];
#pragma unroll 2
    for (int c = 0; c < CH; ++c) {
        const float m = (float)mrow[c];
        const float4* wrow = (const float4*)&sWp[c * COUT_ + dbase];
#pragma unroll
        for (int j4 = 0; j4 < 16; ++j4) {
            const float4 wv = wrow[j4];
            acc[j4 * 4 + 0] = fmaf(m, wv.x, acc[j4 * 4 + 0]);
            acc[j4 * 4 + 1] = fmaf(m, wv.y, acc[j4 * 4 + 1]);
            acc[j4 * 4 + 2] = fmaf(m, wv.z, acc[j4 * 4 + 2]);
            acc[j4 * 4 + 3] = fmaf(m, wv.w, acc[j4 * 4 + 3]);
        }
    }

#pragma unroll
    for (int j = 0; j < 64; ++j) {
        const int d = dbase + j;
        float o = fmaxf(fmaf(acc[j], sAlpha[d], sDelta[d]), 0.0f);
        o = fminf(o, 512.0f);
        out[(((size_t)bg * COUT_ + d) * BEVH + hrow) * BEVW + w] = o;
    }
}

// ---------------------------------------------------------------------------
// Diagnostics beacon (insurance; healthy run writes nothing).
// ---------------------------------------------------------------------------
__global__ __launch_bounds__(256) void k_diag(
    const unsigned int* __restrict__ cnt,
    const float* __restrict__ sums,
    const unsigned int* __restrict__ magic,
    const unsigned int* __restrict__ flags,
    float* __restrict__ out,
    int hostbits)
{
    __shared__ float red[256];
    __shared__ unsigned int credu[256];
    const int t = threadIdx.x;

    unsigned int cs = 0;
    for (int i = t; i < HW_; i += 256) cs += cnt[i];
    credu[t] = cs;

    float sl = 0.0f;
    for (int i = t; i < CH * CH; i += 256) sl += fabsf(sums[i]);
    red[t] = sl;
    __syncthreads();

    for (int s = 128; s > 0; s >>= 1) {
        if (t < s) { red[t] += red[t + s]; credu[t] += credu[t + s]; }
        __syncthreads();
    }

    if (t == 0) {
        int code = hostbits;
        if (*magic != 0xCAFEBABEu) code |= 1;
        if (credu[0] < 1000u)      code |= 2;
        if (!(red[0] > 0.0f))      code |= 4;
        if (code) {
            code |= (int)(flags[0] ? 32 : 0);
            code |= (int)(flags[1] ? 64 : 0);
            out[0] = 1024.0f * (float)code;
        }
    }
}

extern "C" void kernel_launch(void* const* d_in, const int* in_sizes, int n_in,
                              void* d_out, int out_size, void* d_ws, size_t ws_size,
                              hipStream_t stream) {
    const void* pts   = d_in[0];
    const void* W1    = d_in[1];
    const void* b1    = d_in[2];
    const void* W2    = d_in[3];
    const void* b2    = d_in[4];
    const void* Wp    = d_in[5];
    const void* bp    = d_in[6];
    const void* gamma = d_in[7];
    const void* beta  = d_in[8];
    const void* rmean = d_in[9];
    const void* rvar  = d_in[10];

    int hostbits = 0;
    if (n_in != 11 ||
        in_sizes[0] != B_ * NP_ * 4 ||
        in_sizes[1] != 4 * CH  || in_sizes[2] != CH ||
        in_sizes[3] != CH * CH || in_sizes[4] != CH ||
        in_sizes[5] != CH * COUT_ || in_sizes[6] != COUT_ ||
        out_size != B_ * COUT_ * HW_)
        hostbits |= 8;
    if (ws_size < SCRATCH_OFF + PER_BATCH + EXTRA_BYTES) hostbits |= 16;

    unsigned int* flags = (unsigned int*)d_ws;
    unsigned int* magic = (unsigned int*)((char*)d_ws + MAGIC_OFF);
    char* base = (char*)d_ws + SCRATCH_OFF;
    const size_t avail = (ws_size > SCRATCH_OFF + EXTRA_BYTES)
                       ? (ws_size - SCRATCH_OFF - EXTRA_BYTES) : PER_BATCH;
    int nb = (int)(avail / PER_BATCH);
    if (nb < 1) nb = 1;
    if (nb > B_) nb = B_;

    // Layout: cnt | sums (5 planes, incl. staging rows) | offs(+4) | cursor |
    //         psorted8 (8B-aligned) | scell16 | bsums
    unsigned int*   cnt      = (unsigned int*)base;
    float*          sums     = (float*)(cnt + (size_t)nb * HW_);
    const size_t    sumsFl   = (size_t)5 * ((size_t)nb * HW_ + (size_t)nb * NCHK) * 16;
    unsigned int*   offs     = (unsigned int*)(sums + sumsFl);
    unsigned int*   cursor   = offs + (size_t)nb * HW_ + 4;
    ushort4*        psorted8 = (ushort4*)(cursor + (size_t)nb * HW_);
    unsigned short* scell16  = (unsigned short*)(psorted8 + (size_t)nb * NP_);
    unsigned int*   bsums    = (unsigned int*)(scell16 + (size_t)nb * NP_);

    k_detect<<<2, 64, 0, stream>>>((const unsigned short*)W1,
                                   (const unsigned short*)pts, flags);

    for (int b0 = 0; b0 < B_; b0 += nb) {
        const int bcnt = (B_ - b0 < nb) ? (B_ - b0) : nb;
        const int ncells = bcnt * HW_;
        const int npts   = bcnt * NP_;
        const int nblk   = ncells >> 10;      // 1024 cells per scan block
        const int P      = (ncells + bcnt * NCHK) * 16;   // plane stride (f32)

        // Zero cnt + the first CH*CH sums floats (k_diag window). Occupied
        // sums rows are fully owner-written; k_head gates on cnt>0; staging
        // rows are only read when their write-condition held.
        k_zero<<<128, 256, 0, stream>>>((float4*)cnt, ncells / 4 + 1600);

        k_bin<<<(npts + 255) / 256, 256, 0, stream>>>(
            pts, flags, cnt, b0, npts);

        k_scan_part<<<nblk, 256, 0, stream>>>(cnt, bsums);
        k_scan_apply<<<nblk, 256, 0, stream>>>(cnt, bsums, offs, cursor,
                                               nblk, ncells);

        k_scatteridx<<<(npts + 255) / 256, 256, 0, stream>>>(
            pts, flags, cursor, psorted8, scell16, b0, npts);

        k_mlp_mfma<<<1280, 256, 0, stream>>>(
            psorted8, scell16, W1, b1, W2, b2, flags, magic, offs, sums,
            ncells, P);

        k_head<<<bcnt * BEVH, 256, 0, stream>>>(
            sums, cnt, offs, Wp, bp, gamma, beta, rmean, rvar, flags,
            (float*)d_out, b0, ncells, P);
    }

    k_diag<<<1, 256, 0, stream>>>(cnt, sums, magic, flags,
                                  (float*)d_out, hostbits);
}

// Round 4
// 264.262 us; speedup vs baseline: 1.1369x; 1.1369x over previous
//
#include <hip/hip_runtime.h>
#include <hip/hip_bf16.h>

// PointsToBEV round 18b (resubmit: R18 bench died on container infra, no
// data). R17 post-mortem: plane-major stores did NOT move WRITE (100->126MB,
// worse with prefetch regs) -> the ~85MB/85MB symmetric mystery traffic was
// never store RMW, it is SCRATCH SPILL. VGPR_Count=64 all along:
// __launch_bounds__(256,4) caps unified VGPR+AGPR at 128/wave, compiler
// split 64+64, and the live set (Af=48 VGPRs + pm + prefetch) spills
// ~38 dwords/lane/chunk = ~100MB each way. Fix: launch_bounds(256,2)
// -> 256-reg budget, zero spills; grid 1024. Keep R17's plane-major sums,
// 8B packed points, folded fixup, minimal zero.

#define B_    4
#define NP_   200000
#define CH    80
#define COUT_ 128
#define BEVH  128
#define BEVW  128
#define HW_   (BEVH * BEVW)
#define NCHK  (NP_ / 64)        // 3125 chunks per batch (NP_ % 64 == 0)

// Per-batch bytes: cnt(HW u32) + sums+staging((HW+NCHK)*80 f32) +
// offs(HW u32 +pad) + cursor(HW u32) + psorted8(NP*8) + scell16(NP*2)
#define PER_BATCH ((size_t)HW_ * 332 + (size_t)NCHK * 320 + (size_t)NP_ * 10)
#define EXTRA_BYTES 512

#define MAGIC_OFF   128
#define SCRATCH_OFF 256

typedef _Float16 half4_t __attribute__((ext_vector_type(4)));
typedef _Float16 half8_t __attribute__((ext_vector_type(8)));
typedef float    f32x4_t __attribute__((ext_vector_type(4)));

#define HSTR 104   // W2T k-stride in f16 (52 dwords -> 2-way banks, free)
#define ESTR 72    // embT pt-stride in f16 (36 dwords -> 2-way banks, free)

__device__ __forceinline__ float bf2f(unsigned short u) {
    return __uint_as_float(((unsigned int)u) << 16);
}
__device__ __forceinline__ unsigned short f2h(float f) {
    return __builtin_bit_cast(unsigned short, (_Float16)f);
}
__device__ __forceinline__ float h2f(unsigned short u) {
    return (float)__builtin_bit_cast(_Float16, u);
}

// ---------------------------------------------------------------------------
// dtype probes: flags[0]=params fp32, flags[1]=points fp32.
// ---------------------------------------------------------------------------
__global__ void k_detect(const unsigned short* __restrict__ w1bits,
                         const unsigned short* __restrict__ ptsbits,
                         unsigned int* __restrict__ flags) {
    const int t = threadIdx.x;
    const int which = blockIdx.x;
    const unsigned short* src = which ? ptsbits : w1bits;
    const int n = which ? 512 : 320;
    float m = 0.0f;
    for (int i = t; i < n; i += 64) {
        const float a = fabsf(bf2f(src[i]));
        if (a == a) m = fmaxf(m, a);
    }
#pragma unroll
    for (int off = 32; off > 0; off >>= 1)
        m = fmaxf(m, __shfl_down(m, off));
    if (t == 0) flags[which] = (m > 1.0e6f) ? 1u : 0u;
}

__global__ __launch_bounds__(256) void k_zero(float4* __restrict__ p, int n4) {
    const float4 z = {0.0f, 0.0f, 0.0f, 0.0f};
    for (int i = blockIdx.x * 256 + threadIdx.x; i < n4; i += gridDim.x * 256)
        p[i] = z;
}

__device__ __forceinline__ int cell_of(float px, float py, int bloc) {
    const int ix = (int)floorf((px + 50.0f) / 0.78125f);
    const int iy = (int)floorf((py + 50.0f) / 0.78125f);
    if (ix < 0 || ix >= BEVW || iy < 0 || iy >= BEVH) return -1;
    return bloc * HW_ + iy * BEVW + ix;
}

__device__ __forceinline__ void load_pt(const void* pts_raw, size_t pidx, int pf32,
                                        float& px, float& py, float& pz, float& pw) {
    if (pf32) {
        const float4 p = ((const float4*)pts_raw)[pidx];
        px = p.x; py = p.y; pz = p.z; pw = p.w;
    } else {
        const ushort4 p = ((const ushort4*)pts_raw)[pidx];
        px = bf2f(p.x); py = bf2f(p.y); pz = bf2f(p.z); pw = bf2f(p.w);
    }
}

// ---------------------------------------------------------------------------
// Phase A: histogram.
// ---------------------------------------------------------------------------
__global__ __launch_bounds__(256) void k_bin(
    const void* __restrict__ pts_raw,
    const unsigned int* __restrict__ flags,
    unsigned int* __restrict__ cnt,
    int b0, int npts)
{
    const int gid = blockIdx.x * 256 + threadIdx.x;
    if (gid >= npts) return;
    float px, py, pz, pw;
    load_pt(pts_raw, (size_t)b0 * NP_ + gid, (int)flags[1], px, py, pz, pw);
    const int g = cell_of(px, py, gid / NP_);
    if (g >= 0) atomicAdd(&cnt[g], 1u);
}

// ---------------------------------------------------------------------------
// Phase B1: per-block (1024 cells) sums.
// ---------------------------------------------------------------------------
__global__ __launch_bounds__(256) void k_scan_part(
    const unsigned int* __restrict__ cnt,
    unsigned int* __restrict__ bsums)
{
    __shared__ unsigned int sd[256];
    const int t = threadIdx.x;
    const int i0 = blockIdx.x * 1024 + t * 4;
    unsigned int s = cnt[i0] + cnt[i0 + 1] + cnt[i0 + 2] + cnt[i0 + 3];
    sd[t] = s;
    __syncthreads();
    for (int d = 128; d > 0; d >>= 1) {
        if (t < d) sd[t] += sd[t + d];
        __syncthreads();
    }
    if (t == 0) bsums[blockIdx.x] = sd[0];
}

// ---------------------------------------------------------------------------
// Phase B2: apply prefix -> offs (+sentinel) and cursor.
// ---------------------------------------------------------------------------
__global__ __launch_bounds__(256) void k_scan_apply(
    const unsigned int* __restrict__ cnt,
    const unsigned int* __restrict__ bsums,
    unsigned int* __restrict__ offs,
    unsigned int* __restrict__ cursor,
    int nblocks, int n)
{
    __shared__ unsigned int sd[256];
    __shared__ unsigned int sBase;
    const int t = threadIdx.x;
    const int blk = blockIdx.x;
    const int i0 = blk * 1024 + t * 4;
    unsigned int c0 = cnt[i0], c1 = cnt[i0 + 1], c2 = cnt[i0 + 2], c3 = cnt[i0 + 3];
    const unsigned int s4 = c0 + c1 + c2 + c3;
    sd[t] = s4;
    if (t == 0) {
        unsigned int b = 0;
        for (int j = 0; j < blk; ++j) b += bsums[j];
        sBase = b;
    }
    __syncthreads();
    for (int d = 1; d < 256; d <<= 1) {
        const unsigned int add = (t >= d) ? sd[t - d] : 0u;
        __syncthreads();
        sd[t] += add;
        __syncthreads();
    }
    unsigned int run = sBase + sd[t] - s4;    // exclusive prefix
    offs[i0] = run;     cursor[i0] = run;     run += c0;
    offs[i0 + 1] = run; cursor[i0 + 1] = run; run += c1;
    offs[i0 + 2] = run; cursor[i0 + 2] = run; run += c2;
    offs[i0 + 3] = run; cursor[i0 + 3] = run; run += c3;
    if (blk == nblocks - 1 && t == 255) offs[n] = run;
}

// ---------------------------------------------------------------------------
// Phase C: materialize the sort — packed 8B fp16 cell-delta + u16 cell.
// ---------------------------------------------------------------------------
__global__ __launch_bounds__(256) void k_scatteridx(
    const void* __restrict__ pts_raw,
    const unsigned int* __restrict__ flags,
    unsigned int* __restrict__ cursor,
    ushort4* __restrict__ psorted8,
    unsigned short* __restrict__ scell16,
    int b0, int npts)
{
    const int gid = blockIdx.x * 256 + threadIdx.x;
    if (gid >= npts) return;
    float px, py, pz, pw;
    load_pt(pts_raw, (size_t)b0 * NP_ + gid, (int)flags[1], px, py, pz, pw);
    const int g = cell_of(px, py, gid / NP_);
    if (g < 0) return;
    const unsigned int pos = atomicAdd(&cursor[g], 1u);
    const int cellin = g & (HW_ - 1);
    const float cx = fmaf((float)(cellin & 127), 0.78125f, -49.609375f);
    const float cy = fmaf((float)(cellin >> 7), 0.78125f, -49.609375f);
    ushort4 r;
    r.x = f2h(px - cx);
    r.y = f2h(py - cy);
    r.z = f2h(pz);
    r.w = f2h(pw);
    psorted8[pos] = r;
    scell16[pos] = (unsigned short)g;
}

// ---------------------------------------------------------------------------
// Phase D (persistent MFMA): waves grid-stride over 64-point chunks.
// Plane-major sums: element (row, ch = nt*16+m15) at sums[nt*P + row*16+m15].
// launch_bounds(256,2): 256-reg unified budget -> Af/pm/prefetch all live in
// registers, no scratch (R18 fix; R15-R17's ~90MB/way FETCH/WRITE was spill).
// ---------------------------------------------------------------------------
__global__ __launch_bounds__(256, 2) void k_mlp_mfma(
    const ushort4* __restrict__ psorted8,
    const unsigned short* __restrict__ scell16,
    const void* __restrict__ W1_raw,
    const void* __restrict__ b1_raw,
    const void* __restrict__ W2_raw,
    const void* __restrict__ b2_raw,
    const unsigned int* __restrict__ flags,
    unsigned int* __restrict__ magic,
    const unsigned int* __restrict__ offs,    // ncells+1 (sentinel = total)
    float* __restrict__ sums,                 // 5 planes of P floats
    int ncells, int P)
{
    __shared__ float sW1[4 * CH];             // [f][k]
    __shared__ float sb1[CH];
    __shared__ float sb2f[CH];
    __shared__ _Float16 sW2T[80 * HSTR];      // [ch_out][k], k 80..95 zero
    __shared__ _Float16 sEmb[4][16 * ESTR];   // per-wave embT slice [ch16][pt]
    __shared__ unsigned int sCellG[4][64];

    const int t = threadIdx.x;
    const int wf32 = (int)flags[0];

    if (wf32) {
        const float* W1 = (const float*)W1_raw;
        const float* b1 = (const float*)b1_raw;
        const float* b2 = (const float*)b2_raw;
        for (int i = t; i < 4 * CH; i += 256) sW1[i] = W1[i];
        if (t < CH) { sb1[t] = b1[t]; sb2f[t] = b2[t]; }
        const float* W2 = (const float*)W2_raw;
        for (int i = t; i < 80 * HSTR; i += 256) {
            const int row = i / HSTR, k = i % HSTR;
            sW2T[i] = (_Float16)((k < 80) ? W2[k * CH + row] : 0.0f);
        }
    } else {
        const unsigned short* W1 = (const unsigned short*)W1_raw;
        const unsigned short* b1 = (const unsigned short*)b1_raw;
        const unsigned short* b2 = (const unsigned short*)b2_raw;
        for (int i = t; i < 4 * CH; i += 256) sW1[i] = bf2f(W1[i]);
        if (t < CH) { sb1[t] = bf2f(b1[t]); sb2f[t] = bf2f(b2[t]); }
        const unsigned short* W2 = (const unsigned short*)W2_raw;
        for (int i = t; i < 80 * HSTR; i += 256) {
            const int row = i / HSTR, k = i % HSTR;
            sW2T[i] = (_Float16)((k < 80) ? bf2f(W2[k * CH + row]) : 0.0f);
        }
    }
    __syncthreads();

    if (blockIdx.x == 0 && t == 0) *magic = 0xCAFEBABEu;

    const int end = (int)offs[ncells];
    const int lane = t & 63;
    const int wid = t >> 6;
    const int m15 = lane & 15;
    const int quad = lane >> 4;
    const int totalWaves = gridDim.x * 4;
    const int nChunks = (end + 63) >> 6;

    int wv = blockIdx.x * 4 + wid;
    if (wv < nChunks) {
        // first-chunk loads (clamped so inactive lanes read a valid record)
        int pc = wv * 64 + lane; if (pc > end - 1) pc = end - 1;
        ushort4 pr = psorted8[pc];
        unsigned short c16 = scell16[pc];

        for (;;) {
            const int chunkStart = wv * 64;
            const int p = chunkStart + lane;
            const bool active = p < end;
            const int wvn = wv + totalWaves;
            const bool hasNext = wvn < nChunks;

            // ---- decode current record (always finite: clamped load).
            const int gi = (int)c16;
            const int cellin = gi & (HW_ - 1);
            const float cx = fmaf((float)(cellin & 127), 0.78125f, -49.609375f);
            const float cy = fmaf((float)(cellin >> 7), 0.78125f, -49.609375f);
            const float px = cx + h2f(pr.x);
            const float py = cy + h2f(pr.y);
            const float pz = h2f(pr.z);
            const float pw = h2f(pr.w);
            const int g = active ? gi : -1;

            // ---- segment bookkeeping (R13-verified).
            const int gprev = __shfl_up(g, 1);
            const bool isHead = active && (lane == 0 || gprev != g);
            const unsigned long long headmask = __ballot(isHead);
            const int cellLocal = active
                ? (__popcll(headmask << (63 - lane)) - 1) : 255;
            const int ncellsW = __popcll(headmask);
            if (isHead) {
                // Ownership: cell start within this chunk -> direct row g;
                // head cell that started earlier -> per-chunk staging row.
                unsigned int row = (unsigned int)g;
                if (cellLocal == 0) {
                    const unsigned int o = offs[g];
                    if (o < (unsigned int)chunkStart)
                        row = (unsigned int)(ncells + wv);
                }
                sCellG[wid][cellLocal] = row;
            }

            // ---- gather the 4 points this lane's A-fragments cover.
            float pmx[4], pmy[4], pmz[4], pmw[4];
#pragma unroll
            for (int mt = 0; mt < 4; ++mt) {
                const int src = mt * 16 + m15;
                pmx[mt] = __shfl(px, src);
                pmy[mt] = __shfl(py, src);
                pmz[mt] = __shfl(pz, src);
                pmw[mt] = __shfl(pw, src);
            }

            // ---- prefetch next chunk (latency hidden under nt loop).
            ushort4 prN = {0, 0, 0, 0};
            unsigned short c16N = 0;
            if (hasNext) {
                int pcn = wvn * 64 + lane; if (pcn > end - 1) pcn = end - 1;
                prN = psorted8[pcn];
                c16N = scell16[pcn];
            }

            // ---- layer 1 transposed: A-frag values born in registers.
            half8_t Af[3][4];
#pragma unroll
            for (int ks = 0; ks < 3; ++ks) {
                const int kb = ks * 32 + quad * 8;
                if (kb < 80) {
                    const float4 wa0 = *(const float4*)&sW1[0 * CH + kb];
                    const float4 wb0 = *(const float4*)&sW1[0 * CH + kb + 4];
                    const float4 wa1 = *(const float4*)&sW1[1 * CH + kb];
                    const float4 wb1 = *(const float4*)&sW1[1 * CH + kb + 4];
                    const float4 wa2 = *(const float4*)&sW1[2 * CH + kb];
                    const float4 wb2 = *(const float4*)&sW1[2 * CH + kb + 4];
                    const float4 wa3 = *(const float4*)&sW1[3 * CH + kb];
                    const float4 wb3 = *(const float4*)&sW1[3 * CH + kb + 4];
                    const float4 ba  = *(const float4*)&sb1[kb];
                    const float4 bb  = *(const float4*)&sb1[kb + 4];
                    float w0[8] = {wa0.x, wa0.y, wa0.z, wa0.w, wb0.x, wb0.y, wb0.z, wb0.w};
                    float w1[8] = {wa1.x, wa1.y, wa1.z, wa1.w, wb1.x, wb1.y, wb1.z, wb1.w};
                    float w2[8] = {wa2.x, wa2.y, wa2.z, wa2.w, wb2.x, wb2.y, wb2.z, wb2.w};
                    float w3[8] = {wa3.x, wa3.y, wa3.z, wa3.w, wb3.x, wb3.y, wb3.z, wb3.w};
                    float bv[8] = {ba.x, ba.y, ba.z, ba.w, bb.x, bb.y, bb.z, bb.w};
#pragma unroll
                    for (int mt = 0; mt < 4; ++mt) {
                        half8_t v;
#pragma unroll
                        for (int j = 0; j < 8; ++j) {
                            float hv = bv[j];
                            hv = fmaf(pmx[mt], w0[j], hv);
                            hv = fmaf(pmy[mt], w1[j], hv);
                            hv = fmaf(pmz[mt], w2[j], hv);
                            hv = fmaf(pmw[mt], w3[j], hv);
                            v[j] = (_Float16)fmaxf(hv, 0.0f);
                        }
                        Af[ks][mt] = v;
                    }
                } else {
                    const half8_t z8 = {0, 0, 0, 0, 0, 0, 0, 0};
#pragma unroll
                    for (int mt = 0; mt < 4; ++mt) Af[ks][mt] = z8;
                }
            }

            // ---- selector columns for MFMA2.
            int cl[2][8];
#pragma unroll
            for (int ks2 = 0; ks2 < 2; ++ks2)
#pragma unroll
                for (int j = 0; j < 8; ++j)
                    cl[ks2][j] = __shfl(cellLocal, ks2 * 32 + quad * 8 + j);

            const int nMt2 = (ncellsW + 15) >> 4;
            _Float16* embT = &sEmb[wid][0];

            // ---- per 16-channel tile: MFMA1 -> epilogue -> embT -> MFMA2 -> store.
#pragma unroll 1
            for (int nt = 0; nt < 5; ++nt) {
                f32x4_t acc[4];
#pragma unroll
                for (int mt = 0; mt < 4; ++mt) acc[mt] = (f32x4_t){0.0f, 0.0f, 0.0f, 0.0f};

#pragma unroll
                for (int ks = 0; ks < 3; ++ks) {
                    const half8_t Bf = *(const half8_t*)
                        &sW2T[(nt * 16 + m15) * HSTR + ks * 32 + quad * 8];
#pragma unroll
                    for (int mt = 0; mt < 4; ++mt)
                        acc[mt] = __builtin_amdgcn_mfma_f32_16x16x32_f16(
                            Af[ks][mt], Bf, acc[mt], 0, 0, 0);
                }

                // bias + relu -> embT slice [ch16=m15][pt].
                const float bb2 = sb2f[nt * 16 + m15];
#pragma unroll
                for (int mt = 0; mt < 4; ++mt) {
                    const f32x4_t a = acc[mt];
                    half4_t v;
                    v[0] = (_Float16)fmaxf(a[0] + bb2, 0.0f);
                    v[1] = (_Float16)fmaxf(a[1] + bb2, 0.0f);
                    v[2] = (_Float16)fmaxf(a[2] + bb2, 0.0f);
                    v[3] = (_Float16)fmaxf(a[3] + bb2, 0.0f);
                    *(half4_t*)&embT[m15 * ESTR + mt * 16 + quad * 4] = v;
                }

                half8_t B2[2];
#pragma unroll
                for (int ks2 = 0; ks2 < 2; ++ks2)
                    B2[ks2] = *(const half8_t*)&embT[m15 * ESTR + ks2 * 32 + quad * 8];

                float* const plane = sums + (size_t)nt * (size_t)P;
                for (int mt2 = 0; mt2 < nMt2; ++mt2) {
                    const int m2 = mt2 * 16 + m15;
                    f32x4_t acc2 = (f32x4_t){0.0f, 0.0f, 0.0f, 0.0f};
#pragma unroll
                    for (int ks2 = 0; ks2 < 2; ++ks2) {
                        half8_t A2;
#pragma unroll
                        for (int j = 0; j < 8; ++j)
                            A2[j] = (cl[ks2][j] == m2) ? (_Float16)1 : (_Float16)0;
                        acc2 = __builtin_amdgcn_mfma_f32_16x16x32_f16(
                            A2, B2[ks2], acc2, 0, 0, 0);
                    }
#pragma unroll
                    for (int r = 0; r < 4; ++r) {
                        const int cell = mt2 * 16 + quad * 4 + r;
                        if (cell < ncellsW) {
                            const unsigned int row = sCellG[wid][cell];
                            plane[((size_t)row << 4) + m15] = acc2[r];
                        }
                    }
                }
            }

            if (!hasNext) break;
            wv = wvn; pr = prN; c16 = c16N;
        }
    }
}

// ---------------------------------------------------------------------------
// Head: mean -> 1x1 conv -> BN -> relu -> out (fp32). Mean staged f16.
// Folds staged head-partials (plane rows ncells+b for b in the cell's chunk
// span) and gates on cnt>0 (sums is NOT pre-zeroed).
// ---------------------------------------------------------------------------
#define MPAD 84

__global__ __launch_bounds__(256) void k_head(
    const float* __restrict__ sums,
    const unsigned int* __restrict__ cnt,
    const unsigned int* __restrict__ offs,
    const void* __restrict__ Wp_raw,
    const void* __restrict__ bp_raw,
    const void* __restrict__ gamma_raw,
    const void* __restrict__ beta_raw,
    const void* __restrict__ rmean_raw,
    const void* __restrict__ rvar_raw,
    const unsigned int* __restrict__ flags,
    float* __restrict__ out,
    int b0, int ncells, int P)
{
    __shared__ float sWp[CH * COUT_];
    __shared__ _Float16 sMean[BEVW * MPAD];
    __shared__ float sAlpha[COUT_], sDelta[COUT_];

    const int t = threadIdx.x;
    const int blk = blockIdx.x;
    const int bl = blk >> 7, hrow = blk & 127;
    const int bg = b0 + bl;
    const int wf32 = (int)flags[0];

    if (wf32) {
        const float* Wp = (const float*)Wp_raw;
        for (int i = t; i < CH * COUT_; i += 256) sWp[i] = Wp[i];
        if (t < COUT_) {
            const float rs = rsqrtf(((const float*)rvar_raw)[t] + 1e-5f);
            const float al = ((const float*)gamma_raw)[t] * rs;
            sAlpha[t] = al;
            sDelta[t] = al * (((const float*)bp_raw)[t] - ((const float*)rmean_raw)[t])
                        + ((const float*)beta_raw)[t];
        }
    } else {
        const unsigned short* Wp = (const unsigned short*)Wp_raw;
        for (int i = t; i < CH * COUT_; i += 256) sWp[i] = bf2f(Wp[i]);
        if (t < COUT_) {
            const float rs = rsqrtf(bf2f(((const unsigned short*)rvar_raw)[t]) + 1e-5f);
            const float al = bf2f(((const unsigned short*)gamma_raw)[t]) * rs;
            sAlpha[t] = al;
            sDelta[t] = al * (bf2f(((const unsigned short*)bp_raw)[t])
                              - bf2f(((const unsigned short*)rmean_raw)[t]))
                        + bf2f(((const unsigned short*)beta_raw)[t]);
        }
    }

    const int cellbase = bl * HW_ + hrow * BEVW;
    for (int i = t; i < BEVW * 20; i += 256) {
        const int w = i / 20, c4 = i % 20;
        const int nt = c4 >> 2, q = c4 & 3;
        const int cell = cellbase + w;
        const unsigned int c = cnt[cell];
        float4 s = {0.0f, 0.0f, 0.0f, 0.0f};
        if (c > 0) {
            const float4* plane4 = (const float4*)(sums + (size_t)nt * (size_t)P);
            s = plane4[cell * 4 + q];
            const unsigned int o = offs[cell];
            const int bA = (int)(o >> 6) + 1;
            const int bB = (int)((o + c - 1) >> 6);
            for (int b = bA; b <= bB; ++b) {
                const float4 st = plane4[(ncells + b) * 4 + q];
                s.x += st.x; s.y += st.y; s.z += st.z; s.w += st.w;
            }
        }
        const float inv = 1.0f / fmaxf((float)c, 1.0f);
        _Float16* m = &sMean[w * MPAD + c4 * 4];
        m[0] = (_Float16)(s.x * inv);
        m[1] = (_Float16)(s.y * inv);
        m[2] = (_Float16)(s.z * inv);
        m[3] = (_Float16)(s.w * inv);
    }
    __syncthreads();

    const int v = t >> 6;
    const int w = (t & 63) + (v & 1) * 64;
    const int dbase = (v >> 1) * 64;

    float acc[64];
#pragma unroll
    for (int j = 0; j < 64; ++j) acc[j] = 0.0f;

    const _Float16* mrow = &sMean[w * MPAD];
#pragma unroll 2
    for (int c = 0; c < CH; ++c) {
        const float m = (float)mrow[c];
        const float4* wrow = (const float4*)&sWp[c * COUT_ + dbase];
#pragma unroll
        for (int j4 = 0; j4 < 16; ++j4) {
            const float4 wv = wrow[j4];
            acc[j4 * 4 + 0] = fmaf(m, wv.x, acc[j4 * 4 + 0]);
            acc[j4 * 4 + 1] = fmaf(m, wv.y, acc[j4 * 4 + 1]);
            acc[j4 * 4 + 2] = fmaf(m, wv.z, acc[j4 * 4 + 2]);
            acc[j4 * 4 + 3] = fmaf(m, wv.w, acc[j4 * 4 + 3]);
        }
    }

#pragma unroll
    for (int j = 0; j < 64; ++j) {
        const int d = dbase + j;
        float o = fmaxf(fmaf(acc[j], sAlpha[d], sDelta[d]), 0.0f);
        o = fminf(o, 512.0f);
        out[(((size_t)bg * COUT_ + d) * BEVH + hrow) * BEVW + w] = o;
    }
}

// ---------------------------------------------------------------------------
// Diagnostics beacon (insurance; healthy run writes nothing).
// ---------------------------------------------------------------------------
__global__ __launch_bounds__(256) void k_diag(
    const unsigned int* __restrict__ cnt,
    const float* __restrict__ sums,
    const unsigned int* __restrict__ magic,
    const unsigned int* __restrict__ flags,
    float* __restrict__ out,
    int hostbits)
{
    __shared__ float red[256];
    __shared__ unsigned int credu[256];
    const int t = threadIdx.x;

    unsigned int cs = 0;
    for (int i = t; i < HW_; i += 256) cs += cnt[i];
    credu[t] = cs;

    float sl = 0.0f;
    for (int i = t; i < CH * CH; i += 256) sl += fabsf(sums[i]);
    red[t] = sl;
    __syncthreads();

    for (int s = 128; s > 0; s >>= 1) {
        if (t < s) { red[t] += red[t + s]; credu[t] += credu[t + s]; }
        __syncthreads();
    }

    if (t == 0) {
        int code = hostbits;
        if (*magic != 0xCAFEBABEu) code |= 1;
        if (credu[0] < 1000u)      code |= 2;
        if (!(red[0] > 0.0f))      code |= 4;
        if (code) {
            code |= (int)(flags[0] ? 32 : 0);
            code |= (int)(flags[1] ? 64 : 0);
            out[0] = 1024.0f * (float)code;
        }
    }
}

extern "C" void kernel_launch(void* const* d_in, const int* in_sizes, int n_in,
                              void* d_out, int out_size, void* d_ws, size_t ws_size,
                              hipStream_t stream) {
    const void* pts   = d_in[0];
    const void* W1    = d_in[1];
    const void* b1    = d_in[2];
    const void* W2    = d_in[3];
    const void* b2    = d_in[4];
    const void* Wp    = d_in[5];
    const void* bp    = d_in[6];
    const void* gamma = d_in[7];
    const void* beta  = d_in[8];
    const void* rmean = d_in[9];
    const void* rvar  = d_in[10];

    int hostbits = 0;
    if (n_in != 11 ||
        in_sizes[0] != B_ * NP_ * 4 ||
        in_sizes[1] != 4 * CH  || in_sizes[2] != CH ||
        in_sizes[3] != CH * CH || in_sizes[4] != CH ||
        in_sizes[5] != CH * COUT_ || in_sizes[6] != COUT_ ||
        out_size != B_ * COUT_ * HW_)
        hostbits |= 8;
    if (ws_size < SCRATCH_OFF + PER_BATCH + EXTRA_BYTES) hostbits |= 16;

    unsigned int* flags = (unsigned int*)d_ws;
    unsigned int* magic = (unsigned int*)((char*)d_ws + MAGIC_OFF);
    char* base = (char*)d_ws + SCRATCH_OFF;
    const size_t avail = (ws_size > SCRATCH_OFF + EXTRA_BYTES)
                       ? (ws_size - SCRATCH_OFF - EXTRA_BYTES) : PER_BATCH;
    int nb = (int)(avail / PER_BATCH);
    if (nb < 1) nb = 1;
    if (nb > B_) nb = B_;

    // Layout: cnt | sums (5 planes, incl. staging rows) | offs(+4) | cursor |
    //         psorted8 (8B-aligned) | scell16 | bsums
    unsigned int*   cnt      = (unsigned int*)base;
    float*          sums     = (float*)(cnt + (size_t)nb * HW_);
    const size_t    sumsFl   = (size_t)5 * ((size_t)nb * HW_ + (size_t)nb * NCHK) * 16;
    unsigned int*   offs     = (unsigned int*)(sums + sumsFl);
    unsigned int*   cursor   = offs + (size_t)nb * HW_ + 4;
    ushort4*        psorted8 = (ushort4*)(cursor + (size_t)nb * HW_);
    unsigned short* scell16  = (unsigned short*)(psorted8 + (size_t)nb * NP_);
    unsigned int*   bsums    = (unsigned int*)(scell16 + (size_t)nb * NP_);

    k_detect<<<2, 64, 0, stream>>>((const unsigned short*)W1,
                                   (const unsigned short*)pts, flags);

    for (int b0 = 0; b0 < B_; b0 += nb) {
        const int bcnt = (B_ - b0 < nb) ? (B_ - b0) : nb;
        const int ncells = bcnt * HW_;
        const int npts   = bcnt * NP_;
        const int nblk   = ncells >> 10;      // 1024 cells per scan block
        const int P      = (ncells + bcnt * NCHK) * 16;   // plane stride (f32)

        // Zero cnt + the first CH*CH sums floats (k_diag window). Occupied
        // sums rows are fully owner-written; k_head gates on cnt>0; staging
        // rows are only read when their write-condition held.
        k_zero<<<128, 256, 0, stream>>>((float4*)cnt, ncells / 4 + 1600);

        k_bin<<<(npts + 255) / 256, 256, 0, stream>>>(
            pts, flags, cnt, b0, npts);

        k_scan_part<<<nblk, 256, 0, stream>>>(cnt, bsums);
        k_scan_apply<<<nblk, 256, 0, stream>>>(cnt, bsums, offs, cursor,
                                               nblk, ncells);

        k_scatteridx<<<(npts + 255) / 256, 256, 0, stream>>>(
            pts, flags, cursor, psorted8, scell16, b0, npts);

        k_mlp_mfma<<<1024, 256, 0, stream>>>(
            psorted8, scell16, W1, b1, W2, b2, flags, magic, offs, sums,
            ncells, P);

        k_head<<<bcnt * BEVH, 256, 0, stream>>>(
            sums, cnt, offs, Wp, bp, gamma, beta, rmean, rvar, flags,
            (float*)d_out, b0, ncells, P);
    }

    k_diag<<<1, 256, 0, stream>>>(cnt, sums, magic, flags,
                                  (float*)d_out, hostbits);
}

// Round 5
// 256.040 us; speedup vs baseline: 1.1734x; 1.0321x over previous
//
#include <hip/hip_runtime.h>
#include <hip/hip_bf16.h>

// PointsToBEV round 19. R18 confirmed the spill theory: (256,2) -> VGPR 108,
// FETCH 99->4MB, WRITE 126->23MB, dur 85->53us. k_mlp now VALU/latency-bound
// (VALUBusy 40%, MfmaUtil 8%, HBM 6.6%). R19 attacks VALU count + stall
// chains: (1) coalesced W2T staging (was stride-160B uncoalesced L2 reads);
// (2) direct 4-point gather loads replace own-load + 16 shfl chain, register
// prefetch dropped (frees ~15 VGPR); (3) nMt2==1 fast path hoists the A2
// selector (nt-invariant, ~128 VALU/chunk) and sCellG row lookups out of the
// nt loop. Grid 1280 (5 blocks/CU if VGPR<=102).

#define B_    4
#define NP_   200000
#define CH    80
#define COUT_ 128
#define BEVH  128
#define BEVW  128
#define HW_   (BEVH * BEVW)
#define NCHK  (NP_ / 64)        // 3125 chunks per batch (NP_ % 64 == 0)

// Per-batch bytes: cnt(HW u32) + sums+staging((HW+NCHK)*80 f32) +
// offs(HW u32 +pad) + cursor(HW u32) + psorted8(NP*8) + scell16(NP*2)
#define PER_BATCH ((size_t)HW_ * 332 + (size_t)NCHK * 320 + (size_t)NP_ * 10)
#define EXTRA_BYTES 512

#define MAGIC_OFF   128
#define SCRATCH_OFF 256

typedef _Float16 half4_t __attribute__((ext_vector_type(4)));
typedef _Float16 half8_t __attribute__((ext_vector_type(8)));
typedef float    f32x4_t __attribute__((ext_vector_type(4)));

#define HSTR 104   // W2T k-stride in f16 (52 dwords -> 2-way banks, free)
#define ESTR 72    // embT pt-stride in f16 (36 dwords -> 2-way banks, free)

__device__ __forceinline__ float bf2f(unsigned short u) {
    return __uint_as_float(((unsigned int)u) << 16);
}
__device__ __forceinline__ unsigned short f2h(float f) {
    return __builtin_bit_cast(unsigned short, (_Float16)f);
}
__device__ __forceinline__ float h2f(unsigned short u) {
    return (float)__builtin_bit_cast(_Float16, u);
}

// ---------------------------------------------------------------------------
// dtype probes: flags[0]=params fp32, flags[1]=points fp32.
// ---------------------------------------------------------------------------
__global__ void k_detect(const unsigned short* __restrict__ w1bits,
                         const unsigned short* __restrict__ ptsbits,
                         unsigned int* __restrict__ flags) {
    const int t = threadIdx.x;
    const int which = blockIdx.x;
    const unsigned short* src = which ? ptsbits : w1bits;
    const int n = which ? 512 : 320;
    float m = 0.0f;
    for (int i = t; i < n; i += 64) {
        const float a = fabsf(bf2f(src[i]));
        if (a == a) m = fmaxf(m, a);
    }
#pragma unroll
    for (int off = 32; off > 0; off >>= 1)
        m = fmaxf(m, __shfl_down(m, off));
    if (t == 0) flags[which] = (m > 1.0e6f) ? 1u : 0u;
}

__global__ __launch_bounds__(256) void k_zero(float4* __restrict__ p, int n4) {
    const float4 z = {0.0f, 0.0f, 0.0f, 0.0f};
    for (int i = blockIdx.x * 256 + threadIdx.x; i < n4; i += gridDim.x * 256)
        p[i] = z;
}

__device__ __forceinline__ int cell_of(float px, float py, int bloc) {
    const int ix = (int)floorf((px + 50.0f) / 0.78125f);
    const int iy = (int)floorf((py + 50.0f) / 0.78125f);
    if (ix < 0 || ix >= BEVW || iy < 0 || iy >= BEVH) return -1;
    return bloc * HW_ + iy * BEVW + ix;
}

__device__ __forceinline__ void load_pt(const void* pts_raw, size_t pidx, int pf32,
                                        float& px, float& py, float& pz, float& pw) {
    if (pf32) {
        const float4 p = ((const float4*)pts_raw)[pidx];
        px = p.x; py = p.y; pz = p.z; pw = p.w;
    } else {
        const ushort4 p = ((const ushort4*)pts_raw)[pidx];
        px = bf2f(p.x); py = bf2f(p.y); pz = bf2f(p.z); pw = bf2f(p.w);
    }
}

// ---------------------------------------------------------------------------
// Phase A: histogram.
// ---------------------------------------------------------------------------
__global__ __launch_bounds__(256) void k_bin(
    const void* __restrict__ pts_raw,
    const unsigned int* __restrict__ flags,
    unsigned int* __restrict__ cnt,
    int b0, int npts)
{
    const int gid = blockIdx.x * 256 + threadIdx.x;
    if (gid >= npts) return;
    float px, py, pz, pw;
    load_pt(pts_raw, (size_t)b0 * NP_ + gid, (int)flags[1], px, py, pz, pw);
    const int g = cell_of(px, py, gid / NP_);
    if (g >= 0) atomicAdd(&cnt[g], 1u);
}

// ---------------------------------------------------------------------------
// Phase B1: per-block (1024 cells) sums.
// ---------------------------------------------------------------------------
__global__ __launch_bounds__(256) void k_scan_part(
    const unsigned int* __restrict__ cnt,
    unsigned int* __restrict__ bsums)
{
    __shared__ unsigned int sd[256];
    const int t = threadIdx.x;
    const int i0 = blockIdx.x * 1024 + t * 4;
    unsigned int s = cnt[i0] + cnt[i0 + 1] + cnt[i0 + 2] + cnt[i0 + 3];
    sd[t] = s;
    __syncthreads();
    for (int d = 128; d > 0; d >>= 1) {
        if (t < d) sd[t] += sd[t + d];
        __syncthreads();
    }
    if (t == 0) bsums[blockIdx.x] = sd[0];
}

// ---------------------------------------------------------------------------
// Phase B2: apply prefix -> offs (+sentinel) and cursor.
// ---------------------------------------------------------------------------
__global__ __launch_bounds__(256) void k_scan_apply(
    const unsigned int* __restrict__ cnt,
    const unsigned int* __restrict__ bsums,
    unsigned int* __restrict__ offs,
    unsigned int* __restrict__ cursor,
    int nblocks, int n)
{
    __shared__ unsigned int sd[256];
    __shared__ unsigned int sBase;
    const int t = threadIdx.x;
    const int blk = blockIdx.x;
    const int i0 = blk * 1024 + t * 4;
    unsigned int c0 = cnt[i0], c1 = cnt[i0 + 1], c2 = cnt[i0 + 2], c3 = cnt[i0 + 3];
    const unsigned int s4 = c0 + c1 + c2 + c3;
    sd[t] = s4;
    if (t == 0) {
        unsigned int b = 0;
        for (int j = 0; j < blk; ++j) b += bsums[j];
        sBase = b;
    }
    __syncthreads();
    for (int d = 1; d < 256; d <<= 1) {
        const unsigned int add = (t >= d) ? sd[t - d] : 0u;
        __syncthreads();
        sd[t] += add;
        __syncthreads();
    }
    unsigned int run = sBase + sd[t] - s4;    // exclusive prefix
    offs[i0] = run;     cursor[i0] = run;     run += c0;
    offs[i0 + 1] = run; cursor[i0 + 1] = run; run += c1;
    offs[i0 + 2] = run; cursor[i0 + 2] = run; run += c2;
    offs[i0 + 3] = run; cursor[i0 + 3] = run; run += c3;
    if (blk == nblocks - 1 && t == 255) offs[n] = run;
}

// ---------------------------------------------------------------------------
// Phase C: materialize the sort — packed 8B fp16 cell-delta + u16 cell.
// ---------------------------------------------------------------------------
__global__ __launch_bounds__(256) void k_scatteridx(
    const void* __restrict__ pts_raw,
    const unsigned int* __restrict__ flags,
    unsigned int* __restrict__ cursor,
    ushort4* __restrict__ psorted8,
    unsigned short* __restrict__ scell16,
    int b0, int npts)
{
    const int gid = blockIdx.x * 256 + threadIdx.x;
    if (gid >= npts) return;
    float px, py, pz, pw;
    load_pt(pts_raw, (size_t)b0 * NP_ + gid, (int)flags[1], px, py, pz, pw);
    const int g = cell_of(px, py, gid / NP_);
    if (g < 0) return;
    const unsigned int pos = atomicAdd(&cursor[g], 1u);
    const int cellin = g & (HW_ - 1);
    const float cx = fmaf((float)(cellin & 127), 0.78125f, -49.609375f);
    const float cy = fmaf((float)(cellin >> 7), 0.78125f, -49.609375f);
    ushort4 r;
    r.x = f2h(px - cx);
    r.y = f2h(py - cy);
    r.z = f2h(pz);
    r.w = f2h(pw);
    psorted8[pos] = r;
    scell16[pos] = (unsigned short)g;
}

// ---------------------------------------------------------------------------
// Phase D (persistent MFMA): waves grid-stride over 64-point chunks.
// Plane-major sums: element (row, ch = nt*16+m15) at sums[nt*P + row*16+m15].
// R19: coalesced W2T staging; direct 4-point gather loads (no shfl chain,
// no prefetch regs); nMt2==1 fast path with hoisted A2 selector + row LUT.
// ---------------------------------------------------------------------------
__global__ __launch_bounds__(256, 2) void k_mlp_mfma(
    const ushort4* __restrict__ psorted8,
    const unsigned short* __restrict__ scell16,
    const void* __restrict__ W1_raw,
    const void* __restrict__ b1_raw,
    const void* __restrict__ W2_raw,
    const void* __restrict__ b2_raw,
    const unsigned int* __restrict__ flags,
    unsigned int* __restrict__ magic,
    const unsigned int* __restrict__ offs,    // ncells+1 (sentinel = total)
    float* __restrict__ sums,                 // 5 planes of P floats
    int ncells, int P)
{
    __shared__ float sW1[4 * CH];             // [f][k]
    __shared__ float sb1[CH];
    __shared__ float sb2f[CH];
    __shared__ _Float16 sW2T[80 * HSTR];      // [ch_out][k], k 80..95 zero
    __shared__ _Float16 sEmb[4][16 * ESTR];   // per-wave embT slice [ch16][pt]
    __shared__ unsigned int sCellG[4][64];

    const int t = threadIdx.x;
    const int wf32 = (int)flags[0];

    // ---- staging (R19: W2 read coalesced, LDS-scatter write).
    if (wf32) {
        const float* W1 = (const float*)W1_raw;
        const float* b1 = (const float*)b1_raw;
        const float* b2 = (const float*)b2_raw;
        for (int i = t; i < 4 * CH; i += 256) sW1[i] = W1[i];
        if (t < CH) { sb1[t] = b1[t]; sb2f[t] = b2[t]; }
        const float* W2 = (const float*)W2_raw;
        for (int i = t; i < CH * CH; i += 256)      // i = c*80 + d, coalesced
            sW2T[(i % CH) * HSTR + i / CH] = (_Float16)W2[i];
    } else {
        const unsigned short* W1 = (const unsigned short*)W1_raw;
        const unsigned short* b1 = (const unsigned short*)b1_raw;
        const unsigned short* b2 = (const unsigned short*)b2_raw;
        for (int i = t; i < 4 * CH; i += 256) sW1[i] = bf2f(W1[i]);
        if (t < CH) { sb1[t] = bf2f(b1[t]); sb2f[t] = bf2f(b2[t]); }
        const unsigned short* W2 = (const unsigned short*)W2_raw;
        for (int i = t; i < CH * CH; i += 256)      // coalesced
            sW2T[(i % CH) * HSTR + i / CH] = (_Float16)bf2f(W2[i]);
    }
    // zero the k = 80..103 pad of every row
    for (int i = t; i < CH * (HSTR - CH); i += 256)
        sW2T[(i / (HSTR - CH)) * HSTR + CH + (i % (HSTR - CH))] = (_Float16)0.0f;
    __syncthreads();

    if (blockIdx.x == 0 && t == 0) *magic = 0xCAFEBABEu;

    const int end = (int)offs[ncells];
    const int lane = t & 63;
    const int wid = t >> 6;
    const int m15 = lane & 15;
    const int quad = lane >> 4;
    const int totalWaves = gridDim.x * 4;
    const int nChunks = (end + 63) >> 6;

    for (int wv = blockIdx.x * 4 + wid; wv < nChunks; wv += totalWaves) {
        const int chunkStart = wv * 64;
        const int p = chunkStart + lane;
        const bool active = p < end;

        // ---- own cell (bookkeeping) + 4 gathered point records (A-frags).
        const int pOwn = active ? p : (end - 1);
        const int g = active ? (int)scell16[pOwn] : -1;

        ushort4 prm[4];
        int gm[4];
#pragma unroll
        for (int mt = 0; mt < 4; ++mt) {
            int idx = chunkStart + mt * 16 + m15;
            if (idx > end - 1) idx = end - 1;
            prm[mt] = psorted8[idx];            // 16-lane broadcast, L1/L2
            gm[mt] = (int)scell16[idx];
        }

        float pmx[4], pmy[4], pmz[4], pmw[4];
#pragma unroll
        for (int mt = 0; mt < 4; ++mt) {
            const int cellin = gm[mt] & (HW_ - 1);
            const float cx = fmaf((float)(cellin & 127), 0.78125f, -49.609375f);
            const float cy = fmaf((float)(cellin >> 7), 0.78125f, -49.609375f);
            pmx[mt] = cx + h2f(prm[mt].x);
            pmy[mt] = cy + h2f(prm[mt].y);
            pmz[mt] = h2f(prm[mt].z);
            pmw[mt] = h2f(prm[mt].w);
        }

        // ---- segment bookkeeping (R13-verified).
        const int gprev = __shfl_up(g, 1);
        const bool isHead = active && (lane == 0 || gprev != g);
        const unsigned long long headmask = __ballot(isHead);
        const int cellLocal = active
            ? (__popcll(headmask << (63 - lane)) - 1) : 255;
        const int ncellsW = __popcll(headmask);
        if (isHead) {
            // Ownership: cell start within this chunk -> direct row g;
            // head cell that started earlier -> per-chunk staging row.
            unsigned int row = (unsigned int)g;
            if (cellLocal == 0) {
                const unsigned int o = offs[g];
                if (o < (unsigned int)chunkStart)
                    row = (unsigned int)(ncells + wv);
            }
            sCellG[wid][cellLocal] = row;
        }

        // ---- layer 1 transposed: A-frag values born in registers.
        half8_t Af[3][4];
#pragma unroll
        for (int ks = 0; ks < 3; ++ks) {
            const int kb = ks * 32 + quad * 8;
            if (kb < 80) {
                const float4 wa0 = *(const float4*)&sW1[0 * CH + kb];
                const float4 wb0 = *(const float4*)&sW1[0 * CH + kb + 4];
                const float4 wa1 = *(const float4*)&sW1[1 * CH + kb];
                const float4 wb1 = *(const float4*)&sW1[1 * CH + kb + 4];
                const float4 wa2 = *(const float4*)&sW1[2 * CH + kb];
                const float4 wb2 = *(const float4*)&sW1[2 * CH + kb + 4];
                const float4 wa3 = *(const float4*)&sW1[3 * CH + kb];
                const float4 wb3 = *(const float4*)&sW1[3 * CH + kb + 4];
                const float4 ba  = *(const float4*)&sb1[kb];
                const float4 bb  = *(const float4*)&sb1[kb + 4];
                float w0[8] = {wa0.x, wa0.y, wa0.z, wa0.w, wb0.x, wb0.y, wb0.z, wb0.w};
                float w1[8] = {wa1.x, wa1.y, wa1.z, wa1.w, wb1.x, wb1.y, wb1.z, wb1.w};
                float w2[8] = {wa2.x, wa2.y, wa2.z, wa2.w, wb2.x, wb2.y, wb2.z, wb2.w};
                float w3[8] = {wa3.x, wa3.y, wa3.z, wa3.w, wb3.x, wb3.y, wb3.z, wb3.w};
                float bv[8] = {ba.x, ba.y, ba.z, ba.w, bb.x, bb.y, bb.z, bb.w};
#pragma unroll
                for (int mt = 0; mt < 4; ++mt) {
                    half8_t v;
#pragma unroll
                    for (int j = 0; j < 8; ++j) {
                        float hv = bv[j];
                        hv = fmaf(pmx[mt], w0[j], hv);
                        hv = fmaf(pmy[mt], w1[j], hv);
                        hv = fmaf(pmz[mt], w2[j], hv);
                        hv = fmaf(pmw[mt], w3[j], hv);
                        v[j] = (_Float16)fmaxf(hv, 0.0f);
                    }
                    Af[ks][mt] = v;
                }
            } else {
                const half8_t z8 = {0, 0, 0, 0, 0, 0, 0, 0};
#pragma unroll
                for (int mt = 0; mt < 4; ++mt) Af[ks][mt] = z8;
            }
        }

        // ---- selector columns for MFMA2.
        int cl[2][8];
#pragma unroll
        for (int ks2 = 0; ks2 < 2; ++ks2)
#pragma unroll
            for (int j = 0; j < 8; ++j)
                cl[ks2][j] = __shfl(cellLocal, ks2 * 32 + quad * 8 + j);

        const int nMt2 = (ncellsW + 15) >> 4;
        _Float16* embT = &sEmb[wid][0];

        if (nMt2 == 1) {
            // ======== fast path (<=16 cells): A2 + row LUT hoisted ========
            half8_t A2h[2];
#pragma unroll
            for (int ks2 = 0; ks2 < 2; ++ks2)
#pragma unroll
                for (int j = 0; j < 8; ++j)
                    A2h[ks2][j] = (cl[ks2][j] == m15) ? (_Float16)1 : (_Float16)0;
            unsigned int rowr[4];
#pragma unroll
            for (int r = 0; r < 4; ++r) {
                const int cell = quad * 4 + r;
                rowr[r] = (cell < ncellsW) ? sCellG[wid][cell] : 0xFFFFFFFFu;
            }

#pragma unroll 1
            for (int nt = 0; nt < 5; ++nt) {
                f32x4_t acc[4];
#pragma unroll
                for (int mt = 0; mt < 4; ++mt) acc[mt] = (f32x4_t){0.0f, 0.0f, 0.0f, 0.0f};
#pragma unroll
                for (int ks = 0; ks < 3; ++ks) {
                    const half8_t Bf = *(const half8_t*)
                        &sW2T[(nt * 16 + m15) * HSTR + ks * 32 + quad * 8];
#pragma unroll
                    for (int mt = 0; mt < 4; ++mt)
                        acc[mt] = __builtin_amdgcn_mfma_f32_16x16x32_f16(
                            Af[ks][mt], Bf, acc[mt], 0, 0, 0);
                }
                const float bb2 = sb2f[nt * 16 + m15];
#pragma unroll
                for (int mt = 0; mt < 4; ++mt) {
                    const f32x4_t a = acc[mt];
                    half4_t v;
                    v[0] = (_Float16)fmaxf(a[0] + bb2, 0.0f);
                    v[1] = (_Float16)fmaxf(a[1] + bb2, 0.0f);
                    v[2] = (_Float16)fmaxf(a[2] + bb2, 0.0f);
                    v[3] = (_Float16)fmaxf(a[3] + bb2, 0.0f);
                    *(half4_t*)&embT[m15 * ESTR + mt * 16 + quad * 4] = v;
                }
                half8_t B2[2];
#pragma unroll
                for (int ks2 = 0; ks2 < 2; ++ks2)
                    B2[ks2] = *(const half8_t*)&embT[m15 * ESTR + ks2 * 32 + quad * 8];

                f32x4_t acc2 = (f32x4_t){0.0f, 0.0f, 0.0f, 0.0f};
#pragma unroll
                for (int ks2 = 0; ks2 < 2; ++ks2)
                    acc2 = __builtin_amdgcn_mfma_f32_16x16x32_f16(
                        A2h[ks2], B2[ks2], acc2, 0, 0, 0);

                float* const plane = sums + (size_t)nt * (size_t)P;
#pragma unroll
                for (int r = 0; r < 4; ++r)
                    if (rowr[r] != 0xFFFFFFFFu)
                        plane[((size_t)rowr[r] << 4) + m15] = acc2[r];
            }
        } else {
            // ======== general path (>16 cells in chunk) ========
#pragma unroll 1
            for (int nt = 0; nt < 5; ++nt) {
                f32x4_t acc[4];
#pragma unroll
                for (int mt = 0; mt < 4; ++mt) acc[mt] = (f32x4_t){0.0f, 0.0f, 0.0f, 0.0f};
#pragma unroll
                for (int ks = 0; ks < 3; ++ks) {
                    const half8_t Bf = *(const half8_t*)
                        &sW2T[(nt * 16 + m15) * HSTR + ks * 32 + quad * 8];
#pragma unroll
                    for (int mt = 0; mt < 4; ++mt)
                        acc[mt] = __builtin_amdgcn_mfma_f32_16x16x32_f16(
                            Af[ks][mt], Bf, acc[mt], 0, 0, 0);
                }
                const float bb2 = sb2f[nt * 16 + m15];
#pragma unroll
                for (int mt = 0; mt < 4; ++mt) {
                    const f32x4_t a = acc[mt];
                    half4_t v;
                    v[0] = (_Float16)fmaxf(a[0] + bb2, 0.0f);
                    v[1] = (_Float16)fmaxf(a[1] + bb2, 0.0f);
                    v[2] = (_Float16)fmaxf(a[2] + bb2, 0.0f);
                    v[3] = (_Float16)fmaxf(a[3] + bb2, 0.0f);
                    *(half4_t*)&embT[m15 * ESTR + mt * 16 + quad * 4] = v;
                }
                half8_t B2[2];
#pragma unroll
                for (int ks2 = 0; ks2 < 2; ++ks2)
                    B2[ks2] = *(const half8_t*)&embT[m15 * ESTR + ks2 * 32 + quad * 8];

                float* const plane = sums + (size_t)nt * (size_t)P;
                for (int mt2 = 0; mt2 < nMt2; ++mt2) {
                    const int m2 = mt2 * 16 + m15;
                    f32x4_t acc2 = (f32x4_t){0.0f, 0.0f, 0.0f, 0.0f};
#pragma unroll
                    for (int ks2 = 0; ks2 < 2; ++ks2) {
                        half8_t A2;
#pragma unroll
                        for (int j = 0; j < 8; ++j)
                            A2[j] = (cl[ks2][j] == m2) ? (_Float16)1 : (_Float16)0;
                        acc2 = __builtin_amdgcn_mfma_f32_16x16x32_f16(
                            A2, B2[ks2], acc2, 0, 0, 0);
                    }
#pragma unroll
                    for (int r = 0; r < 4; ++r) {
                        const int cell = mt2 * 16 + quad * 4 + r;
                        if (cell < ncellsW) {
                            const unsigned int row = sCellG[wid][cell];
                            plane[((size_t)row << 4) + m15] = acc2[r];
                        }
                    }
                }
            }
        }
    }
}

// ---------------------------------------------------------------------------
// Head: mean -> 1x1 conv -> BN -> relu -> out (fp32). Mean staged f16.
// Folds staged head-partials (plane rows ncells+b for b in the cell's chunk
// span) and gates on cnt>0 (sums is NOT pre-zeroed).
// ---------------------------------------------------------------------------
#define MPAD 84

__global__ __launch_bounds__(256) void k_head(
    const float* __restrict__ sums,
    const unsigned int* __restrict__ cnt,
    const unsigned int* __restrict__ offs,
    const void* __restrict__ Wp_raw,
    const void* __restrict__ bp_raw,
    const void* __restrict__ gamma_raw,
    const void* __restrict__ beta_raw,
    const void* __restrict__ rmean_raw,
    const void* __restrict__ rvar_raw,
    const unsigned int* __restrict__ flags,
    float* __restrict__ out,
    int b0, int ncells, int P)
{
    __shared__ float sWp[CH * COUT_];
    __shared__ _Float16 sMean[BEVW * MPAD];
    __shared__ float sAlpha[COUT_], sDelta[COUT_];

    const int t = threadIdx.x;
    const int blk = blockIdx.x;
    const int bl = blk >> 7, hrow = blk & 127;
    const int bg = b0 + bl;
    const int wf32 = (int)flags[0];

    if (wf32) {
        const float* Wp = (const float*)Wp_raw;
        for (int i = t; i < CH * COUT_; i += 256) sWp[i] = Wp[i];
        if (t < COUT_) {
            const float rs = rsqrtf(((const float*)rvar_raw)[t] + 1e-5f);
            const float al = ((const float*)gamma_raw)[t] * rs;
            sAlpha[t] = al;
            sDelta[t] = al * (((const float*)bp_raw)[t] - ((const float*)rmean_raw)[t])
                        + ((const float*)beta_raw)[t];
        }
    } else {
        const unsigned short* Wp = (const unsigned short*)Wp_raw;
        for (int i = t; i < CH * COUT_; i += 256) sWp[i] = bf2f(Wp[i]);
        if (t < COUT_) {
            const float rs = rsqrtf(bf2f(((const unsigned short*)rvar_raw)[t]) + 1e-5f);
            const float al = bf2f(((const unsigned short*)gamma_raw)[t]) * rs;
            sAlpha[t] = al;
            sDelta[t] = al * (bf2f(((const unsigned short*)bp_raw)[t])
                              - bf2f(((const unsigned short*)rmean_raw)[t]))
                        + bf2f(((const unsigned short*)beta_raw)[t]);
        }
    }

    const int cellbase = bl * HW_ + hrow * BEVW;
    for (int i = t; i < BEVW * 20; i += 256) {
        const int w = i / 20, c4 = i % 20;
        const int nt = c4 >> 2, q = c4 & 3;
        const int cell = cellbase + w;
        const unsigned int c = cnt[cell];
        float4 s = {0.0f, 0.0f, 0.0f, 0.0f};
        if (c > 0) {
            const float4* plane4 = (const float4*)(sums + (size_t)nt * (size_t)P);
            s = plane4[cell * 4 + q];
            const unsigned int o = offs[cell];
            const int bA = (int)(o >> 6) + 1;
            const int bB = (int)((o + c - 1) >> 6);
            for (int b = bA; b <= bB; ++b) {
                const float4 st = plane4[(ncells + b) * 4 + q];
                s.x += st.x; s.y += st.y; s.z += st.z; s.w += st.w;
            }
        }
        const float inv = 1.0f / fmaxf((float)c, 1.0f);
        _Float16* m = &sMean[w * MPAD + c4 * 4];
        m[0] = (_Float16)(s.x * inv);
        m[1] = (_Float16)(s.y * inv);
        m[2] = (_Float16)(s.z * inv);
        m[3] = (_Float16)(s.w * inv);
    }
    __syncthreads();

    const int v = t >> 6;
    const int w = (t & 63) + (v & 1) * 64;
    const int dbase = (v >> 1) * 64;

    float acc[64];
#pragma unroll
    for (int j = 0; j < 64; ++j) acc[j] = 0.0f;

    const _Float16* mrow = &sMean[w * MPAD];
#pragma unroll 2
    for (int c = 0; c < CH; ++c) {
        const float m = (float)mrow[c];
        const float4* wrow = (const float4*)&sWp[c * COUT_ + dbase];
#pragma unroll
        for (int j4 = 0; j4 < 16; ++j4) {
            const float4 wv = wrow[j4];
            acc[j4 * 4 + 0] = fmaf(m, wv.x, acc[j4 * 4 + 0]);
            acc[j4 * 4 + 1] = fmaf(m, wv.y, acc[j4 * 4 + 1]);
            acc[j4 * 4 + 2] = fmaf(m, wv.z, acc[j4 * 4 + 2]);
            acc[j4 * 4 + 3] = fmaf(m, wv.w, acc[j4 * 4 + 3]);
        }
    }

#pragma unroll
    for (int j = 0; j < 64; ++j) {
        const int d = dbase + j;
        float o = fmaxf(fmaf(acc[j], sAlpha[d], sDelta[d]), 0.0f);
        o = fminf(o, 512.0f);
        out[(((size_t)bg * COUT_ + d) * BEVH + hrow) * BEVW + w] = o;
    }
}

// ---------------------------------------------------------------------------
// Diagnostics beacon (insurance; healthy run writes nothing).
// ---------------------------------------------------------------------------
__global__ __launch_bounds__(256) void k_diag(
    const unsigned int* __restrict__ cnt,
    const float* __restrict__ sums,
    const unsigned int* __restrict__ magic,
    const unsigned int* __restrict__ flags,
    float* __restrict__ out,
    int hostbits)
{
    __shared__ float red[256];
    __shared__ unsigned int credu[256];
    const int t = threadIdx.x;

    unsigned int cs = 0;
    for (int i = t; i < HW_; i += 256) cs += cnt[i];
    credu[t] = cs;

    float sl = 0.0f;
    for (int i = t; i < CH * CH; i += 256) sl += fabsf(sums[i]);
    red[t] = sl;
    __syncthreads();

    for (int s = 128; s > 0; s >>= 1) {
        if (t < s) { red[t] += red[t + s]; credu[t] += credu[t + s]; }
        __syncthreads();
    }

    if (t == 0) {
        int code = hostbits;
        if (*magic != 0xCAFEBABEu) code |= 1;
        if (credu[0] < 1000u)      code |= 2;
        if (!(red[0] > 0.0f))      code |= 4;
        if (code) {
            code |= (int)(flags[0] ? 32 : 0);
            code |= (int)(flags[1] ? 64 : 0);
            out[0] = 1024.0f * (float)code;
        }
    }
}

extern "C" void kernel_launch(void* const* d_in, const int* in_sizes, int n_in,
                              void* d_out, int out_size, void* d_ws, size_t ws_size,
                              hipStream_t stream) {
    const void* pts   = d_in[0];
    const void* W1    = d_in[1];
    const void* b1    = d_in[2];
    const void* W2    = d_in[3];
    const void* b2    = d_in[4];
    const void* Wp    = d_in[5];
    const void* bp    = d_in[6];
    const void* gamma = d_in[7];
    const void* beta  = d_in[8];
    const void* rmean = d_in[9];
    const void* rvar  = d_in[10];

    int hostbits = 0;
    if (n_in != 11 ||
        in_sizes[0] != B_ * NP_ * 4 ||
        in_sizes[1] != 4 * CH  || in_sizes[2] != CH ||
        in_sizes[3] != CH * CH || in_sizes[4] != CH ||
        in_sizes[5] != CH * COUT_ || in_sizes[6] != COUT_ ||
        out_size != B_ * COUT_ * HW_)
        hostbits |= 8;
    if (ws_size < SCRATCH_OFF + PER_BATCH + EXTRA_BYTES) hostbits |= 16;

    unsigned int* flags = (unsigned int*)d_ws;
    unsigned int* magic = (unsigned int*)((char*)d_ws + MAGIC_OFF);
    char* base = (char*)d_ws + SCRATCH_OFF;
    const size_t avail = (ws_size > SCRATCH_OFF + EXTRA_BYTES)
                       ? (ws_size - SCRATCH_OFF - EXTRA_BYTES) : PER_BATCH;
    int nb = (int)(avail / PER_BATCH);
    if (nb < 1) nb = 1;
    if (nb > B_) nb = B_;

    // Layout: cnt | sums (5 planes, incl. staging rows) | offs(+4) | cursor |
    //         psorted8 (8B-aligned) | scell16 | bsums
    unsigned int*   cnt      = (unsigned int*)base;
    float*          sums     = (float*)(cnt + (size_t)nb * HW_);
    const size_t    sumsFl   = (size_t)5 * ((size_t)nb * HW_ + (size_t)nb * NCHK) * 16;
    unsigned int*   offs     = (unsigned int*)(sums + sumsFl);
    unsigned int*   cursor   = offs + (size_t)nb * HW_ + 4;
    ushort4*        psorted8 = (ushort4*)(cursor + (size_t)nb * HW_);
    unsigned short* scell16  = (unsigned short*)(psorted8 + (size_t)nb * NP_);
    unsigned int*   bsums    = (unsigned int*)(scell16 + (size_t)nb * NP_);

    k_detect<<<2, 64, 0, stream>>>((const unsigned short*)W1,
                                   (const unsigned short*)pts, flags);

    for (int b0 = 0; b0 < B_; b0 += nb) {
        const int bcnt = (B_ - b0 < nb) ? (B_ - b0) : nb;
        const int ncells = bcnt * HW_;
        const int npts   = bcnt * NP_;
        const int nblk   = ncells >> 10;      // 1024 cells per scan block
        const int P      = (ncells + bcnt * NCHK) * 16;   // plane stride (f32)

        // Zero cnt + the first CH*CH sums floats (k_diag window). Occupied
        // sums rows are fully owner-written; k_head gates on cnt>0; staging
        // rows are only read when their write-condition held.
        k_zero<<<128, 256, 0, stream>>>((float4*)cnt, ncells / 4 + 1600);

        k_bin<<<(npts + 255) / 256, 256, 0, stream>>>(
            pts, flags, cnt, b0, npts);

        k_scan_part<<<nblk, 256, 0, stream>>>(cnt, bsums);
        k_scan_apply<<<nblk, 256, 0, stream>>>(cnt, bsums, offs, cursor,
                                               nblk, ncells);

        k_scatteridx<<<(npts + 255) / 256, 256, 0, stream>>>(
            pts, flags, cursor, psorted8, scell16, b0, npts);

        k_mlp_mfma<<<1280, 256, 0, stream>>>(
            psorted8, scell16, W1, b1, W2, b2, flags, magic, offs, sums,
            ncells, P);

        k_head<<<bcnt * BEVH, 256, 0, stream>>>(
            sums, cnt, offs, Wp, bp, gamma, beta, rmean, rvar, flags,
            (float*)d_out, b0, ncells, P);
    }

    k_diag<<<1, 256, 0, stream>>>(cnt, sums, magic, flags,
                                  (float*)d_out, hostbits);
}

// Round 6
// 252.128 us; speedup vs baseline: 1.1916x; 1.0155x over previous
//
#include <hip/hip_runtime.h>
#include <hip/hip_bf16.h>

// PointsToBEV round 20. R19 post-mortem: VALU cut landed (VALUBusy 40->34)
// but dur flat at ~53us -> k_mlp is stall-bound on serial L2 chains, not
// VALU-throughput. Also non-k_mlp ~200us across 9 dispatches is the bigger
// pool (launch bubbles + small kernels). R20: (1) chHead byte per chunk,
// precomputed in the scan, replaces k_mlp's dependent offs[g] load (kills
// one L2 round-trip per chunk); (2) fuse 9 dispatches -> 6: k_init
// (zero+detect), k_scan (part+apply, per-block redundant base re-sum, no
// cross-block sync), k_head absorbs k_diag in block 0.

#define B_    4
#define NP_   200000
#define CH    80
#define COUT_ 128
#define BEVH  128
#define BEVW  128
#define HW_   (BEVH * BEVW)
#define NCHK  (NP_ / 64)        // 3125 chunks per batch (NP_ % 64 == 0)

// Per-batch bytes: cnt(HW u32) + sums+staging((HW+NCHK)*80 f32) +
// offs(HW u32 +pad) + cursor(HW u32) + chHead(NCHK u8) + psorted8(NP*8) +
// scell16(NP*2)
#define PER_BATCH ((size_t)HW_ * 332 + (size_t)NCHK * 321 + (size_t)NP_ * 10)
#define EXTRA_BYTES 512

#define MAGIC_OFF   128
#define SCRATCH_OFF 256

typedef _Float16 half4_t __attribute__((ext_vector_type(4)));
typedef _Float16 half8_t __attribute__((ext_vector_type(8)));
typedef float    f32x4_t __attribute__((ext_vector_type(4)));

#define HSTR 104   // W2T k-stride in f16 (52 dwords -> 2-way banks, free)
#define ESTR 72    // embT pt-stride in f16 (36 dwords -> 2-way banks, free)

__device__ __forceinline__ float bf2f(unsigned short u) {
    return __uint_as_float(((unsigned int)u) << 16);
}
__device__ __forceinline__ unsigned short f2h(float f) {
    return __builtin_bit_cast(unsigned short, (_Float16)f);
}
__device__ __forceinline__ float h2f(unsigned short u) {
    return (float)__builtin_bit_cast(_Float16, u);
}

__device__ __forceinline__ int cell_of(float px, float py, int bloc) {
    const int ix = (int)floorf((px + 50.0f) / 0.78125f);
    const int iy = (int)floorf((py + 50.0f) / 0.78125f);
    if (ix < 0 || ix >= BEVW || iy < 0 || iy >= BEVH) return -1;
    return bloc * HW_ + iy * BEVW + ix;
}

__device__ __forceinline__ void load_pt(const void* pts_raw, size_t pidx, int pf32,
                                        float& px, float& py, float& pz, float& pw) {
    if (pf32) {
        const float4 p = ((const float4*)pts_raw)[pidx];
        px = p.x; py = p.y; pz = p.z; pw = p.w;
    } else {
        const ushort4 p = ((const ushort4*)pts_raw)[pidx];
        px = bf2f(p.x); py = bf2f(p.y); pz = bf2f(p.z); pw = bf2f(p.w);
    }
}

// ---------------------------------------------------------------------------
// k_init: grid-stride zero of cnt + diag window (contiguous float4) and the
// chHead bytes; blocks 0/1 additionally run the dtype probes.
// flags[0]=params fp32, flags[1]=points fp32.
// ---------------------------------------------------------------------------
__global__ __launch_bounds__(256) void k_init(
    float4* __restrict__ zp, int n4,
    unsigned int* __restrict__ chz, int nc4,
    const unsigned short* __restrict__ w1bits,
    const unsigned short* __restrict__ ptsbits,
    unsigned int* __restrict__ flags)
{
    const int t = threadIdx.x;
    if (blockIdx.x < 2 && t < 64) {
        const int which = blockIdx.x;
        const unsigned short* src = which ? ptsbits : w1bits;
        const int n = which ? 512 : 320;
        float m = 0.0f;
        for (int i = t; i < n; i += 64) {
            const float a = fabsf(bf2f(src[i]));
            if (a == a) m = fmaxf(m, a);
        }
#pragma unroll
        for (int off = 32; off > 0; off >>= 1)
            m = fmaxf(m, __shfl_down(m, off));
        if (t == 0) flags[which] = (m > 1.0e6f) ? 1u : 0u;
    }
    const float4 z = {0.0f, 0.0f, 0.0f, 0.0f};
    for (int i = blockIdx.x * 256 + t; i < n4; i += gridDim.x * 256)
        zp[i] = z;
    for (int i = blockIdx.x * 256 + t; i < nc4; i += gridDim.x * 256)
        chz[i] = 0u;
}

// ---------------------------------------------------------------------------
// Phase A: histogram.
// ---------------------------------------------------------------------------
__global__ __launch_bounds__(256) void k_bin(
    const void* __restrict__ pts_raw,
    const unsigned int* __restrict__ flags,
    unsigned int* __restrict__ cnt,
    int b0, int npts)
{
    const int gid = blockIdx.x * 256 + threadIdx.x;
    if (gid >= npts) return;
    float px, py, pz, pw;
    load_pt(pts_raw, (size_t)b0 * NP_ + gid, (int)flags[1], px, py, pz, pw);
    const int g = cell_of(px, py, gid / NP_);
    if (g >= 0) atomicAdd(&cnt[g], 1u);
}

// ---------------------------------------------------------------------------
// Phase B (fused scan): each block redundantly sums cnt[0..base) for its
// prefix (L2-hot, no cross-block sync), then local-scans its 1024 cells,
// writes offs (+sentinel), cursor, and marks chHead[chunk] when a nonempty
// cell starts exactly at a 64-point chunk boundary.
// ---------------------------------------------------------------------------
__global__ __launch_bounds__(256) void k_scan(
    const unsigned int* __restrict__ cnt,
    unsigned int* __restrict__ offs,
    unsigned int* __restrict__ cursor,
    unsigned char* __restrict__ chHead,
    int nblocks, int n)
{
    __shared__ unsigned int sd[256];
    __shared__ unsigned int sBase;
    const int t = threadIdx.x;
    const int blk = blockIdx.x;
    const int i0 = blk * 1024 + t * 4;
    const unsigned int c0 = cnt[i0], c1 = cnt[i0 + 1],
                       c2 = cnt[i0 + 2], c3 = cnt[i0 + 3];
    const unsigned int s4 = c0 + c1 + c2 + c3;

    // base = sum of all cells before this block (redundant re-read).
    unsigned int bsum = 0;
    const int q4 = blk << 8;                  // (blk*1024)/4 uint4 records
    const uint4* cnt4 = (const uint4*)cnt;
    for (int i = t; i < q4; i += 256) {
        const uint4 v = cnt4[i];
        bsum += v.x + v.y + v.z + v.w;
    }
    sd[t] = bsum;
    __syncthreads();
    for (int d = 128; d > 0; d >>= 1) {
        if (t < d) sd[t] += sd[t + d];
        __syncthreads();
    }
    if (t == 0) sBase = sd[0];
    __syncthreads();

    // local inclusive scan of per-thread s4.
    sd[t] = s4;
    __syncthreads();
    for (int d = 1; d < 256; d <<= 1) {
        const unsigned int add = (t >= d) ? sd[t - d] : 0u;
        __syncthreads();
        sd[t] += add;
        __syncthreads();
    }
    unsigned int run = sBase + sd[t] - s4;    // exclusive prefix
    offs[i0] = run;     cursor[i0] = run;
    if (c0 && !(run & 63u)) chHead[run >> 6] = 1;            run += c0;
    offs[i0 + 1] = run; cursor[i0 + 1] = run;
    if (c1 && !(run & 63u)) chHead[run >> 6] = 1;            run += c1;
    offs[i0 + 2] = run; cursor[i0 + 2] = run;
    if (c2 && !(run & 63u)) chHead[run >> 6] = 1;            run += c2;
    offs[i0 + 3] = run; cursor[i0 + 3] = run;
    if (c3 && !(run & 63u)) chHead[run >> 6] = 1;            run += c3;
    if (blk == nblocks - 1 && t == 255) offs[n] = run;
}

// ---------------------------------------------------------------------------
// Phase C: materialize the sort — packed 8B fp16 cell-delta + u16 cell.
// ---------------------------------------------------------------------------
__global__ __launch_bounds__(256) void k_scatteridx(
    const void* __restrict__ pts_raw,
    const unsigned int* __restrict__ flags,
    unsigned int* __restrict__ cursor,
    ushort4* __restrict__ psorted8,
    unsigned short* __restrict__ scell16,
    int b0, int npts)
{
    const int gid = blockIdx.x * 256 + threadIdx.x;
    if (gid >= npts) return;
    float px, py, pz, pw;
    load_pt(pts_raw, (size_t)b0 * NP_ + gid, (int)flags[1], px, py, pz, pw);
    const int g = cell_of(px, py, gid / NP_);
    if (g < 0) return;
    const unsigned int pos = atomicAdd(&cursor[g], 1u);
    const int cellin = g & (HW_ - 1);
    const float cx = fmaf((float)(cellin & 127), 0.78125f, -49.609375f);
    const float cy = fmaf((float)(cellin >> 7), 0.78125f, -49.609375f);
    ushort4 r;
    r.x = f2h(px - cx);
    r.y = f2h(py - cy);
    r.z = f2h(pz);
    r.w = f2h(pw);
    psorted8[pos] = r;
    scell16[pos] = (unsigned short)g;
}

// ---------------------------------------------------------------------------
// Phase D (persistent MFMA): waves grid-stride over 64-point chunks.
// Plane-major sums: element (row, ch = nt*16+m15) at sums[nt*P + row*16+m15].
// R20: chHead byte (independent early load) replaces the dependent offs[g]
// random read -> one L2 round-trip removed from the chunk critical path.
// ---------------------------------------------------------------------------
__global__ __launch_bounds__(256, 2) void k_mlp_mfma(
    const ushort4* __restrict__ psorted8,
    const unsigned short* __restrict__ scell16,
    const void* __restrict__ W1_raw,
    const void* __restrict__ b1_raw,
    const void* __restrict__ W2_raw,
    const void* __restrict__ b2_raw,
    const unsigned int* __restrict__ flags,
    unsigned int* __restrict__ magic,
    const unsigned int* __restrict__ offs,    // ncells+1 (sentinel = total)
    const unsigned char* __restrict__ chHead,
    float* __restrict__ sums,                 // 5 planes of P floats
    int ncells, int P)
{
    __shared__ float sW1[4 * CH];             // [f][k]
    __shared__ float sb1[CH];
    __shared__ float sb2f[CH];
    __shared__ _Float16 sW2T[80 * HSTR];      // [ch_out][k], k 80..95 zero
    __shared__ _Float16 sEmb[4][16 * ESTR];   // per-wave embT slice [ch16][pt]
    __shared__ unsigned int sCellG[4][64];

    const int t = threadIdx.x;
    const int wf32 = (int)flags[0];

    // ---- staging (W2 read coalesced, LDS-scatter write).
    if (wf32) {
        const float* W1 = (const float*)W1_raw;
        const float* b1 = (const float*)b1_raw;
        const float* b2 = (const float*)b2_raw;
        for (int i = t; i < 4 * CH; i += 256) sW1[i] = W1[i];
        if (t < CH) { sb1[t] = b1[t]; sb2f[t] = b2[t]; }
        const float* W2 = (const float*)W2_raw;
        for (int i = t; i < CH * CH; i += 256)      // i = c*80 + d, coalesced
            sW2T[(i % CH) * HSTR + i / CH] = (_Float16)W2[i];
    } else {
        const unsigned short* W1 = (const unsigned short*)W1_raw;
        const unsigned short* b1 = (const unsigned short*)b1_raw;
        const unsigned short* b2 = (const unsigned short*)b2_raw;
        for (int i = t; i < 4 * CH; i += 256) sW1[i] = bf2f(W1[i]);
        if (t < CH) { sb1[t] = bf2f(b1[t]); sb2f[t] = bf2f(b2[t]); }
        const unsigned short* W2 = (const unsigned short*)W2_raw;
        for (int i = t; i < CH * CH; i += 256)      // coalesced
            sW2T[(i % CH) * HSTR + i / CH] = (_Float16)bf2f(W2[i]);
    }
    // zero the k = 80..103 pad of every row
    for (int i = t; i < CH * (HSTR - CH); i += 256)
        sW2T[(i / (HSTR - CH)) * HSTR + CH + (i % (HSTR - CH))] = (_Float16)0.0f;
    __syncthreads();

    if (blockIdx.x == 0 && t == 0) *magic = 0xCAFEBABEu;

    const int end = (int)offs[ncells];
    const int lane = t & 63;
    const int wid = t >> 6;
    const int m15 = lane & 15;
    const int quad = lane >> 4;
    const int totalWaves = gridDim.x * 4;
    const int nChunks = (end + 63) >> 6;

    for (int wv = blockIdx.x * 4 + wid; wv < nChunks; wv += totalWaves) {
        const int chunkStart = wv * 64;
        const int p = chunkStart + lane;
        const bool active = p < end;

        // ---- independent early loads: chunk-head bit + own cell + gathers.
        const unsigned char hb = chHead[wv];

        const int pOwn = active ? p : (end - 1);
        const int g = active ? (int)scell16[pOwn] : -1;

        ushort4 prm[4];
        int gm[4];
#pragma unroll
        for (int mt = 0; mt < 4; ++mt) {
            int idx = chunkStart + mt * 16 + m15;
            if (idx > end - 1) idx = end - 1;
            prm[mt] = psorted8[idx];            // 16-lane broadcast, L1/L2
            gm[mt] = (int)scell16[idx];
        }

        float pmx[4], pmy[4], pmz[4], pmw[4];
#pragma unroll
        for (int mt = 0; mt < 4; ++mt) {
            const int cellin = gm[mt] & (HW_ - 1);
            const float cx = fmaf((float)(cellin & 127), 0.78125f, -49.609375f);
            const float cy = fmaf((float)(cellin >> 7), 0.78125f, -49.609375f);
            pmx[mt] = cx + h2f(prm[mt].x);
            pmy[mt] = cy + h2f(prm[mt].y);
            pmz[mt] = h2f(prm[mt].z);
            pmw[mt] = h2f(prm[mt].w);
        }

        // ---- segment bookkeeping (R13-verified).
        const int gprev = __shfl_up(g, 1);
        const bool isHead = active && (lane == 0 || gprev != g);
        const unsigned long long headmask = __ballot(isHead);
        const int cellLocal = active
            ? (__popcll(headmask << (63 - lane)) - 1) : 255;
        const int ncellsW = __popcll(headmask);
        if (isHead) {
            // Ownership: chHead bit says whether the chunk's first point is
            // a cell start (direct row) or a continuation (staging row).
            unsigned int row = (unsigned int)g;
            if (cellLocal == 0 && !hb)
                row = (unsigned int)(ncells + wv);
            sCellG[wid][cellLocal] = row;
        }

        // ---- layer 1 transposed: A-frag values born in registers.
        half8_t Af[3][4];
#pragma unroll
        for (int ks = 0; ks < 3; ++ks) {
            const int kb = ks * 32 + quad * 8;
            if (kb < 80) {
                const float4 wa0 = *(const float4*)&sW1[0 * CH + kb];
                const float4 wb0 = *(const float4*)&sW1[0 * CH + kb + 4];
                const float4 wa1 = *(const float4*)&sW1[1 * CH + kb];
                const float4 wb1 = *(const float4*)&sW1[1 * CH + kb + 4];
                const float4 wa2 = *(const float4*)&sW1[2 * CH + kb];
                const float4 wb2 = *(const float4*)&sW1[2 * CH + kb + 4];
                const float4 wa3 = *(const float4*)&sW1[3 * CH + kb];
                const float4 wb3 = *(const float4*)&sW1[3 * CH + kb + 4];
                const float4 ba  = *(const float4*)&sb1[kb];
                const float4 bb  = *(const float4*)&sb1[kb + 4];
                float w0[8] = {wa0.x, wa0.y, wa0.z, wa0.w, wb0.x, wb0.y, wb0.z, wb0.w};
                float w1[8] = {wa1.x, wa1.y, wa1.z, wa1.w, wb1.x, wb1.y, wb1.z, wb1.w};
                float w2[8] = {wa2.x, wa2.y, wa2.z, wa2.w, wb2.x, wb2.y, wb2.z, wb2.w};
                float w3[8] = {wa3.x, wa3.y, wa3.z, wa3.w, wb3.x, wb3.y, wb3.z, wb3.w};
                float bv[8] = {ba.x, ba.y, ba.z, ba.w, bb.x, bb.y, bb.z, bb.w};
#pragma unroll
                for (int mt = 0; mt < 4; ++mt) {
                    half8_t v;
#pragma unroll
                    for (int j = 0; j < 8; ++j) {
                        float hv = bv[j];
                        hv = fmaf(pmx[mt], w0[j], hv);
                        hv = fmaf(pmy[mt], w1[j], hv);
                        hv = fmaf(pmz[mt], w2[j], hv);
                        hv = fmaf(pmw[mt], w3[j], hv);
                        v[j] = (_Float16)fmaxf(hv, 0.0f);
                    }
                    Af[ks][mt] = v;
                }
            } else {
                const half8_t z8 = {0, 0, 0, 0, 0, 0, 0, 0};
#pragma unroll
                for (int mt = 0; mt < 4; ++mt) Af[ks][mt] = z8;
            }
        }

        // ---- selector columns for MFMA2.
        int cl[2][8];
#pragma unroll
        for (int ks2 = 0; ks2 < 2; ++ks2)
#pragma unroll
            for (int j = 0; j < 8; ++j)
                cl[ks2][j] = __shfl(cellLocal, ks2 * 32 + quad * 8 + j);

        const int nMt2 = (ncellsW + 15) >> 4;
        _Float16* embT = &sEmb[wid][0];

        if (nMt2 == 1) {
            // ======== fast path (<=16 cells): A2 + row LUT hoisted ========
            half8_t A2h[2];
#pragma unroll
            for (int ks2 = 0; ks2 < 2; ++ks2)
#pragma unroll
                for (int j = 0; j < 8; ++j)
                    A2h[ks2][j] = (cl[ks2][j] == m15) ? (_Float16)1 : (_Float16)0;
            unsigned int rowr[4];
#pragma unroll
            for (int r = 0; r < 4; ++r) {
                const int cell = quad * 4 + r;
                rowr[r] = (cell < ncellsW) ? sCellG[wid][cell] : 0xFFFFFFFFu;
            }

#pragma unroll 1
            for (int nt = 0; nt < 5; ++nt) {
                f32x4_t acc[4];
#pragma unroll
                for (int mt = 0; mt < 4; ++mt) acc[mt] = (f32x4_t){0.0f, 0.0f, 0.0f, 0.0f};
#pragma unroll
                for (int ks = 0; ks < 3; ++ks) {
                    const half8_t Bf = *(const half8_t*)
                        &sW2T[(nt * 16 + m15) * HSTR + ks * 32 + quad * 8];
#pragma unroll
                    for (int mt = 0; mt < 4; ++mt)
                        acc[mt] = __builtin_amdgcn_mfma_f32_16x16x32_f16(
                            Af[ks][mt], Bf, acc[mt], 0, 0, 0);
                }
                const float bb2 = sb2f[nt * 16 + m15];
#pragma unroll
                for (int mt = 0; mt < 4; ++mt) {
                    const f32x4_t a = acc[mt];
                    half4_t v;
                    v[0] = (_Float16)fmaxf(a[0] + bb2, 0.0f);
                    v[1] = (_Float16)fmaxf(a[1] + bb2, 0.0f);
                    v[2] = (_Float16)fmaxf(a[2] + bb2, 0.0f);
                    v[3] = (_Float16)fmaxf(a[3] + bb2, 0.0f);
                    *(half4_t*)&embT[m15 * ESTR + mt * 16 + quad * 4] = v;
                }
                half8_t B2[2];
#pragma unroll
                for (int ks2 = 0; ks2 < 2; ++ks2)
                    B2[ks2] = *(const half8_t*)&embT[m15 * ESTR + ks2 * 32 + quad * 8];

                f32x4_t acc2 = (f32x4_t){0.0f, 0.0f, 0.0f, 0.0f};
#pragma unroll
                for (int ks2 = 0; ks2 < 2; ++ks2)
                    acc2 = __builtin_amdgcn_mfma_f32_16x16x32_f16(
                        A2h[ks2], B2[ks2], acc2, 0, 0, 0);

                float* const plane = sums + (size_t)nt * (size_t)P;
#pragma unroll
                for (int r = 0; r < 4; ++r)
                    if (rowr[r] != 0xFFFFFFFFu)
                        plane[((size_t)rowr[r] << 4) + m15] = acc2[r];
            }
        } else {
            // ======== general path (>16 cells in chunk) ========
#pragma unroll 1
            for (int nt = 0; nt < 5; ++nt) {
                f32x4_t acc[4];
#pragma unroll
                for (int mt = 0; mt < 4; ++mt) acc[mt] = (f32x4_t){0.0f, 0.0f, 0.0f, 0.0f};
#pragma unroll
                for (int ks = 0; ks < 3; ++ks) {
                    const half8_t Bf = *(const half8_t*)
                        &sW2T[(nt * 16 + m15) * HSTR + ks * 32 + quad * 8];
#pragma unroll
                    for (int mt = 0; mt < 4; ++mt)
                        acc[mt] = __builtin_amdgcn_mfma_f32_16x16x32_f16(
                            Af[ks][mt], Bf, acc[mt], 0, 0, 0);
                }
                const float bb2 = sb2f[nt * 16 + m15];
#pragma unroll
                for (int mt = 0; mt < 4; ++mt) {
                    const f32x4_t a = acc[mt];
                    half4_t v;
                    v[0] = (_Float16)fmaxf(a[0] + bb2, 0.0f);
                    v[1] = (_Float16)fmaxf(a[1] + bb2, 0.0f);
                    v[2] = (_Float16)fmaxf(a[2] + bb2, 0.0f);
                    v[3] = (_Float16)fmaxf(a[3] + bb2, 0.0f);
                    *(half4_t*)&embT[m15 * ESTR + mt * 16 + quad * 4] = v;
                }
                half8_t B2[2];
#pragma unroll
                for (int ks2 = 0; ks2 < 2; ++ks2)
                    B2[ks2] = *(const half8_t*)&embT[m15 * ESTR + ks2 * 32 + quad * 8];

                float* const plane = sums + (size_t)nt * (size_t)P;
                for (int mt2 = 0; mt2 < nMt2; ++mt2) {
                    const int m2 = mt2 * 16 + m15;
                    f32x4_t acc2 = (f32x4_t){0.0f, 0.0f, 0.0f, 0.0f};
#pragma unroll
                    for (int ks2 = 0; ks2 < 2; ++ks2) {
                        half8_t A2;
#pragma unroll
                        for (int j = 0; j < 8; ++j)
                            A2[j] = (cl[ks2][j] == m2) ? (_Float16)1 : (_Float16)0;
                        acc2 = __builtin_amdgcn_mfma_f32_16x16x32_f16(
                            A2, B2[ks2], acc2, 0, 0, 0);
                    }
#pragma unroll
                    for (int r = 0; r < 4; ++r) {
                        const int cell = mt2 * 16 + quad * 4 + r;
                        if (cell < ncellsW) {
                            const unsigned int row = sCellG[wid][cell];
                            plane[((size_t)row << 4) + m15] = acc2[r];
                        }
                    }
                }
            }
        }
    }
}

// ---------------------------------------------------------------------------
// Head: mean -> 1x1 conv -> BN -> relu -> out (fp32). Mean staged f16.
// Folds staged head-partials (plane rows ncells+b) and gates on cnt>0.
// Block 0 additionally runs the diagnostics beacon (absorbed k_diag).
// ---------------------------------------------------------------------------
#define MPAD 84

__global__ __launch_bounds__(256) void k_head(
    const float* __restrict__ sums,
    const unsigned int* __restrict__ cnt,
    const unsigned int* __restrict__ offs,
    const void* __restrict__ Wp_raw,
    const void* __restrict__ bp_raw,
    const void* __restrict__ gamma_raw,
    const void* __restrict__ beta_raw,
    const void* __restrict__ rmean_raw,
    const void* __restrict__ rvar_raw,
    const unsigned int* __restrict__ flags,
    const unsigned int* __restrict__ magic,
    float* __restrict__ out,
    int b0, int ncells, int P, int hostbits)
{
    __shared__ float sWp[CH * COUT_];
    __shared__ _Float16 sMean[BEVW * MPAD];
    __shared__ float sAlpha[COUT_], sDelta[COUT_];
    __shared__ float sRed[256];
    __shared__ unsigned int sCredu[256];

    const int t = threadIdx.x;
    const int blk = blockIdx.x;
    const int bl = blk >> 7, hrow = blk & 127;
    const int bg = b0 + bl;
    const int wf32 = (int)flags[0];

    if (wf32) {
        const float* Wp = (const float*)Wp_raw;
        for (int i = t; i < CH * COUT_; i += 256) sWp[i] = Wp[i];
        if (t < COUT_) {
            const float rs = rsqrtf(((const float*)rvar_raw)[t] + 1e-5f);
            const float al = ((const float*)gamma_raw)[t] * rs;
            sAlpha[t] = al;
            sDelta[t] = al * (((const float*)bp_raw)[t] - ((const float*)rmean_raw)[t])
                        + ((const float*)beta_raw)[t];
        }
    } else {
        const unsigned short* Wp = (const unsigned short*)Wp_raw;
        for (int i = t; i < CH * COUT_; i += 256) sWp[i] = bf2f(Wp[i]);
        if (t < COUT_) {
            const float rs = rsqrtf(bf2f(((const unsigned short*)rvar_raw)[t]) + 1e-5f);
            const float al = bf2f(((const unsigned short*)gamma_raw)[t]) * rs;
            sAlpha[t] = al;
            sDelta[t] = al * (bf2f(((const unsigned short*)bp_raw)[t])
                              - bf2f(((const unsigned short*)rmean_raw)[t]))
                        + bf2f(((const unsigned short*)beta_raw)[t]);
        }
    }

    const int cellbase = bl * HW_ + hrow * BEVW;
    for (int i = t; i < BEVW * 20; i += 256) {
        const int w = i / 20, c4 = i % 20;
        const int nt = c4 >> 2, q = c4 & 3;
        const int cell = cellbase + w;
        const unsigned int c = cnt[cell];
        float4 s = {0.0f, 0.0f, 0.0f, 0.0f};
        if (c > 0) {
            const float4* plane4 = (const float4*)(sums + (size_t)nt * (size_t)P);
            s = plane4[cell * 4 + q];
            const unsigned int o = offs[cell];
            const int bA = (int)(o >> 6) + 1;
            const int bB = (int)((o + c - 1) >> 6);
            for (int b = bA; b <= bB; ++b) {
                const float4 st = plane4[(ncells + b) * 4 + q];
                s.x += st.x; s.y += st.y; s.z += st.z; s.w += st.w;
            }
        }
        const float inv = 1.0f / fmaxf((float)c, 1.0f);
        _Float16* m = &sMean[w * MPAD + c4 * 4];
        m[0] = (_Float16)(s.x * inv);
        m[1] = (_Float16)(s.y * inv);
        m[2] = (_Float16)(s.z * inv);
        m[3] = (_Float16)(s.w * inv);
    }
    __syncthreads();

    const int v = t >> 6;
    const int w = (t & 63) + (v & 1) * 64;
    const int dbase = (v >> 1) * 64;

    float acc[64];
#pragma unroll
    for (int j = 0; j < 64; ++j) acc[j] = 0.0f;

    const _Float16* mrow = &sMean[w * MPAD];
#pragma unroll 2
    for (int c = 0; c < CH; ++c) {
        const float m = (float)mrow[c];
        const float4* wrow = (const float4*)&sWp[c * COUT_ + dbase];
#pragma unroll
        for (int j4 = 0; j4 < 16; ++j4) {
            const float4 wv = wrow[j4];
            acc[j4 * 4 + 0] = fmaf(m, wv.x, acc[j4 * 4 + 0]);
            acc[j4 * 4 + 1] = fmaf(m, wv.y, acc[j4 * 4 + 1]);
            acc[j4 * 4 + 2] = fmaf(m, wv.z, acc[j4 * 4 + 2]);
            acc[j4 * 4 + 3] = fmaf(m, wv.w, acc[j4 * 4 + 3]);
        }
    }

#pragma unroll
    for (int j = 0; j < 64; ++j) {
        const int d = dbase + j;
        float o = fmaxf(fmaf(acc[j], sAlpha[d], sDelta[d]), 0.0f);
        o = fminf(o, 512.0f);
        out[(((size_t)bg * COUT_ + d) * BEVH + hrow) * BEVW + w] = o;
    }

    // ---- diagnostics beacon (block 0 only; healthy run writes nothing).
    if (blk == 0) {
        unsigned int cs = 0;
        for (int i = t; i < HW_; i += 256) cs += cnt[i];
        float sl = 0.0f;
        for (int i = t; i < CH * CH; i += 256) sl += fabsf(sums[i]);
        __syncthreads();
        sRed[t] = sl;
        sCredu[t] = cs;
        __syncthreads();
        for (int s = 128; s > 0; s >>= 1) {
            if (t < s) { sRed[t] += sRed[t + s]; sCredu[t] += sCredu[t + s]; }
            __syncthreads();
        }
        if (t == 0) {
            int code = hostbits;
            if (*magic != 0xCAFEBABEu) code |= 1;
            if (sCredu[0] < 1000u)     code |= 2;
            if (!(sRed[0] > 0.0f))     code |= 4;
            if (code) {
                code |= (int)(flags[0] ? 32 : 0);
                code |= (int)(flags[1] ? 64 : 0);
                out[0] = 1024.0f * (float)code;
            }
        }
    }
}

extern "C" void kernel_launch(void* const* d_in, const int* in_sizes, int n_in,
                              void* d_out, int out_size, void* d_ws, size_t ws_size,
                              hipStream_t stream) {
    const void* pts   = d_in[0];
    const void* W1    = d_in[1];
    const void* b1    = d_in[2];
    const void* W2    = d_in[3];
    const void* b2    = d_in[4];
    const void* Wp    = d_in[5];
    const void* bp    = d_in[6];
    const void* gamma = d_in[7];
    const void* beta  = d_in[8];
    const void* rmean = d_in[9];
    const void* rvar  = d_in[10];

    int hostbits = 0;
    if (n_in != 11 ||
        in_sizes[0] != B_ * NP_ * 4 ||
        in_sizes[1] != 4 * CH  || in_sizes[2] != CH ||
        in_sizes[3] != CH * CH || in_sizes[4] != CH ||
        in_sizes[5] != CH * COUT_ || in_sizes[6] != COUT_ ||
        out_size != B_ * COUT_ * HW_)
        hostbits |= 8;
    if (ws_size < SCRATCH_OFF + PER_BATCH + EXTRA_BYTES) hostbits |= 16;

    unsigned int* flags = (unsigned int*)d_ws;
    unsigned int* magic = (unsigned int*)((char*)d_ws + MAGIC_OFF);
    char* base = (char*)d_ws + SCRATCH_OFF;
    const size_t avail = (ws_size > SCRATCH_OFF + EXTRA_BYTES)
                       ? (ws_size - SCRATCH_OFF - EXTRA_BYTES) : PER_BATCH;
    int nb = (int)(avail / PER_BATCH);
    if (nb < 1) nb = 1;
    if (nb > B_) nb = B_;

    // Layout: cnt | sums (5 planes, incl. staging rows) | offs(+4) | cursor |
    //         chHead | psorted8 (16B-aligned) | scell16
    unsigned int*   cnt      = (unsigned int*)base;
    float*          sums     = (float*)(cnt + (size_t)nb * HW_);
    const size_t    sumsFl   = (size_t)5 * ((size_t)nb * HW_ + (size_t)nb * NCHK) * 16;
    unsigned int*   offs     = (unsigned int*)(sums + sumsFl);
    unsigned int*   cursor   = offs + (size_t)nb * HW_ + 4;
    unsigned char*  chHead   = (unsigned char*)(cursor + (size_t)nb * HW_);
    char*           palign   = (char*)chHead + (size_t)nb * NCHK;
    palign = (char*)(((size_t)palign + 15) & ~(size_t)15);
    ushort4*        psorted8 = (ushort4*)palign;
    unsigned short* scell16  = (unsigned short*)(psorted8 + (size_t)nb * NP_);

    for (int b0 = 0; b0 < B_; b0 += nb) {
        const int bcnt = (B_ - b0 < nb) ? (B_ - b0) : nb;
        const int ncells = bcnt * HW_;
        const int npts   = bcnt * NP_;
        const int nblk   = ncells >> 10;      // 1024 cells per scan block
        const int P      = (ncells + bcnt * NCHK) * 16;   // plane stride (f32)

        // Zero cnt + diag window (contiguous) + chHead; blocks 0/1 detect.
        k_init<<<128, 256, 0, stream>>>(
            (float4*)cnt, ncells / 4 + 1600,
            (unsigned int*)chHead, (bcnt * NCHK + 3) / 4,
            (const unsigned short*)W1, (const unsigned short*)pts, flags);

        k_bin<<<(npts + 255) / 256, 256, 0, stream>>>(
            pts, flags, cnt, b0, npts);

        k_scan<<<nblk, 256, 0, stream>>>(cnt, offs, cursor, chHead,
                                         nblk, ncells);

        k_scatteridx<<<(npts + 255) / 256, 256, 0, stream>>>(
            pts, flags, cursor, psorted8, scell16, b0, npts);

        k_mlp_mfma<<<1280, 256, 0, stream>>>(
            psorted8, scell16, W1, b1, W2, b2, flags, magic, offs, chHead,
            sums, ncells, P);

        k_head<<<bcnt * BEVH, 256, 0, stream>>>(
            sums, cnt, offs, Wp, bp, gamma, beta, rmean, rvar, flags, magic,
            (float*)d_out, b0, ncells, P, hostbits);
    }
}

// Round 7
// 248.926 us; speedup vs baseline: 1.2070x; 1.0129x over previous
//
#include <hip/hip_runtime.h>
#include <hip/hip_bf16.h>

// PointsToBEV round 21. R20: k_mlp fell out of top-5; k_head (55us) is now
// the wall: scalar-FMA GEMM, MfmaUtil 0, 1360 ds_read + 5120 v_fma per
// thread, 2 blocks/CU -> LDS/issue bound. R21: MFMA head. Per block (one
// hrow): M=128 douts x N=128 cells x K=80 via mfma_f32_16x16x32_f16, A =
// Wp^T in hi+lo f16 split (residual error ~f16^2 -> head precision
// unchanged), B = sMean[cell][k] f16 (already fragment-layout). Strides 104
// (16B-aligned, 2-way-bank-free). D layout: col=cell -> stores are 4x64B
// full lines. 96 MFMA + ~36 ds_read_b128 per wave replaces 5120 FMA + 1360
// ds_read per thread. Everything else unchanged from R20.

#define B_    4
#define NP_   200000
#define CH    80
#define COUT_ 128
#define BEVH  128
#define BEVW  128
#define HW_   (BEVH * BEVW)
#define NCHK  (NP_ / 64)        // 3125 chunks per batch (NP_ % 64 == 0)

// Per-batch bytes: cnt(HW u32) + sums+staging((HW+NCHK)*80 f32) +
// offs(HW u32 +pad) + cursor(HW u32) + chHead(NCHK u8) + psorted8(NP*8) +
// scell16(NP*2)
#define PER_BATCH ((size_t)HW_ * 332 + (size_t)NCHK * 321 + (size_t)NP_ * 10)
#define EXTRA_BYTES 512

#define MAGIC_OFF   128
#define SCRATCH_OFF 256

typedef _Float16 half4_t __attribute__((ext_vector_type(4)));
typedef _Float16 half8_t __attribute__((ext_vector_type(8)));
typedef float    f32x4_t __attribute__((ext_vector_type(4)));

#define HSTR 104   // W2T k-stride in f16 (52 dwords -> 2-way banks, free)
#define ESTR 72    // embT pt-stride in f16 (36 dwords -> 2-way banks, free)
#define MSTR 104   // sMean k-stride in f16 (16B-aligned, 2-way free)
#define WSTR 104   // sWpT k-stride in f16 (16B-aligned, 2-way free)

__device__ __forceinline__ float bf2f(unsigned short u) {
    return __uint_as_float(((unsigned int)u) << 16);
}
__device__ __forceinline__ unsigned short f2h(float f) {
    return __builtin_bit_cast(unsigned short, (_Float16)f);
}
__device__ __forceinline__ float h2f(unsigned short u) {
    return (float)__builtin_bit_cast(_Float16, u);
}

__device__ __forceinline__ int cell_of(float px, float py, int bloc) {
    const int ix = (int)floorf((px + 50.0f) / 0.78125f);
    const int iy = (int)floorf((py + 50.0f) / 0.78125f);
    if (ix < 0 || ix >= BEVW || iy < 0 || iy >= BEVH) return -1;
    return bloc * HW_ + iy * BEVW + ix;
}

__device__ __forceinline__ void load_pt(const void* pts_raw, size_t pidx, int pf32,
                                        float& px, float& py, float& pz, float& pw) {
    if (pf32) {
        const float4 p = ((const float4*)pts_raw)[pidx];
        px = p.x; py = p.y; pz = p.z; pw = p.w;
    } else {
        const ushort4 p = ((const ushort4*)pts_raw)[pidx];
        px = bf2f(p.x); py = bf2f(p.y); pz = bf2f(p.z); pw = bf2f(p.w);
    }
}

// ---------------------------------------------------------------------------
// k_init: grid-stride zero of cnt + diag window (contiguous float4) and the
// chHead bytes; blocks 0/1 additionally run the dtype probes.
// flags[0]=params fp32, flags[1]=points fp32.
// ---------------------------------------------------------------------------
__global__ __launch_bounds__(256) void k_init(
    float4* __restrict__ zp, int n4,
    unsigned int* __restrict__ chz, int nc4,
    const unsigned short* __restrict__ w1bits,
    const unsigned short* __restrict__ ptsbits,
    unsigned int* __restrict__ flags)
{
    const int t = threadIdx.x;
    if (blockIdx.x < 2 && t < 64) {
        const int which = blockIdx.x;
        const unsigned short* src = which ? ptsbits : w1bits;
        const int n = which ? 512 : 320;
        float m = 0.0f;
        for (int i = t; i < n; i += 64) {
            const float a = fabsf(bf2f(src[i]));
            if (a == a) m = fmaxf(m, a);
        }
#pragma unroll
        for (int off = 32; off > 0; off >>= 1)
            m = fmaxf(m, __shfl_down(m, off));
        if (t == 0) flags[which] = (m > 1.0e6f) ? 1u : 0u;
    }
    const float4 z = {0.0f, 0.0f, 0.0f, 0.0f};
    for (int i = blockIdx.x * 256 + t; i < n4; i += gridDim.x * 256)
        zp[i] = z;
    for (int i = blockIdx.x * 256 + t; i < nc4; i += gridDim.x * 256)
        chz[i] = 0u;
}

// ---------------------------------------------------------------------------
// Phase A: histogram.
// ---------------------------------------------------------------------------
__global__ __launch_bounds__(256) void k_bin(
    const void* __restrict__ pts_raw,
    const unsigned int* __restrict__ flags,
    unsigned int* __restrict__ cnt,
    int b0, int npts)
{
    const int gid = blockIdx.x * 256 + threadIdx.x;
    if (gid >= npts) return;
    float px, py, pz, pw;
    load_pt(pts_raw, (size_t)b0 * NP_ + gid, (int)flags[1], px, py, pz, pw);
    const int g = cell_of(px, py, gid / NP_);
    if (g >= 0) atomicAdd(&cnt[g], 1u);
}

// ---------------------------------------------------------------------------
// Phase B (fused scan): each block redundantly sums cnt[0..base) for its
// prefix (L2-hot, no cross-block sync), then local-scans its 1024 cells,
// writes offs (+sentinel), cursor, and marks chHead[chunk] when a nonempty
// cell starts exactly at a 64-point chunk boundary.
// ---------------------------------------------------------------------------
__global__ __launch_bounds__(256) void k_scan(
    const unsigned int* __restrict__ cnt,
    unsigned int* __restrict__ offs,
    unsigned int* __restrict__ cursor,
    unsigned char* __restrict__ chHead,
    int nblocks, int n)
{
    __shared__ unsigned int sd[256];
    __shared__ unsigned int sBase;
    const int t = threadIdx.x;
    const int blk = blockIdx.x;
    const int i0 = blk * 1024 + t * 4;
    const unsigned int c0 = cnt[i0], c1 = cnt[i0 + 1],
                       c2 = cnt[i0 + 2], c3 = cnt[i0 + 3];
    const unsigned int s4 = c0 + c1 + c2 + c3;

    // base = sum of all cells before this block (redundant re-read).
    unsigned int bsum = 0;
    const int q4 = blk << 8;                  // (blk*1024)/4 uint4 records
    const uint4* cnt4 = (const uint4*)cnt;
    for (int i = t; i < q4; i += 256) {
        const uint4 v = cnt4[i];
        bsum += v.x + v.y + v.z + v.w;
    }
    sd[t] = bsum;
    __syncthreads();
    for (int d = 128; d > 0; d >>= 1) {
        if (t < d) sd[t] += sd[t + d];
        __syncthreads();
    }
    if (t == 0) sBase = sd[0];
    __syncthreads();

    // local inclusive scan of per-thread s4.
    sd[t] = s4;
    __syncthreads();
    for (int d = 1; d < 256; d <<= 1) {
        const unsigned int add = (t >= d) ? sd[t - d] : 0u;
        __syncthreads();
        sd[t] += add;
        __syncthreads();
    }
    unsigned int run = sBase + sd[t] - s4;    // exclusive prefix
    offs[i0] = run;     cursor[i0] = run;
    if (c0 && !(run & 63u)) chHead[run >> 6] = 1;            run += c0;
    offs[i0 + 1] = run; cursor[i0 + 1] = run;
    if (c1 && !(run & 63u)) chHead[run >> 6] = 1;            run += c1;
    offs[i0 + 2] = run; cursor[i0 + 2] = run;
    if (c2 && !(run & 63u)) chHead[run >> 6] = 1;            run += c2;
    offs[i0 + 3] = run; cursor[i0 + 3] = run;
    if (c3 && !(run & 63u)) chHead[run >> 6] = 1;            run += c3;
    if (blk == nblocks - 1 && t == 255) offs[n] = run;
}

// ---------------------------------------------------------------------------
// Phase C: materialize the sort — packed 8B fp16 cell-delta + u16 cell.
// ---------------------------------------------------------------------------
__global__ __launch_bounds__(256) void k_scatteridx(
    const void* __restrict__ pts_raw,
    const unsigned int* __restrict__ flags,
    unsigned int* __restrict__ cursor,
    ushort4* __restrict__ psorted8,
    unsigned short* __restrict__ scell16,
    int b0, int npts)
{
    const int gid = blockIdx.x * 256 + threadIdx.x;
    if (gid >= npts) return;
    float px, py, pz, pw;
    load_pt(pts_raw, (size_t)b0 * NP_ + gid, (int)flags[1], px, py, pz, pw);
    const int g = cell_of(px, py, gid / NP_);
    if (g < 0) return;
    const unsigned int pos = atomicAdd(&cursor[g], 1u);
    const int cellin = g & (HW_ - 1);
    const float cx = fmaf((float)(cellin & 127), 0.78125f, -49.609375f);
    const float cy = fmaf((float)(cellin >> 7), 0.78125f, -49.609375f);
    ushort4 r;
    r.x = f2h(px - cx);
    r.y = f2h(py - cy);
    r.z = f2h(pz);
    r.w = f2h(pw);
    psorted8[pos] = r;
    scell16[pos] = (unsigned short)g;
}

// ---------------------------------------------------------------------------
// Phase D (persistent MFMA): waves grid-stride over 64-point chunks.
// Plane-major sums: element (row, ch = nt*16+m15) at sums[nt*P + row*16+m15].
// chHead byte (independent early load) replaces the dependent offs[g] read.
// ---------------------------------------------------------------------------
__global__ __launch_bounds__(256, 2) void k_mlp_mfma(
    const ushort4* __restrict__ psorted8,
    const unsigned short* __restrict__ scell16,
    const void* __restrict__ W1_raw,
    const void* __restrict__ b1_raw,
    const void* __restrict__ W2_raw,
    const void* __restrict__ b2_raw,
    const unsigned int* __restrict__ flags,
    unsigned int* __restrict__ magic,
    const unsigned int* __restrict__ offs,    // ncells+1 (sentinel = total)
    const unsigned char* __restrict__ chHead,
    float* __restrict__ sums,                 // 5 planes of P floats
    int ncells, int P)
{
    __shared__ float sW1[4 * CH];             // [f][k]
    __shared__ float sb1[CH];
    __shared__ float sb2f[CH];
    __shared__ _Float16 sW2T[80 * HSTR];      // [ch_out][k], k 80..95 zero
    __shared__ _Float16 sEmb[4][16 * ESTR];   // per-wave embT slice [ch16][pt]
    __shared__ unsigned int sCellG[4][64];

    const int t = threadIdx.x;
    const int wf32 = (int)flags[0];

    // ---- staging (W2 read coalesced, LDS-scatter write).
    if (wf32) {
        const float* W1 = (const float*)W1_raw;
        const float* b1 = (const float*)b1_raw;
        const float* b2 = (const float*)b2_raw;
        for (int i = t; i < 4 * CH; i += 256) sW1[i] = W1[i];
        if (t < CH) { sb1[t] = b1[t]; sb2f[t] = b2[t]; }
        const float* W2 = (const float*)W2_raw;
        for (int i = t; i < CH * CH; i += 256)      // i = c*80 + d, coalesced
            sW2T[(i % CH) * HSTR + i / CH] = (_Float16)W2[i];
    } else {
        const unsigned short* W1 = (const unsigned short*)W1_raw;
        const unsigned short* b1 = (const unsigned short*)b1_raw;
        const unsigned short* b2 = (const unsigned short*)b2_raw;
        for (int i = t; i < 4 * CH; i += 256) sW1[i] = bf2f(W1[i]);
        if (t < CH) { sb1[t] = bf2f(b1[t]); sb2f[t] = bf2f(b2[t]); }
        const unsigned short* W2 = (const unsigned short*)W2_raw;
        for (int i = t; i < CH * CH; i += 256)      // coalesced
            sW2T[(i % CH) * HSTR + i / CH] = (_Float16)bf2f(W2[i]);
    }
    // zero the k = 80..103 pad of every row
    for (int i = t; i < CH * (HSTR - CH); i += 256)
        sW2T[(i / (HSTR - CH)) * HSTR + CH + (i % (HSTR - CH))] = (_Float16)0.0f;
    __syncthreads();

    if (blockIdx.x == 0 && t == 0) *magic = 0xCAFEBABEu;

    const int end = (int)offs[ncells];
    const int lane = t & 63;
    const int wid = t >> 6;
    const int m15 = lane & 15;
    const int quad = lane >> 4;
    const int totalWaves = gridDim.x * 4;
    const int nChunks = (end + 63) >> 6;

    for (int wv = blockIdx.x * 4 + wid; wv < nChunks; wv += totalWaves) {
        const int chunkStart = wv * 64;
        const int p = chunkStart + lane;
        const bool active = p < end;

        // ---- independent early loads: chunk-head bit + own cell + gathers.
        const unsigned char hb = chHead[wv];

        const int pOwn = active ? p : (end - 1);
        const int g = active ? (int)scell16[pOwn] : -1;

        ushort4 prm[4];
        int gm[4];
#pragma unroll
        for (int mt = 0; mt < 4; ++mt) {
            int idx = chunkStart + mt * 16 + m15;
            if (idx > end - 1) idx = end - 1;
            prm[mt] = psorted8[idx];            // 16-lane broadcast, L1/L2
            gm[mt] = (int)scell16[idx];
        }

        float pmx[4], pmy[4], pmz[4], pmw[4];
#pragma unroll
        for (int mt = 0; mt < 4; ++mt) {
            const int cellin = gm[mt] & (HW_ - 1);
            const float cx = fmaf((float)(cellin & 127), 0.78125f, -49.609375f);
            const float cy = fmaf((float)(cellin >> 7), 0.78125f, -49.609375f);
            pmx[mt] = cx + h2f(prm[mt].x);
            pmy[mt] = cy + h2f(prm[mt].y);
            pmz[mt] = h2f(prm[mt].z);
            pmw[mt] = h2f(prm[mt].w);
        }

        // ---- segment bookkeeping (R13-verified).
        const int gprev = __shfl_up(g, 1);
        const bool isHead = active && (lane == 0 || gprev != g);
        const unsigned long long headmask = __ballot(isHead);
        const int cellLocal = active
            ? (__popcll(headmask << (63 - lane)) - 1) : 255;
        const int ncellsW = __popcll(headmask);
        if (isHead) {
            unsigned int row = (unsigned int)g;
            if (cellLocal == 0 && !hb)
                row = (unsigned int)(ncells + wv);
            sCellG[wid][cellLocal] = row;
        }

        // ---- layer 1 transposed: A-frag values born in registers.
        half8_t Af[3][4];
#pragma unroll
        for (int ks = 0; ks < 3; ++ks) {
            const int kb = ks * 32 + quad * 8;
            if (kb < 80) {
                const float4 wa0 = *(const float4*)&sW1[0 * CH + kb];
                const float4 wb0 = *(const float4*)&sW1[0 * CH + kb + 4];
                const float4 wa1 = *(const float4*)&sW1[1 * CH + kb];
                const float4 wb1 = *(const float4*)&sW1[1 * CH + kb + 4];
                const float4 wa2 = *(const float4*)&sW1[2 * CH + kb];
                const float4 wb2 = *(const float4*)&sW1[2 * CH + kb + 4];
                const float4 wa3 = *(const float4*)&sW1[3 * CH + kb];
                const float4 wb3 = *(const float4*)&sW1[3 * CH + kb + 4];
                const float4 ba  = *(const float4*)&sb1[kb];
                const float4 bb  = *(const float4*)&sb1[kb + 4];
                float w0[8] = {wa0.x, wa0.y, wa0.z, wa0.w, wb0.x, wb0.y, wb0.z, wb0.w};
                float w1[8] = {wa1.x, wa1.y, wa1.z, wa1.w, wb1.x, wb1.y, wb1.z, wb1.w};
                float w2[8] = {wa2.x, wa2.y, wa2.z, wa2.w, wb2.x, wb2.y, wb2.z, wb2.w};
                float w3[8] = {wa3.x, wa3.y, wa3.z, wa3.w, wb3.x, wb3.y, wb3.z, wb3.w};
                float bv[8] = {ba.x, ba.y, ba.z, ba.w, bb.x, bb.y, bb.z, bb.w};
#pragma unroll
                for (int mt = 0; mt < 4; ++mt) {
                    half8_t v;
#pragma unroll
                    for (int j = 0; j < 8; ++j) {
                        float hv = bv[j];
                        hv = fmaf(pmx[mt], w0[j], hv);
                        hv = fmaf(pmy[mt], w1[j], hv);
                        hv = fmaf(pmz[mt], w2[j], hv);
                        hv = fmaf(pmw[mt], w3[j], hv);
                        v[j] = (_Float16)fmaxf(hv, 0.0f);
                    }
                    Af[ks][mt] = v;
                }
            } else {
                const half8_t z8 = {0, 0, 0, 0, 0, 0, 0, 0};
#pragma unroll
                for (int mt = 0; mt < 4; ++mt) Af[ks][mt] = z8;
            }
        }

        // ---- selector columns for MFMA2.
        int cl[2][8];
#pragma unroll
        for (int ks2 = 0; ks2 < 2; ++ks2)
#pragma unroll
            for (int j = 0; j < 8; ++j)
                cl[ks2][j] = __shfl(cellLocal, ks2 * 32 + quad * 8 + j);

        const int nMt2 = (ncellsW + 15) >> 4;
        _Float16* embT = &sEmb[wid][0];

        if (nMt2 == 1) {
            // ======== fast path (<=16 cells): A2 + row LUT hoisted ========
            half8_t A2h[2];
#pragma unroll
            for (int ks2 = 0; ks2 < 2; ++ks2)
#pragma unroll
                for (int j = 0; j < 8; ++j)
                    A2h[ks2][j] = (cl[ks2][j] == m15) ? (_Float16)1 : (_Float16)0;
            unsigned int rowr[4];
#pragma unroll
            for (int r = 0; r < 4; ++r) {
                const int cell = quad * 4 + r;
                rowr[r] = (cell < ncellsW) ? sCellG[wid][cell] : 0xFFFFFFFFu;
            }

#pragma unroll 1
            for (int nt = 0; nt < 5; ++nt) {
                f32x4_t acc[4];
#pragma unroll
                for (int mt = 0; mt < 4; ++mt) acc[mt] = (f32x4_t){0.0f, 0.0f, 0.0f, 0.0f};
#pragma unroll
                for (int ks = 0; ks < 3; ++ks) {
                    const half8_t Bf = *(const half8_t*)
                        &sW2T[(nt * 16 + m15) * HSTR + ks * 32 + quad * 8];
#pragma unroll
                    for (int mt = 0; mt < 4; ++mt)
                        acc[mt] = __builtin_amdgcn_mfma_f32_16x16x32_f16(
                            Af[ks][mt], Bf, acc[mt], 0, 0, 0);
                }
                const float bb2 = sb2f[nt * 16 + m15];
#pragma unroll
                for (int mt = 0; mt < 4; ++mt) {
                    const f32x4_t a = acc[mt];
                    half4_t v;
                    v[0] = (_Float16)fmaxf(a[0] + bb2, 0.0f);
                    v[1] = (_Float16)fmaxf(a[1] + bb2, 0.0f);
                    v[2] = (_Float16)fmaxf(a[2] + bb2, 0.0f);
                    v[3] = (_Float16)fmaxf(a[3] + bb2, 0.0f);
                    *(half4_t*)&embT[m15 * ESTR + mt * 16 + quad * 4] = v;
                }
                half8_t B2[2];
#pragma unroll
                for (int ks2 = 0; ks2 < 2; ++ks2)
                    B2[ks2] = *(const half8_t*)&embT[m15 * ESTR + ks2 * 32 + quad * 8];

                f32x4_t acc2 = (f32x4_t){0.0f, 0.0f, 0.0f, 0.0f};
#pragma unroll
                for (int ks2 = 0; ks2 < 2; ++ks2)
                    acc2 = __builtin_amdgcn_mfma_f32_16x16x32_f16(
                        A2h[ks2], B2[ks2], acc2, 0, 0, 0);

                float* const plane = sums + (size_t)nt * (size_t)P;
#pragma unroll
                for (int r = 0; r < 4; ++r)
                    if (rowr[r] != 0xFFFFFFFFu)
                        plane[((size_t)rowr[r] << 4) + m15] = acc2[r];
            }
        } else {
            // ======== general path (>16 cells in chunk) ========
#pragma unroll 1
            for (int nt = 0; nt < 5; ++nt) {
                f32x4_t acc[4];
#pragma unroll
                for (int mt = 0; mt < 4; ++mt) acc[mt] = (f32x4_t){0.0f, 0.0f, 0.0f, 0.0f};
#pragma unroll
                for (int ks = 0; ks < 3; ++ks) {
                    const half8_t Bf = *(const half8_t*)
                        &sW2T[(nt * 16 + m15) * HSTR + ks * 32 + quad * 8];
#pragma unroll
                    for (int mt = 0; mt < 4; ++mt)
                        acc[mt] = __builtin_amdgcn_mfma_f32_16x16x32_f16(
                            Af[ks][mt], Bf, acc[mt], 0, 0, 0);
                }
                const float bb2 = sb2f[nt * 16 + m15];
#pragma unroll
                for (int mt = 0; mt < 4; ++mt) {
                    const f32x4_t a = acc[mt];
                    half4_t v;
                    v[0] = (_Float16)fmaxf(a[0] + bb2, 0.0f);
                    v[1] = (_Float16)fmaxf(a[1] + bb2, 0.0f);
                    v[2] = (_Float16)fmaxf(a[2] + bb2, 0.0f);
                    v[3] = (_Float16)fmaxf(a[3] + bb2, 0.0f);
                    *(half4_t*)&embT[m15 * ESTR + mt * 16 + quad * 4] = v;
                }
                half8_t B2[2];
#pragma unroll
                for (int ks2 = 0; ks2 < 2; ++ks2)
                    B2[ks2] = *(const half8_t*)&embT[m15 * ESTR + ks2 * 32 + quad * 8];

                float* const plane = sums + (size_t)nt * (size_t)P;
                for (int mt2 = 0; mt2 < nMt2; ++mt2) {
                    const int m2 = mt2 * 16 + m15;
                    f32x4_t acc2 = (f32x4_t){0.0f, 0.0f, 0.0f, 0.0f};
#pragma unroll
                    for (int ks2 = 0; ks2 < 2; ++ks2) {
                        half8_t A2;
#pragma unroll
                        for (int j = 0; j < 8; ++j)
                            A2[j] = (cl[ks2][j] == m2) ? (_Float16)1 : (_Float16)0;
                        acc2 = __builtin_amdgcn_mfma_f32_16x16x32_f16(
                            A2, B2[ks2], acc2, 0, 0, 0);
                    }
#pragma unroll
                    for (int r = 0; r < 4; ++r) {
                        const int cell = mt2 * 16 + quad * 4 + r;
                        if (cell < ncellsW) {
                            const unsigned int row = sCellG[wid][cell];
                            plane[((size_t)row << 4) + m15] = acc2[r];
                        }
                    }
                }
            }
        }
    }
}

// ---------------------------------------------------------------------------
// Head (R21, MFMA): mean -> 1x1 conv -> BN -> relu -> out. Per block (one
// hrow): D[dout][cell] = WpT_hi/lo (A) x mean (B), f32 accum. A-frags
// preloaded (12 half8/wave); B-frags from sMean[cell][k] (natural layout).
// Stores: col=cell -> 4x64B full lines. Folds staged partials; cnt>0 gate.
// Block 0 runs the diagnostics beacon.
// ---------------------------------------------------------------------------
__global__ __launch_bounds__(256, 2) void k_head(
    const float* __restrict__ sums,
    const unsigned int* __restrict__ cnt,
    const unsigned int* __restrict__ offs,
    const void* __restrict__ Wp_raw,
    const void* __restrict__ bp_raw,
    const void* __restrict__ gamma_raw,
    const void* __restrict__ beta_raw,
    const void* __restrict__ rmean_raw,
    const void* __restrict__ rvar_raw,
    const unsigned int* __restrict__ flags,
    const unsigned int* __restrict__ magic,
    float* __restrict__ out,
    int b0, int ncells, int P, int hostbits)
{
    __shared__ _Float16 sWpHi[COUT_ * WSTR];   // [dout][k], k 80..103 zero
    __shared__ _Float16 sWpLo[COUT_ * WSTR];
    __shared__ _Float16 sMean[BEVW * MSTR];    // [cell][k], k 80..103 zero
    __shared__ float sAlpha[COUT_], sDelta[COUT_];
    __shared__ float sRedF[4];
    __shared__ unsigned int sRedU[4];

    const int t = threadIdx.x;
    const int blk = blockIdx.x;
    const int bl = blk >> 7, hrow = blk & 127;
    const int bg = b0 + bl;
    const int wf32 = (int)flags[0];

    // ---- stage WpT hi/lo (coalesced read, LDS scatter) + alpha/delta.
    for (int i = t; i < CH * COUT_; i += 256) {
        const int d = i & 127;                 // i = c*128 + d
        const int c = i >> 7;
        const float w = wf32 ? ((const float*)Wp_raw)[i]
                             : bf2f(((const unsigned short*)Wp_raw)[i]);
        const _Float16 hi = (_Float16)w;
        sWpHi[d * WSTR + c] = hi;
        sWpLo[d * WSTR + c] = (_Float16)(w - (float)hi);
    }
    for (int i = t; i < COUT_ * (WSTR - CH); i += 256) {
        const int d = i / (WSTR - CH), k = CH + i % (WSTR - CH);
        sWpHi[d * WSTR + k] = (_Float16)0.0f;
        sWpLo[d * WSTR + k] = (_Float16)0.0f;
    }
    if (t < COUT_) {
        if (wf32) {
            const float rs = rsqrtf(((const float*)rvar_raw)[t] + 1e-5f);
            const float al = ((const float*)gamma_raw)[t] * rs;
            sAlpha[t] = al;
            sDelta[t] = al * (((const float*)bp_raw)[t] - ((const float*)rmean_raw)[t])
                        + ((const float*)beta_raw)[t];
        } else {
            const float rs = rsqrtf(bf2f(((const unsigned short*)rvar_raw)[t]) + 1e-5f);
            const float al = bf2f(((const unsigned short*)gamma_raw)[t]) * rs;
            sAlpha[t] = al;
            sDelta[t] = al * (bf2f(((const unsigned short*)bp_raw)[t])
                              - bf2f(((const unsigned short*)rmean_raw)[t]))
                        + bf2f(((const unsigned short*)beta_raw)[t]);
        }
    }

    // ---- stage mean[cell][k] f16 (+zero pad k 80..103).
    const int cellbase = bl * HW_ + hrow * BEVW;
    for (int i = t; i < BEVW * 26; i += 256) {
        const int w = i / 26, c4 = i % 26;
        _Float16* m = &sMean[w * MSTR + c4 * 4];
        if (c4 < 20) {
            const int nt = c4 >> 2, q = c4 & 3;
            const int cell = cellbase + w;
            const unsigned int c = cnt[cell];
            float4 s = {0.0f, 0.0f, 0.0f, 0.0f};
            if (c > 0) {
                const float4* plane4 = (const float4*)(sums + (size_t)nt * (size_t)P);
                s = plane4[cell * 4 + q];
                const unsigned int o = offs[cell];
                const int bA = (int)(o >> 6) + 1;
                const int bB = (int)((o + c - 1) >> 6);
                for (int b = bA; b <= bB; ++b) {
                    const float4 st = plane4[(ncells + b) * 4 + q];
                    s.x += st.x; s.y += st.y; s.z += st.z; s.w += st.w;
                }
            }
            const float inv = 1.0f / fmaxf((float)c, 1.0f);
            m[0] = (_Float16)(s.x * inv);
            m[1] = (_Float16)(s.y * inv);
            m[2] = (_Float16)(s.z * inv);
            m[3] = (_Float16)(s.w * inv);
        } else {
            m[0] = (_Float16)0.0f; m[1] = (_Float16)0.0f;
            m[2] = (_Float16)0.0f; m[3] = (_Float16)0.0f;
        }
    }
    __syncthreads();

    // ---- MFMA GEMM: wave wid owns douts [wid*32, wid*32+32).
    const int lane = t & 63;
    const int wid = t >> 6;
    const int m15 = lane & 15;
    const int quad = lane >> 4;

    half8_t Ahi[2][3], Alo[2][3];
#pragma unroll
    for (int m = 0; m < 2; ++m)
#pragma unroll
        for (int ks = 0; ks < 3; ++ks) {
            const int addr = ((wid * 2 + m) * 16 + m15) * WSTR + ks * 32 + quad * 8;
            Ahi[m][ks] = *(const half8_t*)&sWpHi[addr];
            Alo[m][ks] = *(const half8_t*)&sWpLo[addr];
        }

#pragma unroll
    for (int n = 0; n < 8; ++n) {
        half8_t Bf[3];
#pragma unroll
        for (int ks = 0; ks < 3; ++ks)
            Bf[ks] = *(const half8_t*)&sMean[(n * 16 + m15) * MSTR + ks * 32 + quad * 8];
#pragma unroll
        for (int m = 0; m < 2; ++m) {
            f32x4_t acc = (f32x4_t){0.0f, 0.0f, 0.0f, 0.0f};
#pragma unroll
            for (int ks = 0; ks < 3; ++ks) {
                acc = __builtin_amdgcn_mfma_f32_16x16x32_f16(Ahi[m][ks], Bf[ks], acc, 0, 0, 0);
                acc = __builtin_amdgcn_mfma_f32_16x16x32_f16(Alo[m][ks], Bf[ks], acc, 0, 0, 0);
            }
#pragma unroll
            for (int r = 0; r < 4; ++r) {
                const int d = (wid * 2 + m) * 16 + quad * 4 + r;
                float o = fmaxf(fmaf(acc[r], sAlpha[d], sDelta[d]), 0.0f);
                o = fminf(o, 512.0f);
                out[(((size_t)bg * COUT_ + d) * BEVH + hrow) * BEVW + n * 16 + m15] = o;
            }
        }
    }

    // ---- diagnostics beacon (block 0 only; healthy run writes nothing).
    if (blk == 0) {
        unsigned int cs = 0;
        for (int i = t; i < HW_; i += 256) cs += cnt[i];
        float sl = 0.0f;
        for (int i = t; i < CH * CH; i += 256) sl += fabsf(sums[i]);
#pragma unroll
        for (int off = 32; off > 0; off >>= 1) {
            cs += __shfl_down(cs, off);
            sl += __shfl_down(sl, off);
        }
        if (lane == 0) { sRedU[wid] = cs; sRedF[wid] = sl; }
        __syncthreads();
        if (t == 0) {
            const unsigned int csum = sRedU[0] + sRedU[1] + sRedU[2] + sRedU[3];
            const float ssum = sRedF[0] + sRedF[1] + sRedF[2] + sRedF[3];
            int code = hostbits;
            if (*magic != 0xCAFEBABEu) code |= 1;
            if (csum < 1000u)          code |= 2;
            if (!(ssum > 0.0f))        code |= 4;
            if (code) {
                code |= (int)(flags[0] ? 32 : 0);
                code |= (int)(flags[1] ? 64 : 0);
                out[0] = 1024.0f * (float)code;
            }
        }
    }
}

extern "C" void kernel_launch(void* const* d_in, const int* in_sizes, int n_in,
                              void* d_out, int out_size, void* d_ws, size_t ws_size,
                              hipStream_t stream) {
    const void* pts   = d_in[0];
    const void* W1    = d_in[1];
    const void* b1    = d_in[2];
    const void* W2    = d_in[3];
    const void* b2    = d_in[4];
    const void* Wp    = d_in[5];
    const void* bp    = d_in[6];
    const void* gamma = d_in[7];
    const void* beta  = d_in[8];
    const void* rmean = d_in[9];
    const void* rvar  = d_in[10];

    int hostbits = 0;
    if (n_in != 11 ||
        in_sizes[0] != B_ * NP_ * 4 ||
        in_sizes[1] != 4 * CH  || in_sizes[2] != CH ||
        in_sizes[3] != CH * CH || in_sizes[4] != CH ||
        in_sizes[5] != CH * COUT_ || in_sizes[6] != COUT_ ||
        out_size != B_ * COUT_ * HW_)
        hostbits |= 8;
    if (ws_size < SCRATCH_OFF + PER_BATCH + EXTRA_BYTES) hostbits |= 16;

    unsigned int* flags = (unsigned int*)d_ws;
    unsigned int* magic = (unsigned int*)((char*)d_ws + MAGIC_OFF);
    char* base = (char*)d_ws + SCRATCH_OFF;
    const size_t avail = (ws_size > SCRATCH_OFF + EXTRA_BYTES)
                       ? (ws_size - SCRATCH_OFF - EXTRA_BYTES) : PER_BATCH;
    int nb = (int)(avail / PER_BATCH);
    if (nb < 1) nb = 1;
    if (nb > B_) nb = B_;

    // Layout: cnt | sums (5 planes, incl. staging rows) | offs(+4) | cursor |
    //         chHead | psorted8 (16B-aligned) | scell16
    unsigned int*   cnt      = (unsigned int*)base;
    float*          sums     = (float*)(cnt + (size_t)nb * HW_);
    const size_t    sumsFl   = (size_t)5 * ((size_t)nb * HW_ + (size_t)nb * NCHK) * 16;
    unsigned int*   offs     = (unsigned int*)(sums + sumsFl);
    unsigned int*   cursor   = offs + (size_t)nb * HW_ + 4;
    unsigned char*  chHead   = (unsigned char*)(cursor + (size_t)nb * HW_);
    char*           palign   = (char*)chHead + (size_t)nb * NCHK;
    palign = (char*)(((size_t)palign + 15) & ~(size_t)15);
    ushort4*        psorted8 = (ushort4*)palign;
    unsigned short* scell16  = (unsigned short*)(psorted8 + (size_t)nb * NP_);

    for (int b0 = 0; b0 < B_; b0 += nb) {
        const int bcnt = (B_ - b0 < nb) ? (B_ - b0) : nb;
        const int ncells = bcnt * HW_;
        const int npts   = bcnt * NP_;
        const int nblk   = ncells >> 10;      // 1024 cells per scan block
        const int P      = (ncells + bcnt * NCHK) * 16;   // plane stride (f32)

        // Zero cnt + diag window (contiguous) + chHead; blocks 0/1 detect.
        k_init<<<128, 256, 0, stream>>>(
            (float4*)cnt, ncells / 4 + 1600,
            (unsigned int*)chHead, (bcnt * NCHK + 3) / 4,
            (const unsigned short*)W1, (const unsigned short*)pts, flags);

        k_bin<<<(npts + 255) / 256, 256, 0, stream>>>(
            pts, flags, cnt, b0, npts);

        k_scan<<<nblk, 256, 0, stream>>>(cnt, offs, cursor, chHead,
                                         nblk, ncells);

        k_scatteridx<<<(npts + 255) / 256, 256, 0, stream>>>(
            pts, flags, cursor, psorted8, scell16, b0, npts);

        k_mlp_mfma<<<1280, 256, 0, stream>>>(
            psorted8, scell16, W1, b1, W2, b2, flags, magic, offs, chHead,
            sums, ncells, P);

        k_head<<<bcnt * BEVH, 256, 0, stream>>>(
            sums, cnt, offs, Wp, bp, gamma, beta, rmean, rvar, flags, magic,
            (float*)d_out, b0, ncells, P, hostbits);
    }
}

// Round 8
// 238.437 us; speedup vs baseline: 1.2600x; 1.0440x over previous
//
#include <hip/hip_runtime.h>
#include <hip/hip_bf16.h>

// PointsToBEV round 22. R21 post-mortem: MFMA head landed (VALUBusy 21->9)
// but only 55->46us: LDS 81.4KB -> exactly 2 blocks/CU, serial
// stage->sync->GEMM exposes staging latency (all utils <15%); 1.44M bank
// conflicts from the Wp hi/lo LDS scatter-write (stride-52-dword, 8-way).
// R22: Wp A-fragments loaded DIRECTLY from global into registers (48 x 4B
// L2-hot loads/lane, fragment layout) -- sWpHi/sWpLo deleted: LDS 81->28KB
// (5 blocks/CU by LDS), conflict-free staging, ~40% less pre-sync work.
// alpha/delta hoisted to regs. k_mlp & pipeline unchanged from R21.

#define B_    4
#define NP_   200000
#define CH    80
#define COUT_ 128
#define BEVH  128
#define BEVW  128
#define HW_   (BEVH * BEVW)
#define NCHK  (NP_ / 64)        // 3125 chunks per batch (NP_ % 64 == 0)

// Per-batch bytes: cnt(HW u32) + sums+staging((HW+NCHK)*80 f32) +
// offs(HW u32 +pad) + cursor(HW u32) + chHead(NCHK u8) + psorted8(NP*8) +
// scell16(NP*2)
#define PER_BATCH ((size_t)HW_ * 332 + (size_t)NCHK * 321 + (size_t)NP_ * 10)
#define EXTRA_BYTES 512

#define MAGIC_OFF   128
#define SCRATCH_OFF 256

typedef _Float16 half4_t __attribute__((ext_vector_type(4)));
typedef _Float16 half8_t __attribute__((ext_vector_type(8)));
typedef float    f32x4_t __attribute__((ext_vector_type(4)));

#define HSTR 104   // W2T k-stride in f16 (52 dwords -> 2-way banks, free)
#define ESTR 72    // embT pt-stride in f16 (36 dwords -> 2-way banks, free)
#define MSTR 104   // sMean k-stride in f16 (16B-aligned, 2-way free)

__device__ __forceinline__ float bf2f(unsigned short u) {
    return __uint_as_float(((unsigned int)u) << 16);
}
__device__ __forceinline__ unsigned short f2h(float f) {
    return __builtin_bit_cast(unsigned short, (_Float16)f);
}
__device__ __forceinline__ float h2f(unsigned short u) {
    return (float)__builtin_bit_cast(_Float16, u);
}

__device__ __forceinline__ int cell_of(float px, float py, int bloc) {
    const int ix = (int)floorf((px + 50.0f) / 0.78125f);
    const int iy = (int)floorf((py + 50.0f) / 0.78125f);
    if (ix < 0 || ix >= BEVW || iy < 0 || iy >= BEVH) return -1;
    return bloc * HW_ + iy * BEVW + ix;
}

__device__ __forceinline__ void load_pt(const void* pts_raw, size_t pidx, int pf32,
                                        float& px, float& py, float& pz, float& pw) {
    if (pf32) {
        const float4 p = ((const float4*)pts_raw)[pidx];
        px = p.x; py = p.y; pz = p.z; pw = p.w;
    } else {
        const ushort4 p = ((const ushort4*)pts_raw)[pidx];
        px = bf2f(p.x); py = bf2f(p.y); pz = bf2f(p.z); pw = bf2f(p.w);
    }
}

// ---------------------------------------------------------------------------
// k_init: grid-stride zero of cnt + diag window (contiguous float4) and the
// chHead bytes; blocks 0/1 additionally run the dtype probes.
// flags[0]=params fp32, flags[1]=points fp32.
// ---------------------------------------------------------------------------
__global__ __launch_bounds__(256) void k_init(
    float4* __restrict__ zp, int n4,
    unsigned int* __restrict__ chz, int nc4,
    const unsigned short* __restrict__ w1bits,
    const unsigned short* __restrict__ ptsbits,
    unsigned int* __restrict__ flags)
{
    const int t = threadIdx.x;
    if (blockIdx.x < 2 && t < 64) {
        const int which = blockIdx.x;
        const unsigned short* src = which ? ptsbits : w1bits;
        const int n = which ? 512 : 320;
        float m = 0.0f;
        for (int i = t; i < n; i += 64) {
            const float a = fabsf(bf2f(src[i]));
            if (a == a) m = fmaxf(m, a);
        }
#pragma unroll
        for (int off = 32; off > 0; off >>= 1)
            m = fmaxf(m, __shfl_down(m, off));
        if (t == 0) flags[which] = (m > 1.0e6f) ? 1u : 0u;
    }
    const float4 z = {0.0f, 0.0f, 0.0f, 0.0f};
    for (int i = blockIdx.x * 256 + t; i < n4; i += gridDim.x * 256)
        zp[i] = z;
    for (int i = blockIdx.x * 256 + t; i < nc4; i += gridDim.x * 256)
        chz[i] = 0u;
}

// ---------------------------------------------------------------------------
// Phase A: histogram.
// ---------------------------------------------------------------------------
__global__ __launch_bounds__(256) void k_bin(
    const void* __restrict__ pts_raw,
    const unsigned int* __restrict__ flags,
    unsigned int* __restrict__ cnt,
    int b0, int npts)
{
    const int gid = blockIdx.x * 256 + threadIdx.x;
    if (gid >= npts) return;
    float px, py, pz, pw;
    load_pt(pts_raw, (size_t)b0 * NP_ + gid, (int)flags[1], px, py, pz, pw);
    const int g = cell_of(px, py, gid / NP_);
    if (g >= 0) atomicAdd(&cnt[g], 1u);
}

// ---------------------------------------------------------------------------
// Phase B (fused scan): each block redundantly sums cnt[0..base) for its
// prefix (L2-hot, no cross-block sync), then local-scans its 1024 cells,
// writes offs (+sentinel), cursor, and marks chHead[chunk] when a nonempty
// cell starts exactly at a 64-point chunk boundary.
// ---------------------------------------------------------------------------
__global__ __launch_bounds__(256) void k_scan(
    const unsigned int* __restrict__ cnt,
    unsigned int* __restrict__ offs,
    unsigned int* __restrict__ cursor,
    unsigned char* __restrict__ chHead,
    int nblocks, int n)
{
    __shared__ unsigned int sd[256];
    __shared__ unsigned int sBase;
    const int t = threadIdx.x;
    const int blk = blockIdx.x;
    const int i0 = blk * 1024 + t * 4;
    const unsigned int c0 = cnt[i0], c1 = cnt[i0 + 1],
                       c2 = cnt[i0 + 2], c3 = cnt[i0 + 3];
    const unsigned int s4 = c0 + c1 + c2 + c3;

    // base = sum of all cells before this block (redundant re-read).
    unsigned int bsum = 0;
    const int q4 = blk << 8;                  // (blk*1024)/4 uint4 records
    const uint4* cnt4 = (const uint4*)cnt;
    for (int i = t; i < q4; i += 256) {
        const uint4 v = cnt4[i];
        bsum += v.x + v.y + v.z + v.w;
    }
    sd[t] = bsum;
    __syncthreads();
    for (int d = 128; d > 0; d >>= 1) {
        if (t < d) sd[t] += sd[t + d];
        __syncthreads();
    }
    if (t == 0) sBase = sd[0];
    __syncthreads();

    // local inclusive scan of per-thread s4.
    sd[t] = s4;
    __syncthreads();
    for (int d = 1; d < 256; d <<= 1) {
        const unsigned int add = (t >= d) ? sd[t - d] : 0u;
        __syncthreads();
        sd[t] += add;
        __syncthreads();
    }
    unsigned int run = sBase + sd[t] - s4;    // exclusive prefix
    offs[i0] = run;     cursor[i0] = run;
    if (c0 && !(run & 63u)) chHead[run >> 6] = 1;            run += c0;
    offs[i0 + 1] = run; cursor[i0 + 1] = run;
    if (c1 && !(run & 63u)) chHead[run >> 6] = 1;            run += c1;
    offs[i0 + 2] = run; cursor[i0 + 2] = run;
    if (c2 && !(run & 63u)) chHead[run >> 6] = 1;            run += c2;
    offs[i0 + 3] = run; cursor[i0 + 3] = run;
    if (c3 && !(run & 63u)) chHead[run >> 6] = 1;            run += c3;
    if (blk == nblocks - 1 && t == 255) offs[n] = run;
}

// ---------------------------------------------------------------------------
// Phase C: materialize the sort — packed 8B fp16 cell-delta + u16 cell.
// ---------------------------------------------------------------------------
__global__ __launch_bounds__(256) void k_scatteridx(
    const void* __restrict__ pts_raw,
    const unsigned int* __restrict__ flags,
    unsigned int* __restrict__ cursor,
    ushort4* __restrict__ psorted8,
    unsigned short* __restrict__ scell16,
    int b0, int npts)
{
    const int gid = blockIdx.x * 256 + threadIdx.x;
    if (gid >= npts) return;
    float px, py, pz, pw;
    load_pt(pts_raw, (size_t)b0 * NP_ + gid, (int)flags[1], px, py, pz, pw);
    const int g = cell_of(px, py, gid / NP_);
    if (g < 0) return;
    const unsigned int pos = atomicAdd(&cursor[g], 1u);
    const int cellin = g & (HW_ - 1);
    const float cx = fmaf((float)(cellin & 127), 0.78125f, -49.609375f);
    const float cy = fmaf((float)(cellin >> 7), 0.78125f, -49.609375f);
    ushort4 r;
    r.x = f2h(px - cx);
    r.y = f2h(py - cy);
    r.z = f2h(pz);
    r.w = f2h(pw);
    psorted8[pos] = r;
    scell16[pos] = (unsigned short)g;
}

// ---------------------------------------------------------------------------
// Phase D (persistent MFMA): waves grid-stride over 64-point chunks.
// Plane-major sums: element (row, ch = nt*16+m15) at sums[nt*P + row*16+m15].
// chHead byte (independent early load) replaces the dependent offs[g] read.
// ---------------------------------------------------------------------------
__global__ __launch_bounds__(256, 2) void k_mlp_mfma(
    const ushort4* __restrict__ psorted8,
    const unsigned short* __restrict__ scell16,
    const void* __restrict__ W1_raw,
    const void* __restrict__ b1_raw,
    const void* __restrict__ W2_raw,
    const void* __restrict__ b2_raw,
    const unsigned int* __restrict__ flags,
    unsigned int* __restrict__ magic,
    const unsigned int* __restrict__ offs,    // ncells+1 (sentinel = total)
    const unsigned char* __restrict__ chHead,
    float* __restrict__ sums,                 // 5 planes of P floats
    int ncells, int P)
{
    __shared__ float sW1[4 * CH];             // [f][k]
    __shared__ float sb1[CH];
    __shared__ float sb2f[CH];
    __shared__ _Float16 sW2T[80 * HSTR];      // [ch_out][k], k 80..95 zero
    __shared__ _Float16 sEmb[4][16 * ESTR];   // per-wave embT slice [ch16][pt]
    __shared__ unsigned int sCellG[4][64];

    const int t = threadIdx.x;
    const int wf32 = (int)flags[0];

    // ---- staging (W2 read coalesced, LDS-scatter write).
    if (wf32) {
        const float* W1 = (const float*)W1_raw;
        const float* b1 = (const float*)b1_raw;
        const float* b2 = (const float*)b2_raw;
        for (int i = t; i < 4 * CH; i += 256) sW1[i] = W1[i];
        if (t < CH) { sb1[t] = b1[t]; sb2f[t] = b2[t]; }
        const float* W2 = (const float*)W2_raw;
        for (int i = t; i < CH * CH; i += 256)      // i = c*80 + d, coalesced
            sW2T[(i % CH) * HSTR + i / CH] = (_Float16)W2[i];
    } else {
        const unsigned short* W1 = (const unsigned short*)W1_raw;
        const unsigned short* b1 = (const unsigned short*)b1_raw;
        const unsigned short* b2 = (const unsigned short*)b2_raw;
        for (int i = t; i < 4 * CH; i += 256) sW1[i] = bf2f(W1[i]);
        if (t < CH) { sb1[t] = bf2f(b1[t]); sb2f[t] = bf2f(b2[t]); }
        const unsigned short* W2 = (const unsigned short*)W2_raw;
        for (int i = t; i < CH * CH; i += 256)      // coalesced
            sW2T[(i % CH) * HSTR + i / CH] = (_Float16)bf2f(W2[i]);
    }
    // zero the k = 80..103 pad of every row
    for (int i = t; i < CH * (HSTR - CH); i += 256)
        sW2T[(i / (HSTR - CH)) * HSTR + CH + (i % (HSTR - CH))] = (_Float16)0.0f;
    __syncthreads();

    if (blockIdx.x == 0 && t == 0) *magic = 0xCAFEBABEu;

    const int end = (int)offs[ncells];
    const int lane = t & 63;
    const int wid = t >> 6;
    const int m15 = lane & 15;
    const int quad = lane >> 4;
    const int totalWaves = gridDim.x * 4;
    const int nChunks = (end + 63) >> 6;

    for (int wv = blockIdx.x * 4 + wid; wv < nChunks; wv += totalWaves) {
        const int chunkStart = wv * 64;
        const int p = chunkStart + lane;
        const bool active = p < end;

        // ---- independent early loads: chunk-head bit + own cell + gathers.
        const unsigned char hb = chHead[wv];

        const int pOwn = active ? p : (end - 1);
        const int g = active ? (int)scell16[pOwn] : -1;

        ushort4 prm[4];
        int gm[4];
#pragma unroll
        for (int mt = 0; mt < 4; ++mt) {
            int idx = chunkStart + mt * 16 + m15;
            if (idx > end - 1) idx = end - 1;
            prm[mt] = psorted8[idx];            // 16-lane broadcast, L1/L2
            gm[mt] = (int)scell16[idx];
        }

        float pmx[4], pmy[4], pmz[4], pmw[4];
#pragma unroll
        for (int mt = 0; mt < 4; ++mt) {
            const int cellin = gm[mt] & (HW_ - 1);
            const float cx = fmaf((float)(cellin & 127), 0.78125f, -49.609375f);
            const float cy = fmaf((float)(cellin >> 7), 0.78125f, -49.609375f);
            pmx[mt] = cx + h2f(prm[mt].x);
            pmy[mt] = cy + h2f(prm[mt].y);
            pmz[mt] = h2f(prm[mt].z);
            pmw[mt] = h2f(prm[mt].w);
        }

        // ---- segment bookkeeping (R13-verified).
        const int gprev = __shfl_up(g, 1);
        const bool isHead = active && (lane == 0 || gprev != g);
        const unsigned long long headmask = __ballot(isHead);
        const int cellLocal = active
            ? (__popcll(headmask << (63 - lane)) - 1) : 255;
        const int ncellsW = __popcll(headmask);
        if (isHead) {
            unsigned int row = (unsigned int)g;
            if (cellLocal == 0 && !hb)
                row = (unsigned int)(ncells + wv);
            sCellG[wid][cellLocal] = row;
        }

        // ---- layer 1 transposed: A-frag values born in registers.
        half8_t Af[3][4];
#pragma unroll
        for (int ks = 0; ks < 3; ++ks) {
            const int kb = ks * 32 + quad * 8;
            if (kb < 80) {
                const float4 wa0 = *(const float4*)&sW1[0 * CH + kb];
                const float4 wb0 = *(const float4*)&sW1[0 * CH + kb + 4];
                const float4 wa1 = *(const float4*)&sW1[1 * CH + kb];
                const float4 wb1 = *(const float4*)&sW1[1 * CH + kb + 4];
                const float4 wa2 = *(const float4*)&sW1[2 * CH + kb];
                const float4 wb2 = *(const float4*)&sW1[2 * CH + kb + 4];
                const float4 wa3 = *(const float4*)&sW1[3 * CH + kb];
                const float4 wb3 = *(const float4*)&sW1[3 * CH + kb + 4];
                const float4 ba  = *(const float4*)&sb1[kb];
                const float4 bb  = *(const float4*)&sb1[kb + 4];
                float w0[8] = {wa0.x, wa0.y, wa0.z, wa0.w, wb0.x, wb0.y, wb0.z, wb0.w};
                float w1[8] = {wa1.x, wa1.y, wa1.z, wa1.w, wb1.x, wb1.y, wb1.z, wb1.w};
                float w2[8] = {wa2.x, wa2.y, wa2.z, wa2.w, wb2.x, wb2.y, wb2.z, wb2.w};
                float w3[8] = {wa3.x, wa3.y, wa3.z, wa3.w, wb3.x, wb3.y, wb3.z, wb3.w};
                float bv[8] = {ba.x, ba.y, ba.z, ba.w, bb.x, bb.y, bb.z, bb.w};
#pragma unroll
                for (int mt = 0; mt < 4; ++mt) {
                    half8_t v;
#pragma unroll
                    for (int j = 0; j < 8; ++j) {
                        float hv = bv[j];
                        hv = fmaf(pmx[mt], w0[j], hv);
                        hv = fmaf(pmy[mt], w1[j], hv);
                        hv = fmaf(pmz[mt], w2[j], hv);
                        hv = fmaf(pmw[mt], w3[j], hv);
                        v[j] = (_Float16)fmaxf(hv, 0.0f);
                    }
                    Af[ks][mt] = v;
                }
            } else {
                const half8_t z8 = {0, 0, 0, 0, 0, 0, 0, 0};
#pragma unroll
                for (int mt = 0; mt < 4; ++mt) Af[ks][mt] = z8;
            }
        }

        // ---- selector columns for MFMA2.
        int cl[2][8];
#pragma unroll
        for (int ks2 = 0; ks2 < 2; ++ks2)
#pragma unroll
            for (int j = 0; j < 8; ++j)
                cl[ks2][j] = __shfl(cellLocal, ks2 * 32 + quad * 8 + j);

        const int nMt2 = (ncellsW + 15) >> 4;
        _Float16* embT = &sEmb[wid][0];

        if (nMt2 == 1) {
            // ======== fast path (<=16 cells): A2 + row LUT hoisted ========
            half8_t A2h[2];
#pragma unroll
            for (int ks2 = 0; ks2 < 2; ++ks2)
#pragma unroll
                for (int j = 0; j < 8; ++j)
                    A2h[ks2][j] = (cl[ks2][j] == m15) ? (_Float16)1 : (_Float16)0;
            unsigned int rowr[4];
#pragma unroll
            for (int r = 0; r < 4; ++r) {
                const int cell = quad * 4 + r;
                rowr[r] = (cell < ncellsW) ? sCellG[wid][cell] : 0xFFFFFFFFu;
            }

#pragma unroll 1
            for (int nt = 0; nt < 5; ++nt) {
                f32x4_t acc[4];
#pragma unroll
                for (int mt = 0; mt < 4; ++mt) acc[mt] = (f32x4_t){0.0f, 0.0f, 0.0f, 0.0f};
#pragma unroll
                for (int ks = 0; ks < 3; ++ks) {
                    const half8_t Bf = *(const half8_t*)
                        &sW2T[(nt * 16 + m15) * HSTR + ks * 32 + quad * 8];
#pragma unroll
                    for (int mt = 0; mt < 4; ++mt)
                        acc[mt] = __builtin_amdgcn_mfma_f32_16x16x32_f16(
                            Af[ks][mt], Bf, acc[mt], 0, 0, 0);
                }
                const float bb2 = sb2f[nt * 16 + m15];
#pragma unroll
                for (int mt = 0; mt < 4; ++mt) {
                    const f32x4_t a = acc[mt];
                    half4_t v;
                    v[0] = (_Float16)fmaxf(a[0] + bb2, 0.0f);
                    v[1] = (_Float16)fmaxf(a[1] + bb2, 0.0f);
                    v[2] = (_Float16)fmaxf(a[2] + bb2, 0.0f);
                    v[3] = (_Float16)fmaxf(a[3] + bb2, 0.0f);
                    *(half4_t*)&embT[m15 * ESTR + mt * 16 + quad * 4] = v;
                }
                half8_t B2[2];
#pragma unroll
                for (int ks2 = 0; ks2 < 2; ++ks2)
                    B2[ks2] = *(const half8_t*)&embT[m15 * ESTR + ks2 * 32 + quad * 8];

                f32x4_t acc2 = (f32x4_t){0.0f, 0.0f, 0.0f, 0.0f};
#pragma unroll
                for (int ks2 = 0; ks2 < 2; ++ks2)
                    acc2 = __builtin_amdgcn_mfma_f32_16x16x32_f16(
                        A2h[ks2], B2[ks2], acc2, 0, 0, 0);

                float* const plane = sums + (size_t)nt * (size_t)P;
#pragma unroll
                for (int r = 0; r < 4; ++r)
                    if (rowr[r] != 0xFFFFFFFFu)
                        plane[((size_t)rowr[r] << 4) + m15] = acc2[r];
            }
        } else {
            // ======== general path (>16 cells in chunk) ========
#pragma unroll 1
            for (int nt = 0; nt < 5; ++nt) {
                f32x4_t acc[4];
#pragma unroll
                for (int mt = 0; mt < 4; ++mt) acc[mt] = (f32x4_t){0.0f, 0.0f, 0.0f, 0.0f};
#pragma unroll
                for (int ks = 0; ks < 3; ++ks) {
                    const half8_t Bf = *(const half8_t*)
                        &sW2T[(nt * 16 + m15) * HSTR + ks * 32 + quad * 8];
#pragma unroll
                    for (int mt = 0; mt < 4; ++mt)
                        acc[mt] = __builtin_amdgcn_mfma_f32_16x16x32_f16(
                            Af[ks][mt], Bf, acc[mt], 0, 0, 0);
                }
                const float bb2 = sb2f[nt * 16 + m15];
#pragma unroll
                for (int mt = 0; mt < 4; ++mt) {
                    const f32x4_t a = acc[mt];
                    half4_t v;
                    v[0] = (_Float16)fmaxf(a[0] + bb2, 0.0f);
                    v[1] = (_Float16)fmaxf(a[1] + bb2, 0.0f);
                    v[2] = (_Float16)fmaxf(a[2] + bb2, 0.0f);
                    v[3] = (_Float16)fmaxf(a[3] + bb2, 0.0f);
                    *(half4_t*)&embT[m15 * ESTR + mt * 16 + quad * 4] = v;
                }
                half8_t B2[2];
#pragma unroll
                for (int ks2 = 0; ks2 < 2; ++ks2)
                    B2[ks2] = *(const half8_t*)&embT[m15 * ESTR + ks2 * 32 + quad * 8];

                float* const plane = sums + (size_t)nt * (size_t)P;
                for (int mt2 = 0; mt2 < nMt2; ++mt2) {
                    const int m2 = mt2 * 16 + m15;
                    f32x4_t acc2 = (f32x4_t){0.0f, 0.0f, 0.0f, 0.0f};
#pragma unroll
                    for (int ks2 = 0; ks2 < 2; ++ks2) {
                        half8_t A2;
#pragma unroll
                        for (int j = 0; j < 8; ++j)
                            A2[j] = (cl[ks2][j] == m2) ? (_Float16)1 : (_Float16)0;
                        acc2 = __builtin_amdgcn_mfma_f32_16x16x32_f16(
                            A2, B2[ks2], acc2, 0, 0, 0);
                    }
#pragma unroll
                    for (int r = 0; r < 4; ++r) {
                        const int cell = mt2 * 16 + quad * 4 + r;
                        if (cell < ncellsW) {
                            const unsigned int row = sCellG[wid][cell];
                            plane[((size_t)row << 4) + m15] = acc2[r];
                        }
                    }
                }
            }
        }
    }
}

// ---------------------------------------------------------------------------
// Head (R22): mean -> 1x1 conv -> BN -> relu -> out via MFMA. Wp A-frags
// loaded directly from global into registers (hi/lo f16 split, L2-hot) --
// no Wp LDS, no staging conflicts. LDS = sMean only (~28KB) -> more blocks
// resident. Block 0 runs the diagnostics beacon.
// ---------------------------------------------------------------------------
__global__ __launch_bounds__(256, 2) void k_head(
    const float* __restrict__ sums,
    const unsigned int* __restrict__ cnt,
    const unsigned int* __restrict__ offs,
    const void* __restrict__ Wp_raw,
    const void* __restrict__ bp_raw,
    const void* __restrict__ gamma_raw,
    const void* __restrict__ beta_raw,
    const void* __restrict__ rmean_raw,
    const void* __restrict__ rvar_raw,
    const unsigned int* __restrict__ flags,
    const unsigned int* __restrict__ magic,
    float* __restrict__ out,
    int b0, int ncells, int P, int hostbits)
{
    __shared__ _Float16 sMean[BEVW * MSTR];    // [cell][k], k 80..103 zero
    __shared__ float sAlpha[COUT_], sDelta[COUT_];
    __shared__ float sRedF[4];
    __shared__ unsigned int sRedU[4];

    const int t = threadIdx.x;
    const int blk = blockIdx.x;
    const int bl = blk >> 7, hrow = blk & 127;
    const int bg = b0 + bl;
    const int wf32 = (int)flags[0];
    const int lane = t & 63;
    const int wid = t >> 6;
    const int m15 = lane & 15;
    const int quad = lane >> 4;

    // ---- alpha/delta staging (1KB LDS).
    if (t < COUT_) {
        if (wf32) {
            const float rs = rsqrtf(((const float*)rvar_raw)[t] + 1e-5f);
            const float al = ((const float*)gamma_raw)[t] * rs;
            sAlpha[t] = al;
            sDelta[t] = al * (((const float*)bp_raw)[t] - ((const float*)rmean_raw)[t])
                        + ((const float*)beta_raw)[t];
        } else {
            const float rs = rsqrtf(bf2f(((const unsigned short*)rvar_raw)[t]) + 1e-5f);
            const float al = bf2f(((const unsigned short*)gamma_raw)[t]) * rs;
            sAlpha[t] = al;
            sDelta[t] = al * (bf2f(((const unsigned short*)bp_raw)[t])
                              - bf2f(((const unsigned short*)rmean_raw)[t]))
                        + bf2f(((const unsigned short*)beta_raw)[t]);
        }
    }

    // ---- A-fragments direct from global (fragment layout, L2-hot), hi/lo.
    half8_t Ahi[2][3], Alo[2][3];
#pragma unroll
    for (int m = 0; m < 2; ++m) {
        const int d = (wid * 2 + m) * 16 + m15;
#pragma unroll
        for (int ks = 0; ks < 3; ++ks) {
#pragma unroll
            for (int j = 0; j < 8; ++j) {
                const int k = ks * 32 + quad * 8 + j;
                float w = 0.0f;
                if (k < CH)
                    w = wf32 ? ((const float*)Wp_raw)[k * COUT_ + d]
                             : bf2f(((const unsigned short*)Wp_raw)[k * COUT_ + d]);
                const _Float16 hi = (_Float16)w;
                Ahi[m][ks][j] = hi;
                Alo[m][ks][j] = (_Float16)(w - (float)hi);
            }
        }
    }

    // ---- stage mean[cell][k] f16 (+zero pad k 80..103).
    const int cellbase = bl * HW_ + hrow * BEVW;
    for (int i = t; i < BEVW * 26; i += 256) {
        const int w = i / 26, c4 = i % 26;
        _Float16* m = &sMean[w * MSTR + c4 * 4];
        if (c4 < 20) {
            const int nt = c4 >> 2, q = c4 & 3;
            const int cell = cellbase + w;
            const unsigned int c = cnt[cell];
            float4 s = {0.0f, 0.0f, 0.0f, 0.0f};
            if (c > 0) {
                const float4* plane4 = (const float4*)(sums + (size_t)nt * (size_t)P);
                s = plane4[cell * 4 + q];
                const unsigned int o = offs[cell];
                const int bA = (int)(o >> 6) + 1;
                const int bB = (int)((o + c - 1) >> 6);
                for (int b = bA; b <= bB; ++b) {
                    const float4 st = plane4[(ncells + b) * 4 + q];
                    s.x += st.x; s.y += st.y; s.z += st.z; s.w += st.w;
                }
            }
            const float inv = 1.0f / fmaxf((float)c, 1.0f);
            m[0] = (_Float16)(s.x * inv);
            m[1] = (_Float16)(s.y * inv);
            m[2] = (_Float16)(s.z * inv);
            m[3] = (_Float16)(s.w * inv);
        } else {
            m[0] = (_Float16)0.0f; m[1] = (_Float16)0.0f;
            m[2] = (_Float16)0.0f; m[3] = (_Float16)0.0f;
        }
    }
    __syncthreads();

    // ---- hoist alpha/delta (8 douts per thread).
    float alph[2][4], delt[2][4];
#pragma unroll
    for (int m = 0; m < 2; ++m)
#pragma unroll
        for (int r = 0; r < 4; ++r) {
            const int d = (wid * 2 + m) * 16 + quad * 4 + r;
            alph[m][r] = sAlpha[d];
            delt[m][r] = sDelta[d];
        }

    // ---- MFMA GEMM: wave wid owns douts [wid*32, wid*32+32).
#pragma unroll
    for (int n = 0; n < 8; ++n) {
        half8_t Bf[3];
#pragma unroll
        for (int ks = 0; ks < 3; ++ks)
            Bf[ks] = *(const half8_t*)&sMean[(n * 16 + m15) * MSTR + ks * 32 + quad * 8];
#pragma unroll
        for (int m = 0; m < 2; ++m) {
            f32x4_t acc = (f32x4_t){0.0f, 0.0f, 0.0f, 0.0f};
#pragma unroll
            for (int ks = 0; ks < 3; ++ks) {
                acc = __builtin_amdgcn_mfma_f32_16x16x32_f16(Ahi[m][ks], Bf[ks], acc, 0, 0, 0);
                acc = __builtin_amdgcn_mfma_f32_16x16x32_f16(Alo[m][ks], Bf[ks], acc, 0, 0, 0);
            }
#pragma unroll
            for (int r = 0; r < 4; ++r) {
                const int d = (wid * 2 + m) * 16 + quad * 4 + r;
                float o = fmaxf(fmaf(acc[r], alph[m][r], delt[m][r]), 0.0f);
                o = fminf(o, 512.0f);
                out[(((size_t)bg * COUT_ + d) * BEVH + hrow) * BEVW + n * 16 + m15] = o;
            }
        }
    }

    // ---- diagnostics beacon (block 0 only; healthy run writes nothing).
    if (blk == 0) {
        unsigned int cs = 0;
        for (int i = t; i < HW_; i += 256) cs += cnt[i];
        float sl = 0.0f;
        for (int i = t; i < CH * CH; i += 256) sl += fabsf(sums[i]);
#pragma unroll
        for (int off = 32; off > 0; off >>= 1) {
            cs += __shfl_down(cs, off);
            sl += __shfl_down(sl, off);
        }
        if (lane == 0) { sRedU[wid] = cs; sRedF[wid] = sl; }
        __syncthreads();
        if (t == 0) {
            const unsigned int csum = sRedU[0] + sRedU[1] + sRedU[2] + sRedU[3];
            const float ssum = sRedF[0] + sRedF[1] + sRedF[2] + sRedF[3];
            int code = hostbits;
            if (*magic != 0xCAFEBABEu) code |= 1;
            if (csum < 1000u)          code |= 2;
            if (!(ssum > 0.0f))        code |= 4;
            if (code) {
                code |= (int)(flags[0] ? 32 : 0);
                code |= (int)(flags[1] ? 64 : 0);
                out[0] = 1024.0f * (float)code;
            }
        }
    }
}

extern "C" void kernel_launch(void* const* d_in, const int* in_sizes, int n_in,
                              void* d_out, int out_size, void* d_ws, size_t ws_size,
                              hipStream_t stream) {
    const void* pts   = d_in[0];
    const void* W1    = d_in[1];
    const void* b1    = d_in[2];
    const void* W2    = d_in[3];
    const void* b2    = d_in[4];
    const void* Wp    = d_in[5];
    const void* bp    = d_in[6];
    const void* gamma = d_in[7];
    const void* beta  = d_in[8];
    const void* rmean = d_in[9];
    const void* rvar  = d_in[10];

    int hostbits = 0;
    if (n_in != 11 ||
        in_sizes[0] != B_ * NP_ * 4 ||
        in_sizes[1] != 4 * CH  || in_sizes[2] != CH ||
        in_sizes[3] != CH * CH || in_sizes[4] != CH ||
        in_sizes[5] != CH * COUT_ || in_sizes[6] != COUT_ ||
        out_size != B_ * COUT_ * HW_)
        hostbits |= 8;
    if (ws_size < SCRATCH_OFF + PER_BATCH + EXTRA_BYTES) hostbits |= 16;

    unsigned int* flags = (unsigned int*)d_ws;
    unsigned int* magic = (unsigned int*)((char*)d_ws + MAGIC_OFF);
    char* base = (char*)d_ws + SCRATCH_OFF;
    const size_t avail = (ws_size > SCRATCH_OFF + EXTRA_BYTES)
                       ? (ws_size - SCRATCH_OFF - EXTRA_BYTES) : PER_BATCH;
    int nb = (int)(avail / PER_BATCH);
    if (nb < 1) nb = 1;
    if (nb > B_) nb = B_;

    // Layout: cnt | sums (5 planes, incl. staging rows) | offs(+4) | cursor |
    //         chHead | psorted8 (16B-aligned) | scell16
    unsigned int*   cnt      = (unsigned int*)base;
    float*          sums     = (float*)(cnt + (size_t)nb * HW_);
    const size_t    sumsFl   = (size_t)5 * ((size_t)nb * HW_ + (size_t)nb * NCHK) * 16;
    unsigned int*   offs     = (unsigned int*)(sums + sumsFl);
    unsigned int*   cursor   = offs + (size_t)nb * HW_ + 4;
    unsigned char*  chHead   = (unsigned char*)(cursor + (size_t)nb * HW_);
    char*           palign   = (char*)chHead + (size_t)nb * NCHK;
    palign = (char*)(((size_t)palign + 15) & ~(size_t)15);
    ushort4*        psorted8 = (ushort4*)palign;
    unsigned short* scell16  = (unsigned short*)(psorted8 + (size_t)nb * NP_);

    for (int b0 = 0; b0 < B_; b0 += nb) {
        const int bcnt = (B_ - b0 < nb) ? (B_ - b0) : nb;
        const int ncells = bcnt * HW_;
        const int npts   = bcnt * NP_;
        const int nblk   = ncells >> 10;      // 1024 cells per scan block
        const int P      = (ncells + bcnt * NCHK) * 16;   // plane stride (f32)

        // Zero cnt + diag window (contiguous) + chHead; blocks 0/1 detect.
        k_init<<<128, 256, 0, stream>>>(
            (float4*)cnt, ncells / 4 + 1600,
            (unsigned int*)chHead, (bcnt * NCHK + 3) / 4,
            (const unsigned short*)W1, (const unsigned short*)pts, flags);

        k_bin<<<(npts + 255) / 256, 256, 0, stream>>>(
            pts, flags, cnt, b0, npts);

        k_scan<<<nblk, 256, 0, stream>>>(cnt, offs, cursor, chHead,
                                         nblk, ncells);

        k_scatteridx<<<(npts + 255) / 256, 256, 0, stream>>>(
            pts, flags, cursor, psorted8, scell16, b0, npts);

        k_mlp_mfma<<<1280, 256, 0, stream>>>(
            psorted8, scell16, W1, b1, W2, b2, flags, magic, offs, chHead,
            sums, ncells, P);

        k_head<<<bcnt * BEVH, 256, 0, stream>>>(
            sums, cnt, offs, Wp, bp, gamma, beta, rmean, rvar, flags, magic,
            (float*)d_out, b0, ncells, P, hostbits);
    }
}

// Round 9
// 235.198 us; speedup vs baseline: 1.2774x; 1.0138x over previous
//
#include <hip/hip_runtime.h>
#include <hip/hip_bf16.h>

// PointsToBEV round 23. R22 landed (k_head off top-5); k_mlp (~53us) again
// the wall, stall-bound: chunk-entry load chain (~600-900cy) + per-nt embT
// LDS write->read round-trip (~240cy x5) are serial and unhidden. R23:
// (1) 16B combined record uint4{dx|dy, z|w, g, 0} -- 4 gather loads total,
// own-g = gm[quad] free, scatteridx does ONE random store per point;
// (2) next-chunk record prefetch (reg-safe now: 112 VGPR @ 256 cap);
// (3) 2-slice embT pipeline P0 P1 C0 P2 C1 P3 C2 P4 C3 C4 hides the LDS
// round-trip under next MFMA1 (LDS 29->38KB, still 4 blocks/CU); grid 768.
// (4) k_bin/k_scatteridx 2 pts/thread (ushort8 loads).

#define B_    4
#define NP_   200000
#define CH    80
#define COUT_ 128
#define BEVH  128
#define BEVW  128
#define HW_   (BEVH * BEVW)
#define NCHK  (NP_ / 64)        // 3125 chunks per batch (NP_ % 64 == 0)

// Per-batch bytes: cnt(HW u32) + sums+staging((HW+NCHK)*80 f32) +
// offs(HW u32 +pad) + cursor(HW u32) + chHead(NCHK u8) + prec(NP*16)
#define PER_BATCH ((size_t)HW_ * 332 + (size_t)NCHK * 321 + (size_t)NP_ * 16)
#define EXTRA_BYTES 512

#define MAGIC_OFF   128
#define SCRATCH_OFF 256

typedef _Float16 half4_t __attribute__((ext_vector_type(4)));
typedef _Float16 half8_t __attribute__((ext_vector_type(8)));
typedef float    f32x4_t __attribute__((ext_vector_type(4)));
typedef unsigned short ushort8_t __attribute__((ext_vector_type(8)));

#define HSTR 104   // W2T k-stride in f16 (52 dwords -> 2-way banks, free)
#define ESTR 72    // embT pt-stride in f16 (36 dwords -> 2-way banks, free)
#define ESLICE (16 * ESTR)
#define MSTR 104   // sMean k-stride in f16 (16B-aligned, 2-way free)

__device__ __forceinline__ float bf2f(unsigned short u) {
    return __uint_as_float(((unsigned int)u) << 16);
}
__device__ __forceinline__ unsigned short f2h(float f) {
    return __builtin_bit_cast(unsigned short, (_Float16)f);
}
__device__ __forceinline__ float h2f(unsigned short u) {
    return (float)__builtin_bit_cast(_Float16, u);
}

__device__ __forceinline__ int cell_of(float px, float py, int bloc) {
    const int ix = (int)floorf((px + 50.0f) / 0.78125f);
    const int iy = (int)floorf((py + 50.0f) / 0.78125f);
    if (ix < 0 || ix >= BEVW || iy < 0 || iy >= BEVH) return -1;
    return bloc * HW_ + iy * BEVW + ix;
}

// Load 2 consecutive points (p0 even) as one vector op where possible.
__device__ __forceinline__ void load_pt2(const void* pts_raw, size_t pbase,
                                         int pf32, float x[2], float y[2],
                                         float z[2], float w[2]) {
    if (pf32) {
        const float4 a = ((const float4*)pts_raw)[pbase];
        const float4 b = ((const float4*)pts_raw)[pbase + 1];
        x[0] = a.x; y[0] = a.y; z[0] = a.z; w[0] = a.w;
        x[1] = b.x; y[1] = b.y; z[1] = b.z; w[1] = b.w;
    } else {
        const ushort8_t u = ((const ushort8_t*)pts_raw)[pbase >> 1];
        x[0] = bf2f(u[0]); y[0] = bf2f(u[1]); z[0] = bf2f(u[2]); w[0] = bf2f(u[3]);
        x[1] = bf2f(u[4]); y[1] = bf2f(u[5]); z[1] = bf2f(u[6]); w[1] = bf2f(u[7]);
    }
}

// ---------------------------------------------------------------------------
// k_init: grid-stride zero of cnt + diag window and chHead; blocks 0/1 run
// the dtype probes. flags[0]=params fp32, flags[1]=points fp32.
// ---------------------------------------------------------------------------
__global__ __launch_bounds__(256) void k_init(
    float4* __restrict__ zp, int n4,
    unsigned int* __restrict__ chz, int nc4,
    const unsigned short* __restrict__ w1bits,
    const unsigned short* __restrict__ ptsbits,
    unsigned int* __restrict__ flags)
{
    const int t = threadIdx.x;
    if (blockIdx.x < 2 && t < 64) {
        const int which = blockIdx.x;
        const unsigned short* src = which ? ptsbits : w1bits;
        const int n = which ? 512 : 320;
        float m = 0.0f;
        for (int i = t; i < n; i += 64) {
            const float a = fabsf(bf2f(src[i]));
            if (a == a) m = fmaxf(m, a);
        }
#pragma unroll
        for (int off = 32; off > 0; off >>= 1)
            m = fmaxf(m, __shfl_down(m, off));
        if (t == 0) flags[which] = (m > 1.0e6f) ? 1u : 0u;
    }
    const float4 z = {0.0f, 0.0f, 0.0f, 0.0f};
    for (int i = blockIdx.x * 256 + t; i < n4; i += gridDim.x * 256)
        zp[i] = z;
    for (int i = blockIdx.x * 256 + t; i < nc4; i += gridDim.x * 256)
        chz[i] = 0u;
}

// ---------------------------------------------------------------------------
// Phase A: histogram (2 points per thread).
// ---------------------------------------------------------------------------
__global__ __launch_bounds__(256) void k_bin(
    const void* __restrict__ pts_raw,
    const unsigned int* __restrict__ flags,
    unsigned int* __restrict__ cnt,
    int b0, int npts)
{
    const int gid = blockIdx.x * 256 + threadIdx.x;
    const int p0 = gid * 2;
    if (p0 >= npts) return;
    const int bloc = p0 / NP_;                 // p0 even, NP_ even: pair same batch
    float x[2], y[2], z[2], w[2];
    load_pt2(pts_raw, (size_t)b0 * NP_ + p0, (int)flags[1], x, y, z, w);
#pragma unroll
    for (int k = 0; k < 2; ++k) {
        const int g = cell_of(x[k], y[k], bloc);
        if (g >= 0) atomicAdd(&cnt[g], 1u);
    }
}

// ---------------------------------------------------------------------------
// Phase B (fused scan): per-block redundant base re-sum (L2-hot, no
// cross-block sync), local scan, offs (+sentinel), cursor, chHead marks.
// ---------------------------------------------------------------------------
__global__ __launch_bounds__(256) void k_scan(
    const unsigned int* __restrict__ cnt,
    unsigned int* __restrict__ offs,
    unsigned int* __restrict__ cursor,
    unsigned char* __restrict__ chHead,
    int nblocks, int n)
{
    __shared__ unsigned int sd[256];
    __shared__ unsigned int sBase;
    const int t = threadIdx.x;
    const int blk = blockIdx.x;
    const int i0 = blk * 1024 + t * 4;
    const unsigned int c0 = cnt[i0], c1 = cnt[i0 + 1],
                       c2 = cnt[i0 + 2], c3 = cnt[i0 + 3];
    const unsigned int s4 = c0 + c1 + c2 + c3;

    unsigned int bsum = 0;
    const int q4 = blk << 8;
    const uint4* cnt4 = (const uint4*)cnt;
    for (int i = t; i < q4; i += 256) {
        const uint4 v = cnt4[i];
        bsum += v.x + v.y + v.z + v.w;
    }
    sd[t] = bsum;
    __syncthreads();
    for (int d = 128; d > 0; d >>= 1) {
        if (t < d) sd[t] += sd[t + d];
        __syncthreads();
    }
    if (t == 0) sBase = sd[0];
    __syncthreads();

    sd[t] = s4;
    __syncthreads();
    for (int d = 1; d < 256; d <<= 1) {
        const unsigned int add = (t >= d) ? sd[t - d] : 0u;
        __syncthreads();
        sd[t] += add;
        __syncthreads();
    }
    unsigned int run = sBase + sd[t] - s4;    // exclusive prefix
    offs[i0] = run;     cursor[i0] = run;
    if (c0 && !(run & 63u)) chHead[run >> 6] = 1;            run += c0;
    offs[i0 + 1] = run; cursor[i0 + 1] = run;
    if (c1 && !(run & 63u)) chHead[run >> 6] = 1;            run += c1;
    offs[i0 + 2] = run; cursor[i0 + 2] = run;
    if (c2 && !(run & 63u)) chHead[run >> 6] = 1;            run += c2;
    offs[i0 + 3] = run; cursor[i0 + 3] = run;
    if (c3 && !(run & 63u)) chHead[run >> 6] = 1;            run += c3;
    if (blk == nblocks - 1 && t == 255) offs[n] = run;
}

// ---------------------------------------------------------------------------
// Phase C: materialize the sort — ONE 16B record per point (2 pts/thread).
// rec = { dx|dy<<16 (fp16), z|w<<16 (fp16), g, 0 }.
// ---------------------------------------------------------------------------
__global__ __launch_bounds__(256) void k_scatteridx(
    const void* __restrict__ pts_raw,
    const unsigned int* __restrict__ flags,
    unsigned int* __restrict__ cursor,
    uint4* __restrict__ prec,
    int b0, int npts)
{
    const int gid = blockIdx.x * 256 + threadIdx.x;
    const int p0 = gid * 2;
    if (p0 >= npts) return;
    const int bloc = p0 / NP_;
    float x[2], y[2], z[2], w[2];
    load_pt2(pts_raw, (size_t)b0 * NP_ + p0, (int)flags[1], x, y, z, w);
#pragma unroll
    for (int k = 0; k < 2; ++k) {
        const int g = cell_of(x[k], y[k], bloc);
        if (g < 0) continue;
        const unsigned int pos = atomicAdd(&cursor[g], 1u);
        const int cellin = g & (HW_ - 1);
        const float cx = fmaf((float)(cellin & 127), 0.78125f, -49.609375f);
        const float cy = fmaf((float)(cellin >> 7), 0.78125f, -49.609375f);
        uint4 r;
        r.x = (unsigned int)f2h(x[k] - cx) | ((unsigned int)f2h(y[k] - cy) << 16);
        r.y = (unsigned int)f2h(z[k]) | ((unsigned int)f2h(w[k]) << 16);
        r.z = (unsigned int)g;
        r.w = 0u;
        prec[pos] = r;
    }
}

// ---------------------------------------------------------------------------
// Phase D (persistent MFMA): waves grid-stride over 64-point chunks.
// 16B records: 4 gather loads/lane, own-g = gm[quad]. Next-chunk prefetch.
// Fast path: 2-slice embT pipeline P0 P1 C0 P2 C1 P3 C2 P4 C3 C4 hides the
// per-nt LDS write->read latency under the next MFMA1 cluster.
// ---------------------------------------------------------------------------
__global__ __launch_bounds__(256, 2) void k_mlp_mfma(
    const uint4* __restrict__ precs,
    const void* __restrict__ W1_raw,
    const void* __restrict__ b1_raw,
    const void* __restrict__ W2_raw,
    const void* __restrict__ b2_raw,
    const unsigned int* __restrict__ flags,
    unsigned int* __restrict__ magic,
    const unsigned int* __restrict__ offs,    // ncells+1 (sentinel = total)
    const unsigned char* __restrict__ chHead,
    float* __restrict__ sums,                 // 5 planes of P floats
    int ncells, int P)
{
    __shared__ float sW1[4 * CH];             // [f][k]
    __shared__ float sb1[CH];
    __shared__ float sb2f[CH];
    __shared__ _Float16 sW2T[80 * HSTR];      // [ch_out][k], k 80..103 zero
    __shared__ _Float16 sEmb[4][2 * ESLICE];  // per-wave 2-slice embT dbuf
    __shared__ unsigned int sCellG[4][64];

    const int t = threadIdx.x;
    const int wf32 = (int)flags[0];

    // ---- staging (W2 read coalesced, LDS-scatter write).
    if (wf32) {
        const float* W1 = (const float*)W1_raw;
        const float* b1 = (const float*)b1_raw;
        const float* b2 = (const float*)b2_raw;
        for (int i = t; i < 4 * CH; i += 256) sW1[i] = W1[i];
        if (t < CH) { sb1[t] = b1[t]; sb2f[t] = b2[t]; }
        const float* W2 = (const float*)W2_raw;
        for (int i = t; i < CH * CH; i += 256)      // i = c*80 + d, coalesced
            sW2T[(i % CH) * HSTR + i / CH] = (_Float16)W2[i];
    } else {
        const unsigned short* W1 = (const unsigned short*)W1_raw;
        const unsigned short* b1 = (const unsigned short*)b1_raw;
        const unsigned short* b2 = (const unsigned short*)b2_raw;
        for (int i = t; i < 4 * CH; i += 256) sW1[i] = bf2f(W1[i]);
        if (t < CH) { sb1[t] = bf2f(b1[t]); sb2f[t] = bf2f(b2[t]); }
        const unsigned short* W2 = (const unsigned short*)W2_raw;
        for (int i = t; i < CH * CH; i += 256)      // coalesced
            sW2T[(i % CH) * HSTR + i / CH] = (_Float16)bf2f(W2[i]);
    }
    for (int i = t; i < CH * (HSTR - CH); i += 256)
        sW2T[(i / (HSTR - CH)) * HSTR + CH + (i % (HSTR - CH))] = (_Float16)0.0f;
    __syncthreads();

    if (blockIdx.x == 0 && t == 0) *magic = 0xCAFEBABEu;

    const int end = (int)offs[ncells];
    const int lane = t & 63;
    const int wid = t >> 6;
    const int m15 = lane & 15;
    const int quad = lane >> 4;
    const int totalWaves = gridDim.x * 4;
    const int nChunks = (end + 63) >> 6;

    int wv = blockIdx.x * 4 + wid;
    if (wv < nChunks) {
        uint4 prm[4];
        unsigned char hb;
        {
            hb = chHead[wv];
            const int cs0 = wv * 64;
#pragma unroll
            for (int mt = 0; mt < 4; ++mt) {
                int idx = cs0 + mt * 16 + m15;
                if (idx > end - 1) idx = end - 1;
                prm[mt] = precs[idx];
            }
        }

        for (;;) {
            const int chunkStart = wv * 64;
            const bool active = chunkStart + lane < end;
            const int wvn = wv + totalWaves;
            const bool hasNext = wvn < nChunks;

            // ---- decode records.
            int gm[4];
            float pmx[4], pmy[4], pmz[4], pmw[4];
#pragma unroll
            for (int mt = 0; mt < 4; ++mt) {
                gm[mt] = (int)prm[mt].z;
                const int cellin = gm[mt] & (HW_ - 1);
                const float cx = fmaf((float)(cellin & 127), 0.78125f, -49.609375f);
                const float cy = fmaf((float)(cellin >> 7), 0.78125f, -49.609375f);
                pmx[mt] = cx + h2f((unsigned short)(prm[mt].x & 0xFFFFu));
                pmy[mt] = cy + h2f((unsigned short)(prm[mt].x >> 16));
                pmz[mt] = h2f((unsigned short)(prm[mt].y & 0xFFFFu));
                pmw[mt] = h2f((unsigned short)(prm[mt].y >> 16));
            }
            const int g = active ? gm[quad] : -1;   // own record = gather mt=quad

            // ---- segment bookkeeping (R13-verified).
            const int gprev = __shfl_up(g, 1);
            const bool isHead = active && (lane == 0 || gprev != g);
            const unsigned long long headmask = __ballot(isHead);
            const int cellLocal = active
                ? (__popcll(headmask << (63 - lane)) - 1) : 255;
            const int ncellsW = __popcll(headmask);
            if (isHead) {
                unsigned int row = (unsigned int)g;
                if (cellLocal == 0 && !hb)
                    row = (unsigned int)(ncells + wv);
                sCellG[wid][cellLocal] = row;
            }

            // ---- prefetch next chunk (hidden under Af + nt pipeline).
            uint4 prmN[4];
            unsigned char hbN = 0;
            if (hasNext) {
                hbN = chHead[wvn];
                const int csn = wvn * 64;
#pragma unroll
                for (int mt = 0; mt < 4; ++mt) {
                    int idx = csn + mt * 16 + m15;
                    if (idx > end - 1) idx = end - 1;
                    prmN[mt] = precs[idx];
                }
            }

            // ---- layer 1 transposed: A-frag values born in registers.
            half8_t Af[3][4];
#pragma unroll
            for (int ks = 0; ks < 3; ++ks) {
                const int kb = ks * 32 + quad * 8;
                if (kb < 80) {
                    const float4 wa0 = *(const float4*)&sW1[0 * CH + kb];
                    const float4 wb0 = *(const float4*)&sW1[0 * CH + kb + 4];
                    const float4 wa1 = *(const float4*)&sW1[1 * CH + kb];
                    const float4 wb1 = *(const float4*)&sW1[1 * CH + kb + 4];
                    const float4 wa2 = *(const float4*)&sW1[2 * CH + kb];
                    const float4 wb2 = *(const float4*)&sW1[2 * CH + kb + 4];
                    const float4 wa3 = *(const float4*)&sW1[3 * CH + kb];
                    const float4 wb3 = *(const float4*)&sW1[3 * CH + kb + 4];
                    const float4 ba  = *(const float4*)&sb1[kb];
                    const float4 bb  = *(const float4*)&sb1[kb + 4];
                    float w0[8] = {wa0.x, wa0.y, wa0.z, wa0.w, wb0.x, wb0.y, wb0.z, wb0.w};
                    float w1[8] = {wa1.x, wa1.y, wa1.z, wa1.w, wb1.x, wb1.y, wb1.z, wb1.w};
                    float w2[8] = {wa2.x, wa2.y, wa2.z, wa2.w, wb2.x, wb2.y, wb2.z, wb2.w};
                    float w3[8] = {wa3.x, wa3.y, wa3.z, wa3.w, wb3.x, wb3.y, wb3.z, wb3.w};
                    float bv[8] = {ba.x, ba.y, ba.z, ba.w, bb.x, bb.y, bb.z, bb.w};
#pragma unroll
                    for (int mt = 0; mt < 4; ++mt) {
                        half8_t v;
#pragma unroll
                        for (int j = 0; j < 8; ++j) {
                            float hv = bv[j];
                            hv = fmaf(pmx[mt], w0[j], hv);
                            hv = fmaf(pmy[mt], w1[j], hv);
                            hv = fmaf(pmz[mt], w2[j], hv);
                            hv = fmaf(pmw[mt], w3[j], hv);
                            v[j] = (_Float16)fmaxf(hv, 0.0f);
                        }
                        Af[ks][mt] = v;
                    }
                } else {
                    const half8_t z8 = {0, 0, 0, 0, 0, 0, 0, 0};
#pragma unroll
                    for (int mt = 0; mt < 4; ++mt) Af[ks][mt] = z8;
                }
            }

            // ---- selector columns for MFMA2.
            int cl[2][8];
#pragma unroll
            for (int ks2 = 0; ks2 < 2; ++ks2)
#pragma unroll
                for (int j = 0; j < 8; ++j)
                    cl[ks2][j] = __shfl(cellLocal, ks2 * 32 + quad * 8 + j);

            const int nMt2 = (ncellsW + 15) >> 4;
            _Float16* embT = &sEmb[wid][0];

            // P(nt): MFMA1 + bias/relu -> embT slice. C(nt): B2 read ->
            // MFMA2 -> plane store.
            auto mfma1_epi = [&](int nt, int slice) {
                f32x4_t acc[4];
#pragma unroll
                for (int mt = 0; mt < 4; ++mt) acc[mt] = (f32x4_t){0.0f, 0.0f, 0.0f, 0.0f};
#pragma unroll
                for (int ks = 0; ks < 3; ++ks) {
                    const half8_t Bf = *(const half8_t*)
                        &sW2T[(nt * 16 + m15) * HSTR + ks * 32 + quad * 8];
#pragma unroll
                    for (int mt = 0; mt < 4; ++mt)
                        acc[mt] = __builtin_amdgcn_mfma_f32_16x16x32_f16(
                            Af[ks][mt], Bf, acc[mt], 0, 0, 0);
                }
                const float bb2 = sb2f[nt * 16 + m15];
#pragma unroll
                for (int mt = 0; mt < 4; ++mt) {
                    const f32x4_t a = acc[mt];
                    half4_t v;
                    v[0] = (_Float16)fmaxf(a[0] + bb2, 0.0f);
                    v[1] = (_Float16)fmaxf(a[1] + bb2, 0.0f);
                    v[2] = (_Float16)fmaxf(a[2] + bb2, 0.0f);
                    v[3] = (_Float16)fmaxf(a[3] + bb2, 0.0f);
                    *(half4_t*)&embT[slice * ESLICE + m15 * ESTR + mt * 16 + quad * 4] = v;
                }
            };

            if (nMt2 == 1) {
                // ======== fast path (<=16 cells): pipelined ========
                half8_t A2h[2];
#pragma unroll
                for (int ks2 = 0; ks2 < 2; ++ks2)
#pragma unroll
                    for (int j = 0; j < 8; ++j)
                        A2h[ks2][j] = (cl[ks2][j] == m15) ? (_Float16)1 : (_Float16)0;
                unsigned int rowr[4];
#pragma unroll
                for (int r = 0; r < 4; ++r) {
                    const int cell = quad * 4 + r;
                    rowr[r] = (cell < ncellsW) ? sCellG[wid][cell] : 0xFFFFFFFFu;
                }

                auto mfma2_store = [&](int nt, int slice) {
                    half8_t B2[2];
#pragma unroll
                    for (int ks2 = 0; ks2 < 2; ++ks2)
                        B2[ks2] = *(const half8_t*)
                            &embT[slice * ESLICE + m15 * ESTR + ks2 * 32 + quad * 8];
                    f32x4_t acc2 = (f32x4_t){0.0f, 0.0f, 0.0f, 0.0f};
#pragma unroll
                    for (int ks2 = 0; ks2 < 2; ++ks2)
                        acc2 = __builtin_amdgcn_mfma_f32_16x16x32_f16(
                            A2h[ks2], B2[ks2], acc2, 0, 0, 0);
                    float* const plane = sums + (size_t)nt * (size_t)P;
#pragma unroll
                    for (int r = 0; r < 4; ++r)
                        if (rowr[r] != 0xFFFFFFFFu)
                            plane[((size_t)rowr[r] << 4) + m15] = acc2[r];
                };

                mfma1_epi(0, 0);
                mfma1_epi(1, 1);
                mfma2_store(0, 0);
                mfma1_epi(2, 0);
                mfma2_store(1, 1);
                mfma1_epi(3, 1);
                mfma2_store(2, 0);
                mfma1_epi(4, 0);
                mfma2_store(3, 1);
                mfma2_store(4, 0);
            } else {
                // ======== general path (>16 cells in chunk) ========
#pragma unroll 1
                for (int nt = 0; nt < 5; ++nt) {
                    mfma1_epi(nt, 0);
                    half8_t B2[2];
#pragma unroll
                    for (int ks2 = 0; ks2 < 2; ++ks2)
                        B2[ks2] = *(const half8_t*)
                            &embT[m15 * ESTR + ks2 * 32 + quad * 8];
                    float* const plane = sums + (size_t)nt * (size_t)P;
                    for (int mt2 = 0; mt2 < nMt2; ++mt2) {
                        const int m2 = mt2 * 16 + m15;
                        f32x4_t acc2 = (f32x4_t){0.0f, 0.0f, 0.0f, 0.0f};
#pragma unroll
                        for (int ks2 = 0; ks2 < 2; ++ks2) {
                            half8_t A2;
#pragma unroll
                            for (int j = 0; j < 8; ++j)
                                A2[j] = (cl[ks2][j] == m2) ? (_Float16)1 : (_Float16)0;
                            acc2 = __builtin_amdgcn_mfma_f32_16x16x32_f16(
                                A2, B2[ks2], acc2, 0, 0, 0);
                        }
#pragma unroll
                        for (int r = 0; r < 4; ++r) {
                            const int cell = mt2 * 16 + quad * 4 + r;
                            if (cell < ncellsW) {
                                const unsigned int row = sCellG[wid][cell];
                                plane[((size_t)row << 4) + m15] = acc2[r];
                            }
                        }
                    }
                }
            }

            if (!hasNext) break;
            wv = wvn; hb = hbN;
#pragma unroll
            for (int mt = 0; mt < 4; ++mt) prm[mt] = prmN[mt];
        }
    }
}

// ---------------------------------------------------------------------------
// Head (R22-style): mean -> 1x1 conv -> BN -> relu -> out via MFMA. Wp
// A-frags direct from global (hi/lo f16 split, L2-hot); LDS = sMean only.
// Block 0 runs the diagnostics beacon.
// ---------------------------------------------------------------------------
__global__ __launch_bounds__(256, 2) void k_head(
    const float* __restrict__ sums,
    const unsigned int* __restrict__ cnt,
    const unsigned int* __restrict__ offs,
    const void* __restrict__ Wp_raw,
    const void* __restrict__ bp_raw,
    const void* __restrict__ gamma_raw,
    const void* __restrict__ beta_raw,
    const void* __restrict__ rmean_raw,
    const void* __restrict__ rvar_raw,
    const unsigned int* __restrict__ flags,
    const unsigned int* __restrict__ magic,
    float* __restrict__ out,
    int b0, int ncells, int P, int hostbits)
{
    __shared__ _Float16 sMean[BEVW * MSTR];    // [cell][k], k 80..103 zero
    __shared__ float sAlpha[COUT_], sDelta[COUT_];
    __shared__ float sRedF[4];
    __shared__ unsigned int sRedU[4];

    const int t = threadIdx.x;
    const int blk = blockIdx.x;
    const int bl = blk >> 7, hrow = blk & 127;
    const int bg = b0 + bl;
    const int wf32 = (int)flags[0];
    const int lane = t & 63;
    const int wid = t >> 6;
    const int m15 = lane & 15;
    const int quad = lane >> 4;

    if (t < COUT_) {
        if (wf32) {
            const float rs = rsqrtf(((const float*)rvar_raw)[t] + 1e-5f);
            const float al = ((const float*)gamma_raw)[t] * rs;
            sAlpha[t] = al;
            sDelta[t] = al * (((const float*)bp_raw)[t] - ((const float*)rmean_raw)[t])
                        + ((const float*)beta_raw)[t];
        } else {
            const float rs = rsqrtf(bf2f(((const unsigned short*)rvar_raw)[t]) + 1e-5f);
            const float al = bf2f(((const unsigned short*)gamma_raw)[t]) * rs;
            sAlpha[t] = al;
            sDelta[t] = al * (bf2f(((const unsigned short*)bp_raw)[t])
                              - bf2f(((const unsigned short*)rmean_raw)[t]))
                        + bf2f(((const unsigned short*)beta_raw)[t]);
        }
    }

    // ---- A-fragments direct from global (fragment layout, L2-hot), hi/lo.
    half8_t Ahi[2][3], Alo[2][3];
#pragma unroll
    for (int m = 0; m < 2; ++m) {
        const int d = (wid * 2 + m) * 16 + m15;
#pragma unroll
        for (int ks = 0; ks < 3; ++ks) {
#pragma unroll
            for (int j = 0; j < 8; ++j) {
                const int k = ks * 32 + quad * 8 + j;
                float w = 0.0f;
                if (k < CH)
                    w = wf32 ? ((const float*)Wp_raw)[k * COUT_ + d]
                             : bf2f(((const unsigned short*)Wp_raw)[k * COUT_ + d]);
                const _Float16 hi = (_Float16)w;
                Ahi[m][ks][j] = hi;
                Alo[m][ks][j] = (_Float16)(w - (float)hi);
            }
        }
    }

    // ---- stage mean[cell][k] f16 (+zero pad k 80..103).
    const int cellbase = bl * HW_ + hrow * BEVW;
    for (int i = t; i < BEVW * 26; i += 256) {
        const int w = i / 26, c4 = i % 26;
        _Float16* m = &sMean[w * MSTR + c4 * 4];
        if (c4 < 20) {
            const int nt = c4 >> 2, q = c4 & 3;
            const int cell = cellbase + w;
            const unsigned int c = cnt[cell];
            float4 s = {0.0f, 0.0f, 0.0f, 0.0f};
            if (c > 0) {
                const float4* plane4 = (const float4*)(sums + (size_t)nt * (size_t)P);
                s = plane4[cell * 4 + q];
                const unsigned int o = offs[cell];
                const int bA = (int)(o >> 6) + 1;
                const int bB = (int)((o + c - 1) >> 6);
                for (int b = bA; b <= bB; ++b) {
                    const float4 st = plane4[(ncells + b) * 4 + q];
                    s.x += st.x; s.y += st.y; s.z += st.z; s.w += st.w;
                }
            }
            const float inv = 1.0f / fmaxf((float)c, 1.0f);
            m[0] = (_Float16)(s.x * inv);
            m[1] = (_Float16)(s.y * inv);
            m[2] = (_Float16)(s.z * inv);
            m[3] = (_Float16)(s.w * inv);
        } else {
            m[0] = (_Float16)0.0f; m[1] = (_Float16)0.0f;
            m[2] = (_Float16)0.0f; m[3] = (_Float16)0.0f;
        }
    }
    __syncthreads();

    float alph[2][4], delt[2][4];
#pragma unroll
    for (int m = 0; m < 2; ++m)
#pragma unroll
        for (int r = 0; r < 4; ++r) {
            const int d = (wid * 2 + m) * 16 + quad * 4 + r;
            alph[m][r] = sAlpha[d];
            delt[m][r] = sDelta[d];
        }

#pragma unroll
    for (int n = 0; n < 8; ++n) {
        half8_t Bf[3];
#pragma unroll
        for (int ks = 0; ks < 3; ++ks)
            Bf[ks] = *(const half8_t*)&sMean[(n * 16 + m15) * MSTR + ks * 32 + quad * 8];
#pragma unroll
        for (int m = 0; m < 2; ++m) {
            f32x4_t acc = (f32x4_t){0.0f, 0.0f, 0.0f, 0.0f};
#pragma unroll
            for (int ks = 0; ks < 3; ++ks) {
                acc = __builtin_amdgcn_mfma_f32_16x16x32_f16(Ahi[m][ks], Bf[ks], acc, 0, 0, 0);
                acc = __builtin_amdgcn_mfma_f32_16x16x32_f16(Alo[m][ks], Bf[ks], acc, 0, 0, 0);
            }
#pragma unroll
            for (int r = 0; r < 4; ++r) {
                const int d = (wid * 2 + m) * 16 + quad * 4 + r;
                float o = fmaxf(fmaf(acc[r], alph[m][r], delt[m][r]), 0.0f);
                o = fminf(o, 512.0f);
                out[(((size_t)bg * COUT_ + d) * BEVH + hrow) * BEVW + n * 16 + m15] = o;
            }
        }
    }

    // ---- diagnostics beacon (block 0 only; healthy run writes nothing).
    if (blk == 0) {
        unsigned int cs = 0;
        for (int i = t; i < HW_; i += 256) cs += cnt[i];
        float sl = 0.0f;
        for (int i = t; i < CH * CH; i += 256) sl += fabsf(sums[i]);
#pragma unroll
        for (int off = 32; off > 0; off >>= 1) {
            cs += __shfl_down(cs, off);
            sl += __shfl_down(sl, off);
        }
        if (lane == 0) { sRedU[wid] = cs; sRedF[wid] = sl; }
        __syncthreads();
        if (t == 0) {
            const unsigned int csum = sRedU[0] + sRedU[1] + sRedU[2] + sRedU[3];
            const float ssum = sRedF[0] + sRedF[1] + sRedF[2] + sRedF[3];
            int code = hostbits;
            if (*magic != 0xCAFEBABEu) code |= 1;
            if (csum < 1000u)          code |= 2;
            if (!(ssum > 0.0f))        code |= 4;
            if (code) {
                code |= (int)(flags[0] ? 32 : 0);
                code |= (int)(flags[1] ? 64 : 0);
                out[0] = 1024.0f * (float)code;
            }
        }
    }
}

extern "C" void kernel_launch(void* const* d_in, const int* in_sizes, int n_in,
                              void* d_out, int out_size, void* d_ws, size_t ws_size,
                              hipStream_t stream) {
    const void* pts   = d_in[0];
    const void* W1    = d_in[1];
    const void* b1    = d_in[2];
    const void* W2    = d_in[3];
    const void* b2    = d_in[4];
    const void* Wp    = d_in[5];
    const void* bp    = d_in[6];
    const void* gamma = d_in[7];
    const void* beta  = d_in[8];
    const void* rmean = d_in[9];
    const void* rvar  = d_in[10];

    int hostbits = 0;
    if (n_in != 11 ||
        in_sizes[0] != B_ * NP_ * 4 ||
        in_sizes[1] != 4 * CH  || in_sizes[2] != CH ||
        in_sizes[3] != CH * CH || in_sizes[4] != CH ||
        in_sizes[5] != CH * COUT_ || in_sizes[6] != COUT_ ||
        out_size != B_ * COUT_ * HW_)
        hostbits |= 8;
    if (ws_size < SCRATCH_OFF + PER_BATCH + EXTRA_BYTES) hostbits |= 16;

    unsigned int* flags = (unsigned int*)d_ws;
    unsigned int* magic = (unsigned int*)((char*)d_ws + MAGIC_OFF);
    char* base = (char*)d_ws + SCRATCH_OFF;
    const size_t avail = (ws_size > SCRATCH_OFF + EXTRA_BYTES)
                       ? (ws_size - SCRATCH_OFF - EXTRA_BYTES) : PER_BATCH;
    int nb = (int)(avail / PER_BATCH);
    if (nb < 1) nb = 1;
    if (nb > B_) nb = B_;

    // Layout: cnt | sums (5 planes, incl. staging rows) | offs(+4) | cursor |
    //         chHead | prec (16B-aligned)
    unsigned int*   cnt      = (unsigned int*)base;
    float*          sums     = (float*)(cnt + (size_t)nb * HW_);
    const size_t    sumsFl   = (size_t)5 * ((size_t)nb * HW_ + (size_t)nb * NCHK) * 16;
    unsigned int*   offs     = (unsigned int*)(sums + sumsFl);
    unsigned int*   cursor   = offs + (size_t)nb * HW_ + 4;
    unsigned char*  chHead   = (unsigned char*)(cursor + (size_t)nb * HW_);
    char*           palign   = (char*)chHead + (size_t)nb * NCHK;
    palign = (char*)(((size_t)palign + 15) & ~(size_t)15);
    uint4*          prec     = (uint4*)palign;

    for (int b0 = 0; b0 < B_; b0 += nb) {
        const int bcnt = (B_ - b0 < nb) ? (B_ - b0) : nb;
        const int ncells = bcnt * HW_;
        const int npts   = bcnt * NP_;
        const int nblk   = ncells >> 10;      // 1024 cells per scan block
        const int P      = (ncells + bcnt * NCHK) * 16;   // plane stride (f32)

        k_init<<<128, 256, 0, stream>>>(
            (float4*)cnt, ncells / 4 + 1600,
            (unsigned int*)chHead, (bcnt * NCHK + 3) / 4,
            (const unsigned short*)W1, (const unsigned short*)pts, flags);

        k_bin<<<(npts / 2 + 255) / 256, 256, 0, stream>>>(
            pts, flags, cnt, b0, npts);

        k_scan<<<nblk, 256, 0, stream>>>(cnt, offs, cursor, chHead,
                                         nblk, ncells);

        k_scatteridx<<<(npts / 2 + 255) / 256, 256, 0, stream>>>(
            pts, flags, cursor, prec, b0, npts);

        k_mlp_mfma<<<768, 256, 0, stream>>>(
            prec, W1, b1, W2, b2, flags, magic, offs, chHead,
            sums, ncells, P);

        k_head<<<bcnt * BEVH, 256, 0, stream>>>(
            sums, cnt, offs, Wp, bp, gamma, beta, rmean, rvar, flags, magic,
            (float*)d_out, b0, ncells, P, hostbits);
    }
}